// Round 7
// baseline (29153.867 us; speedup 1.0000x reference)
//
#include <hip/hip_runtime.h>
#include <hip/hip_bf16.h>
#include <math.h>

typedef __hip_bfloat16 bf16;

#define LRELU(v) ((v) >= 0.f ? (v) : 0.2f * (v))

__device__ __forceinline__ float b2f(bf16 v) { return __bfloat162float(v); }
__device__ __forceinline__ bf16 f2b(float v) { return __float2bfloat16(v); }

// load element i of an EXTERNAL tensor whose dtype is f32 (isf32=1) or bf16
__device__ __forceinline__ float eload(const void* p, long i, int isf32)
{
    return isf32 ? ((const float*)p)[i] : b2f(((const bf16*)p)[i]);
}

// ---------------------------------------------------------------------------
// Input-dtype detector (robustness; inputs observed f32 on this harness).
// ---------------------------------------------------------------------------
__global__ void dtype_detect_kernel(const void* probe, int n, int* flag)
{
    if (threadIdx.x == 0 && blockIdx.x == 0) {
        const bf16* e = (const bf16*)probe;
        int f32 = 0;
        for (int i = 0; i < n; ++i) {
            const float v = b2f(e[i]);
            if (!(v > -1.0f && v < 1.0f)) f32 = 1;   // catches NaN too
        }
        *flag = f32;
    }
}

// ---------------------------------------------------------------------------
// Generic fused 3x3 SAME conv with row-windowed src/dst. fp32 accumulate.
// PS = pixels/thread/axis (1 or 2). Tile = 16*PS. 256 threads/block.
// 16 output channels / block. Weights/bias/es/eb always EXTERNAL (dtype by
// *dflag). src external iff src_ext (batch biased by b_off); add_src external
// iff add_ext. weoff = element offset into wgt (stacked per-branch weights).
// mode 0: dst = act(conv + bias)            (bf16, or fp32 if dst_f32)
// mode 1: (float*)dst += (conv*es[e]+eb[e]) * att[b,e,y,x]   (att fp32)
// mode 2: dst = resid + lrelu(conv+bias) * es[0]   (resid internal bf16)
// ---------------------------------------------------------------------------
template <int PS, int CIC>
__global__ void __launch_bounds__(256)
conv3x3_kernel(const void* __restrict__ src,
               const void* __restrict__ add_src,
               const void* __restrict__ add_scale_ptr,
               const void* __restrict__ wgt, long weoff,
               const void* __restrict__ bias,
               void* __restrict__ dst, int dst_f32,
               const bf16* __restrict__ resid,
               const float* __restrict__ att,
               const void* __restrict__ es_ptr,
               const void* __restrict__ eb_ptr,
               int e_idx,
               const int* __restrict__ dflag, int src_ext, int add_ext,
               int b_off,
               int B, int Cin, int Cout, int H, int W,
               int up, int act, int mode,
               int src_buf_row0, int src_buf_rows,
               int dst_buf_row0, int dst_buf_rows,
               int dst_y0, int dst_rows)
{
    constexpr int TILE = 16 * PS;
    constexpr int TIN  = TILE + 2;
    __shared__ float slds[TIN * TIN * CIC];
    __shared__ float wlds[16 * CIC * 9];

    const int ef = dflag[0];
    const int sf = src_ext ? ef : 0;
    const int af = add_ext ? ef : 0;
    const int sb = src_ext ? b_off : 0;
    const int ab = add_ext ? b_off : 0;

    const int coChunks = (Cout + 15) >> 4;
    const int tilesX   = W / TILE;
    const int tilesY   = dst_rows / TILE;

    int bid = blockIdx.x;
    const int coI = bid % coChunks; bid /= coChunks;
    const int tx  = bid % tilesX;   bid /= tilesX;
    const int ty  = bid % tilesY;
    const int b   = bid / tilesY;

    const int co0 = coI * 16;
    const int coN = min(16, Cout - co0);
    const int tid = threadIdx.x;
    const int py  = tid >> 4;
    const int px  = tid & 15;
    const int inW = up ? (W >> 1) : W;
    const int yb  = dst_y0 + ty * TILE;

    const float a_s = add_src ? eload(add_scale_ptr, 0, ef) : 0.0f;

    float acc[16][PS * PS];
#pragma unroll
    for (int i = 0; i < 16; ++i)
#pragma unroll
        for (int j = 0; j < PS * PS; ++j) acc[i][j] = 0.0f;

    for (int ci0 = 0; ci0 < Cin; ci0 += CIC) {
        const int cic = min(CIC, Cin - ci0);

        const int tot = TIN * TIN * cic;
        for (int i = tid; i < tot; i += 256) {
            const int c = i / (TIN * TIN);
            const int p = i % (TIN * TIN);
            const int iy = yb + p / TIN - 1;
            const int ix = tx * TILE + p % TIN - 1;
            float v = 0.0f;
            if (iy >= 0 && iy < H && ix >= 0 && ix < W) {
                const int sy = up ? (iy >> 1) : iy;
                const int sx = up ? (ix >> 1) : ix;
                const long row = (long)(sy - src_buf_row0);
                const long idxS = (((long)(b + sb) * Cin + ci0 + c) * src_buf_rows
                                   + row) * inW + sx;
                v = eload(src, idxS, sf);
                if (add_src) {
                    const long idxA = (((long)(b + ab) * Cin + ci0 + c) * src_buf_rows
                                       + row) * inW + sx;
                    v += a_s * eload(add_src, idxA, af);
                }
            }
            slds[i] = v;
        }

        const int wtot = 16 * cic * 9;
        for (int i = tid; i < wtot; i += 256) {
            const int co = i / (cic * 9);
            const int r  = i % (cic * 9);
            const int ci = r / 9;
            const int k  = r % 9;
            float v = 0.0f;
            if (co0 + co < Cout)
                v = eload(wgt, weoff + (((long)(co0 + co)) * Cin + ci0 + ci) * 9 + k, ef);
            wlds[(co * CIC + ci) * 9 + k] = v;
        }
        __syncthreads();

        for (int ci = 0; ci < cic; ++ci) {
            float in[(PS + 2) * (PS + 2)];
            const float* sp = &slds[ci * TIN * TIN + (py * PS) * TIN + px * PS];
#pragma unroll
            for (int i = 0; i < PS + 2; ++i)
#pragma unroll
                for (int j = 0; j < PS + 2; ++j)
                    in[i * (PS + 2) + j] = sp[i * TIN + j];

            const float* wbase = &wlds[ci * 9];
#pragma unroll
            for (int co = 0; co < 16; ++co) {
                const float* wp = wbase + co * CIC * 9;
                const float w0 = wp[0], w1 = wp[1], w2 = wp[2];
                const float w3 = wp[3], w4 = wp[4], w5 = wp[5];
                const float w6 = wp[6], w7 = wp[7], w8 = wp[8];
#pragma unroll
                for (int r = 0; r < PS; ++r)
#pragma unroll
                    for (int c = 0; c < PS; ++c) {
                        const float* q = &in[r * (PS + 2) + c];
                        float s = q[0] * w0 + q[1] * w1 + q[2] * w2
                                + q[PS + 2] * w3 + q[PS + 3] * w4 + q[PS + 4] * w5
                                + q[2 * (PS + 2)] * w6 + q[2 * (PS + 2) + 1] * w7
                                + q[2 * (PS + 2) + 2] * w8;
                        acc[co][r * PS + c] += s;
                    }
            }
        }
        __syncthreads();
    }

    const float es = es_ptr ? eload(es_ptr, e_idx, ef) : 1.0f;
    const float eb = eb_ptr ? eload(eb_ptr, e_idx, ef) : 0.0f;
#pragma unroll
    for (int r = 0; r < PS; ++r) {
#pragma unroll
        for (int c = 0; c < PS; ++c) {
            const int y  = yb + py * PS + r;
            const int xx = tx * TILE + px * PS + c;
            const int yr = y - dst_buf_row0;
            float attv = 0.0f;
            if (mode == 1)
                attv = att[(((long)b * 8 + e_idx) * H + y) * W + xx];
#pragma unroll
            for (int co = 0; co < 16; ++co) {
                if (co < coN) {
                    float v = acc[co][r * PS + c];
                    if (bias) v += eload(bias, co0 + co, ef);
                    const long di = (((long)b * Cout + co0 + co) * dst_buf_rows
                                     + yr) * W + xx;
                    if (mode == 0) {
                        if (act) v = LRELU(v);
                        if (dst_f32) ((float*)dst)[di] = v;
                        else         ((bf16*)dst)[di]  = f2b(v);
                    } else if (mode == 1) {
                        ((float*)dst)[di] += (v * es + eb) * attv;
                    } else {
                        const float lr = LRELU(v);
                        ((bf16*)dst)[di] = f2b(b2f(resid[di]) + lr * es);
                    }
                }
            }
        }
    }
}

// ---------------------------------------------------------------------------
__global__ void __launch_bounds__(256)
gn_silu_kernel(bf16* __restrict__ d, const void* __restrict__ g,
               const void* __restrict__ be, const int* __restrict__ dflag,
               int C, int gsize, int HW)
{
    const int ef = dflag[0];
    const int groups = C / gsize;
    const int blk = blockIdx.x;
    const int b  = blk / groups;
    const int gr = blk % groups;
    const long base = ((long)b * C + (long)gr * gsize) * HW;
    const int N = gsize * HW;

    float s = 0.0f, ss = 0.0f;
    for (int i = threadIdx.x; i < N; i += 256) {
        const float v = b2f(d[base + i]);
        s += v;
        ss += v * v;
    }
    __shared__ float rs[256], rss[256];
    rs[threadIdx.x] = s;
    rss[threadIdx.x] = ss;
    __syncthreads();
    for (int o = 128; o > 0; o >>= 1) {
        if (threadIdx.x < o) {
            rs[threadIdx.x]  += rs[threadIdx.x + o];
            rss[threadIdx.x] += rss[threadIdx.x + o];
        }
        __syncthreads();
    }
    __shared__ float mean_s, inv_s;
    if (threadIdx.x == 0) {
        const float mean = rs[0] / (float)N;
        const float var  = rss[0] / (float)N - mean * mean;
        mean_s = mean;
        inv_s  = rsqrtf(var + 1e-5f);
    }
    __syncthreads();
    const float mean = mean_s, inv = inv_s;
    for (int i = threadIdx.x; i < N; i += 256) {
        const int c = gr * gsize + i / HW;
        const float v  = b2f(d[base + i]);
        const float xn = (v - mean) * inv * eload(g, c, ef) + eload(be, c, ef);
        d[base + i] = f2b(xn / (1.0f + expf(-xn)));
    }
}

__global__ void __launch_bounds__(256)
softmax_t_kernel(float* __restrict__ m, int BHW, int HW, float invtemp)
{
    const int i = blockIdx.x * 256 + threadIdx.x;
    if (i >= BHW) return;
    const int b = i / HW;
    const int p = i % HW;
    const long base = (long)b * 8 * HW + p;
    float v[8];
    float mx = -1e30f;
#pragma unroll
    for (int t = 0; t < 8; ++t) {
        v[t] = m[base + (long)t * HW] * invtemp;
        mx = fmaxf(mx, v[t]);
    }
    float s = 0.0f;
#pragma unroll
    for (int t = 0; t < 8; ++t) {
        v[t] = expf(v[t] - mx);
        s += v[t];
    }
    const float r = 1.0f / s;
#pragma unroll
    for (int t = 0; t < 8; ++t)
        m[base + (long)t * HW] = v[t] * r;
}

__global__ void __launch_bounds__(256)
combine_kernel(const bf16* __restrict__ x0, const float* __restrict__ acc,
               const void* __restrict__ ss, const int* __restrict__ dflag,
               bf16* __restrict__ out, long n)
{
    const long i = (long)blockIdx.x * 256 + threadIdx.x;
    if (i < n) out[i] = f2b(b2f(x0[i]) + acc[i] * eload(ss, 0, dflag[0]));
}

__global__ void __launch_bounds__(256)
zero_kernel(float* __restrict__ p, long n)
{
    const long i = (long)blockIdx.x * 256 + threadIdx.x;
    if (i < n) p[i] = 0.0f;
}

// fully-coalesced float4 copy (grid-stride): n4 = number of float4 elements
__global__ void __launch_bounds__(256)
copy4_kernel(const float4* __restrict__ src, float4* __restrict__ dst, long n4)
{
    const long stride = (long)gridDim.x * 256;
    for (long i = (long)blockIdx.x * 256 + threadIdx.x; i < n4; i += stride)
        dst[i] = src[i];
}

// ---------------------------------------------------------------------------
static const int* g_dflag;

static void launch_conv_w(hipStream_t st, const void* src, const void* wgt,
                          const void* bias, void* dst, int dst_f32,
                          int B, int Cin, int Cout, int H, int W,
                          int up, int act,
                          int src_buf_row0, int src_buf_rows,
                          int dst_buf_row0, int dst_buf_rows,
                          int dst_y0, int dst_rows,
                          int src_ext = 0, int b_off = 0,
                          const void* add_src = nullptr,
                          const void* add_scale = nullptr, int add_ext = 0,
                          long weoff = 0,
                          int mode = 0, const bf16* resid = nullptr,
                          const float* att = nullptr,
                          const void* es = nullptr, const void* eb = nullptr,
                          int eidx = 0)
{
    const bool ps2 = (dst_rows % 32 == 0) && (W % 32 == 0) && (dst_y0 % 32 == 0);
    const int TILE = ps2 ? 32 : 16;
    const int blocks = B * (dst_rows / TILE) * (W / TILE) * ((Cout + 15) / 16);
    if (ps2)
        conv3x3_kernel<2, 8><<<blocks, 256, 0, st>>>(
            src, add_src, add_scale, wgt, weoff, bias, dst, dst_f32, resid, att,
            es, eb, eidx, g_dflag, src_ext, add_ext, b_off,
            B, Cin, Cout, H, W, up, act, mode,
            src_buf_row0, src_buf_rows, dst_buf_row0, dst_buf_rows, dst_y0, dst_rows);
    else
        conv3x3_kernel<1, 16><<<blocks, 256, 0, st>>>(
            src, add_src, add_scale, wgt, weoff, bias, dst, dst_f32, resid, att,
            es, eb, eidx, g_dflag, src_ext, add_ext, b_off,
            B, Cin, Cout, H, W, up, act, mode,
            src_buf_row0, src_buf_rows, dst_buf_row0, dst_buf_rows, dst_y0, dst_rows);
}

static void launch_conv(hipStream_t st, const void* src, const void* wgt,
                        const void* bias, void* dst, int dst_f32,
                        int B, int Cin, int Cout, int H, int W,
                        int up, int act,
                        int src_ext = 0, int b_off = 0,
                        const void* add_src = nullptr,
                        const void* add_scale = nullptr, int add_ext = 0,
                        long weoff = 0,
                        int mode = 0, const bf16* resid = nullptr,
                        const float* att = nullptr,
                        const void* es = nullptr, const void* eb = nullptr,
                        int eidx = 0)
{
    launch_conv_w(st, src, wgt, bias, dst, dst_f32, B, Cin, Cout, H, W, up, act,
                  0, up ? (H >> 1) : H, 0, H, 0, H,
                  src_ext, b_off, add_src, add_scale, add_ext, weoff,
                  mode, resid, att, es, eb, eidx);
}

extern "C" void kernel_launch(void* const* d_in, const int* in_sizes, int n_in,
                              void* d_out, int out_size, void* d_ws, size_t ws_size,
                              hipStream_t stream)
{
    const void* x_all   = d_in[0];
    const void* sp_all  = d_in[1];
    const void* nz_all  = d_in[2];
    const void* init_w  = d_in[3];
    const void* init_b  = d_in[4];
    const void* pre_w   = d_in[5];
    const void* tw0     = d_in[6];
    const void* tw1     = d_in[7];
    const void* tw2     = d_in[8];
    const void* tw3     = d_in[9];
    const void* tscale  = d_in[10];
    const void* tbias   = d_in[11];
    const void* nscale  = d_in[12];
    const void* sscale  = d_in[13];
    const void* pscale  = d_in[14];
    const void* post_w  = d_in[15];
    const void* post_b  = d_in[16];
    const void* m1_w    = d_in[17];
    const void* m1_b    = d_in[18];
    const void* m1_g    = d_in[19];
    const void* m1_be   = d_in[20];
    const void* m2_w    = d_in[21];
    const void* m2_g    = d_in[22];
    const void* m2_be   = d_in[23];
    const void* u1a_w   = d_in[24];
    const void* u1b_w   = d_in[25];
    const void* u1b_g   = d_in[26];
    const void* u1b_be  = d_in[27];
    const void* u2a_w   = d_in[28];
    const void* u2b_w   = d_in[29];
    const void* u2b_g   = d_in[30];
    const void* u2b_be  = d_in[31];
    const void* mf_w    = d_in[32];
    const void* up1_w   = d_in[33];
    const void* up1_b   = d_in[34];
    const void* up2_w   = d_in[35];
    const void* up2_b   = d_in[36];
    const void* hr_w    = d_in[37];
    const void* hr_b    = d_in[38];
    const void* fin_w   = d_in[39];
    const void* fin_b   = d_in[40];
    (void)in_sizes; (void)n_in; (void)out_size;

    // dtype flag in first 256 bytes of ws
    char* wsb = (char*)d_ws;
    int* dflag = (int*)wsb;
    g_dflag = dflag;
    dtype_detect_kernel<<<1, 64, 0, stream>>>(tw1, 128, dflag);

    // schedule: batch chunk bc, tail strip S
    // fixed(bc) = 256 + bc*(M 131072 + ACC 1048576 + OUT2 524288 + FOUT 786432)
    //           = 256 + bc*2490368
    int bc = 1, S = 16, tc = 1;
    for (int c = 16; c >= 1; c >>= 1) {
        const size_t fixed = 256u + (size_t)c * 2490368u;
        if (ws_size < fixed) continue;
        const size_t rem = ws_size - fixed;
        if (rem < (size_t)c * 2621440u) continue;
        if (rem >= 18874368u) {
            bc = c; S = 256;
            tc = (int)(rem / 18874368u); if (tc > c) tc = c;
            break;
        } else if (rem >= 9437184u)  { bc = c; S = 64; tc = 1; break; }
        else if (rem >= 7340032u)    { bc = c; S = 32; tc = 1; break; }
        else if (rem >= 6291456u)    { bc = c; S = 16; tc = 1; break; }
    }

    float* M    = (float*)(wsb + 256);
    float* ACC  = (float*)(wsb + 256 + (size_t)bc * 131072u);
    bf16*  OUT2 = (bf16*)(wsb + 256 + (size_t)bc * 1179648u);
    float* FOUT = (float*)(wsb + 256 + (size_t)bc * 1703936u);   // bc*196608 f32
    bf16*  A    = (bf16*)(wsb + 256 + (size_t)bc * 2490368u);    // arena

    for (int b0 = 0; b0 < 16; b0 += bc) {
        float* outp = (float*)d_out + (size_t)b0 * 3 * 65536;    // f32 output

        // ---- phase 1: multiplexer ----
        bf16* f1 = A;
        bf16* f2 = A + (size_t)bc * 65536;
        bf16* g1 = A + (size_t)bc * 131072;
        bf16* g2 = A + (size_t)bc * 262144;
        bf16* h1 = A + (size_t)bc * 393216;
        bf16* h2 = A + (size_t)bc * 655360;

        launch_conv(stream, sp_all, m1_w, m1_b, f1, 0, bc, 256, 256, 16, 16, 0, 0,
                    1, b0);
        gn_silu_kernel<<<bc * 8, 256, 0, stream>>>(f1, m1_g, m1_be, dflag, 256, 32, 256);
        launch_conv(stream, f1, m2_w, nullptr, f2, 0, bc, 256, 256, 16, 16, 0, 0);
        gn_silu_kernel<<<bc * 8, 256, 0, stream>>>(f2, m2_g, m2_be, dflag, 256, 32, 256);
        launch_conv(stream, f2, u1a_w, nullptr, g1, 0, bc, 256, 128, 32, 32, 1, 0);
        launch_conv(stream, g1, u1b_w, nullptr, g2, 0, bc, 128, 128, 32, 32, 0, 0);
        gn_silu_kernel<<<bc * 8, 256, 0, stream>>>(g2, u1b_g, u1b_be, dflag, 128, 16, 1024);
        launch_conv(stream, g2, u2a_w, nullptr, h1, 0, bc, 128, 64, 64, 64, 1, 0);
        launch_conv(stream, h1, u2b_w, nullptr, h2, 0, bc, 64, 64, 64, 64, 0, 0);
        gn_silu_kernel<<<bc * 8, 256, 0, stream>>>(h2, u2b_g, u2b_be, dflag, 64, 8, 4096);
        launch_conv(stream, h2, mf_w, nullptr, M, 1, bc, 64, 8, 64, 64, 0, 0);
        softmax_t_kernel<<<(bc * 4096 + 255) / 256, 256, 0, stream>>>(
            M, bc * 4096, 4096, 1.0f / 20.0f);

        // ---- phase 2: stem + branches ----
        bf16* x0   = A;
        bf16* xsp  = A + (size_t)bc * 262144;
        bf16* ping = A + (size_t)bc * 524288;
        bf16* pong = A + (size_t)bc * 917504;

        launch_conv(stream, x_all, init_w, init_b, x0, 0, bc, 3, 64, 64, 64, 0, 0,
                    1, b0);
        launch_conv(stream, x0, pre_w, nullptr, xsp, 0, bc, 64, 64, 64, 64, 0, 0,
                    0, b0, nz_all, nscale, 1);

        const long accn = (long)bc * 262144;
        zero_kernel<<<(int)((accn + 255) / 256), 256, 0, stream>>>(ACC, accn);

        for (int t = 0; t < 8; ++t) {
            launch_conv(stream, xsp,  tw0, nullptr, ping, 0, bc, 64, 96, 64, 64, 0, 1,
                        0, 0, nullptr, nullptr, 0, (long)t * 96 * 64 * 9);
            launch_conv(stream, ping, tw1, nullptr, pong, 0, bc, 96, 96, 64, 64, 0, 1,
                        0, 0, nullptr, nullptr, 0, (long)t * 96 * 96 * 9);
            launch_conv(stream, pong, tw2, nullptr, ping, 0, bc, 96, 96, 64, 64, 0, 1,
                        0, 0, nullptr, nullptr, 0, (long)t * 96 * 96 * 9);
            launch_conv(stream, ping, tw3, nullptr, ACC, 1, bc, 96, 64, 64, 64, 0, 0,
                        0, 0, nullptr, nullptr, 0, (long)t * 64 * 96 * 9,
                        1, nullptr, M, tscale, tbias, t);
        }

        bf16* outc = xsp;
        combine_kernel<<<(int)((accn + 255) / 256), 256, 0, stream>>>(
            x0, ACC, sscale, dflag, outc, accn);

        launch_conv(stream, outc, post_w, post_b, OUT2, 0, bc, 64, 64, 64, 64, 0, 0,
                    0, 0, nullptr, nullptr, 0, 0,
                    2, outc, nullptr, pscale, nullptr, 0);

        // ---- phase 3: tail; final conv staged to FOUT (HBM), then coalesced
        //      float4 copy to d_out (slow-destination-safe pattern) ----
        if (S == 256) {
            bf16* a1 = A;
            bf16* a2 = A + (size_t)tc * 1048576;
            bf16* a3 = A + (size_t)tc * 5242880;
            for (int s0 = 0; s0 < bc; s0 += tc) {
                const int cur = (tc < bc - s0) ? tc : (bc - s0);
                const bf16* src_c = OUT2 + (size_t)s0 * 64 * 4096;
                float* fout_c = FOUT + (size_t)s0 * 196608;
                launch_conv(stream, src_c, up1_w, up1_b, a1, 0, cur, 64, 64, 128, 128, 1, 1);
                launch_conv(stream, a1,   up2_w, up2_b, a2, 0, cur, 64, 64, 256, 256, 1, 1);
                launch_conv(stream, a2,   hr_w,  hr_b,  a3, 0, cur, 64, 64, 256, 256, 0, 1);
                launch_conv(stream, a3,   fin_w, fin_b, fout_c, 1, cur, 64, 3, 256, 256, 0, 0);
            }
        } else {
            bf16* a1  = A;
            bf16* a2s = A + 1048576;
            bf16* a3s = a2s + (size_t)(S + 64) * 16384;
            for (int i = 0; i < bc; ++i) {
                const bf16* src_i = OUT2 + (size_t)i * 64 * 4096;
                float* fout_i = FOUT + (size_t)i * 196608;
                launch_conv(stream, src_i, up1_w, up1_b, a1, 0, 1, 64, 64, 128, 128, 1, 1);
                for (int r0 = 0; r0 < 256; r0 += S) {
                    const int r1 = r0 + S;
                    const int w2a = (r0 - 32 > 0) ? r0 - 32 : 0;
                    const int w2b = (r1 + 32 < 256) ? r1 + 32 : 256;
                    const int w3a = (r0 - 16 > 0) ? r0 - 16 : 0;
                    const int w3b = (r1 + 16 < 256) ? r1 + 16 : 256;
                    launch_conv_w(stream, a1, up2_w, up2_b, a2s, 0,
                                  1, 64, 64, 256, 256, 1, 1,
                                  0, 128, w2a, w2b - w2a, w2a, w2b - w2a);
                    launch_conv_w(stream, a2s, hr_w, hr_b, a3s, 0,
                                  1, 64, 64, 256, 256, 0, 1,
                                  w2a, w2b - w2a, w3a, w3b - w3a, w3a, w3b - w3a);
                    launch_conv_w(stream, a3s, fin_w, fin_b, fout_i, 1,
                                  1, 64, 3, 256, 256, 0, 0,
                                  w3a, w3b - w3a, 0, 256, r0, S);
                }
            }
        }

        // coalesced copy FOUT -> d_out for this chunk
        const long n4 = (long)bc * 49152;          // bc*196608 floats / 4
        int cblocks = (int)((n4 + 255) / 256);
        if (cblocks > 2048) cblocks = 2048;
        copy4_kernel<<<cblocks, 256, 0, stream>>>(
            (const float4*)FOUT, (float4*)outp, n4);
    }
}

// Round 8
// 17706.561 us; speedup vs baseline: 1.6465x; 1.6465x over previous
//
#include <hip/hip_runtime.h>
#include <hip/hip_bf16.h>
#include <math.h>

typedef __hip_bfloat16 bf16;

#define LRELU(v) ((v) >= 0.f ? (v) : 0.2f * (v))

__device__ __forceinline__ float b2f(bf16 v) { return __bfloat162float(v); }
__device__ __forceinline__ bf16 f2b(float v) { return __float2bfloat16(v); }

// load element i of an EXTERNAL tensor whose dtype is f32 (isf32=1) or bf16
__device__ __forceinline__ float eload(const void* p, long i, int isf32)
{
    return isf32 ? ((const float*)p)[i] : b2f(((const bf16*)p)[i]);
}

union BfPack { short4 s; bf16 h[4]; };

// ---------------------------------------------------------------------------
// Input-dtype detector (inputs observed f32 on this harness; keep for safety).
// ---------------------------------------------------------------------------
__global__ void dtype_detect_kernel(const void* probe, int n, int* flag)
{
    if (threadIdx.x == 0 && blockIdx.x == 0) {
        const bf16* e = (const bf16*)probe;
        int f32 = 0;
        for (int i = 0; i < n; ++i) {
            const float v = b2f(e[i]);
            if (!(v > -1.0f && v < 1.0f)) f32 = 1;   // catches NaN too
        }
        *flag = f32;
    }
}

// ---------------------------------------------------------------------------
// FAST conv path: 32x32 output tile, 16 co per block, 256 threads.
// wave (tid>>6) owns 4 consecutive co; lane (tid&63) owns a 4x4 px tile
// (ty4=lane>>3, tx4=lane&7). acc[4][16] in VGPRs.
// LDS: input tile 34 rows x stride 36 (16B-aligned rows -> float4 reads),
// weights padded to stride 12 (16B-aligned -> float4 broadcast reads).
// Per ci: 12 wide input reads + 12 wide weight broadcasts per 576 FMAs.
// Modes/semantics identical to the generic kernel below.
// ---------------------------------------------------------------------------
__global__ void __launch_bounds__(256)
conv3x3_fast(const void* __restrict__ src,
             const void* __restrict__ add_src,
             const void* __restrict__ add_scale_ptr,
             const void* __restrict__ wgt, long weoff,
             const void* __restrict__ bias,
             void* __restrict__ dst, int dst_f32,
             const bf16* __restrict__ resid,
             const float* __restrict__ att,
             const void* __restrict__ es_ptr,
             const void* __restrict__ eb_ptr,
             int e_idx,
             const int* __restrict__ dflag, int src_ext, int add_ext,
             int b_off,
             int B, int Cin, int Cout, int H, int W,
             int up, int act, int mode,
             int src_buf_row0, int src_buf_rows,
             int dst_buf_row0, int dst_buf_rows,
             int dst_y0, int dst_rows)
{
    constexpr int CIC = 8;
    __shared__ float slds[CIC * 34 * 36];   // 39,168 B
    __shared__ float wlds[CIC * 16 * 12];   //  6,144 B

    const int ef = dflag[0];
    const int sf = src_ext ? ef : 0;
    const int af = add_ext ? ef : 0;
    const int sb = src_ext ? b_off : 0;
    const int ab = add_ext ? b_off : 0;

    const int coChunks = (Cout + 15) >> 4;
    const int tilesX   = W >> 5;
    const int tilesY   = dst_rows >> 5;

    int bid = blockIdx.x;
    const int coI = bid % coChunks; bid /= coChunks;
    const int tx  = bid % tilesX;   bid /= tilesX;
    const int ty  = bid % tilesY;
    const int b   = bid / tilesY;

    const int co0 = coI * 16;
    const int coN = min(16, Cout - co0);
    const int tid = threadIdx.x;
    const int wave = tid >> 6;
    const int lane = tid & 63;
    const int ty4 = lane >> 3;          // 0..7
    const int tx4 = lane & 7;           // 0..7
    const int inW = up ? (W >> 1) : W;
    const int yb  = dst_y0 + ty * 32;
    const int xb  = tx * 32;

    const float a_s = add_src ? eload(add_scale_ptr, 0, ef) : 0.0f;

    float acc[4][16];
#pragma unroll
    for (int i = 0; i < 4; ++i)
#pragma unroll
        for (int j = 0; j < 16; ++j) acc[i][j] = 0.0f;

    for (int ci0 = 0; ci0 < Cin; ci0 += CIC) {
        const int cic = min(CIC, Cin - ci0);

        // ---- stage input tile (34x34, stride 36) ----
        const int tot = 34 * 34 * cic;
        for (int i = tid; i < tot; i += 256) {
            const int c = i / 1156;
            const int p = i % 1156;
            const int row = p / 34;
            const int col = p % 34;
            const int iy = yb + row - 1;
            const int ix = xb + col - 1;
            float v = 0.0f;
            if (iy >= 0 && iy < H && ix >= 0 && ix < W) {
                const int sy = up ? (iy >> 1) : iy;
                const int sx = up ? (ix >> 1) : ix;
                const long rrow = (long)(sy - src_buf_row0);
                const long idxS = (((long)(b + sb) * Cin + ci0 + c) * src_buf_rows
                                   + rrow) * inW + sx;
                v = eload(src, idxS, sf);
                if (add_src) {
                    const long idxA = (((long)(b + ab) * Cin + ci0 + c) * src_buf_rows
                                       + rrow) * inW + sx;
                    v += a_s * eload(add_src, idxA, af);
                }
            }
            slds[(c * 34 + row) * 36 + col] = v;
        }

        // ---- stage weights (layout [ci][co][k], stride 12, zero-padded) ----
        const int wtot = cic * 144;
        for (int i = tid; i < wtot; i += 256) {
            const int ci = i / 144;
            const int r  = i % 144;
            const int co = r / 9;
            const int k  = r % 9;
            float v = 0.0f;
            if (co0 + co < Cout)
                v = eload(wgt, weoff + (((long)(co0 + co)) * Cin + ci0 + ci) * 9 + k, ef);
            wlds[(ci * 16 + co) * 12 + k] = v;
        }
        __syncthreads();

        // ---- compute ----
        for (int ci = 0; ci < cic; ++ci) {
            float in[6][6];
            const float* sp = &slds[(ci * 34 + ty4 * 4) * 36 + tx4 * 4];
#pragma unroll
            for (int r = 0; r < 6; ++r) {
                const float4 v4 = *(const float4*)(sp + r * 36);
                const float2 v2 = *(const float2*)(sp + r * 36 + 4);
                in[r][0] = v4.x; in[r][1] = v4.y; in[r][2] = v4.z; in[r][3] = v4.w;
                in[r][4] = v2.x; in[r][5] = v2.y;
            }
#pragma unroll
            for (int cc = 0; cc < 4; ++cc) {
                const float* wp = &wlds[(ci * 16 + wave * 4 + cc) * 12];
                const float4 wa = *(const float4*)wp;        // w0..w3
                const float4 wb = *(const float4*)(wp + 4);  // w4..w7
                const float w8 = wp[8];
#pragma unroll
                for (int r = 0; r < 4; ++r)
#pragma unroll
                    for (int c = 0; c < 4; ++c) {
                        float s = in[r][c]     * wa.x + in[r][c+1]     * wa.y + in[r][c+2]     * wa.z
                                + in[r+1][c]   * wa.w + in[r+1][c+1]   * wb.x + in[r+1][c+2]   * wb.y
                                + in[r+2][c]   * wb.z + in[r+2][c+1]   * wb.w + in[r+2][c+2]   * w8;
                        acc[cc][r * 4 + c] += s;
                    }
            }
        }
        __syncthreads();
    }

    // ---- epilogue ----
    const float es = es_ptr ? eload(es_ptr, e_idx, ef) : 1.0f;
    const float eb = eb_ptr ? eload(eb_ptr, e_idx, ef) : 0.0f;
    const int xx0 = xb + tx4 * 4;

#pragma unroll
    for (int cc = 0; cc < 4; ++cc) {
        const int cr = wave * 4 + cc;
        if (cr >= coN) continue;
        const int co = co0 + cr;
        const float bv = bias ? eload(bias, co, ef) : 0.0f;
#pragma unroll
        for (int r = 0; r < 4; ++r) {
            const int y  = yb + ty4 * 4 + r;
            const int yr = y - dst_buf_row0;
            const long di = (((long)b * Cout + co) * dst_buf_rows + yr) * W + xx0;
            float v0 = acc[cc][r * 4 + 0] + bv;
            float v1 = acc[cc][r * 4 + 1] + bv;
            float v2 = acc[cc][r * 4 + 2] + bv;
            float v3 = acc[cc][r * 4 + 3] + bv;
            if (mode == 0) {
                if (act) { v0 = LRELU(v0); v1 = LRELU(v1); v2 = LRELU(v2); v3 = LRELU(v3); }
                if (dst_f32) {
                    float4 o; o.x = v0; o.y = v1; o.z = v2; o.w = v3;
                    *(float4*)((float*)dst + di) = o;
                } else {
                    BfPack o;
                    o.h[0] = f2b(v0); o.h[1] = f2b(v1); o.h[2] = f2b(v2); o.h[3] = f2b(v3);
                    *(short4*)((bf16*)dst + di) = o.s;
                }
            } else if (mode == 1) {
                const float4 at = *(const float4*)&att[(((long)b * 8 + e_idx) * H + y) * W + xx0];
                float* dp = (float*)dst + di;
                float4 dv = *(float4*)dp;
                dv.x += (v0 * es + eb) * at.x;
                dv.y += (v1 * es + eb) * at.y;
                dv.z += (v2 * es + eb) * at.z;
                dv.w += (v3 * es + eb) * at.w;
                *(float4*)dp = dv;
            } else {
                BfPack rv; rv.s = *(const short4*)(resid + di);
                BfPack o;
                o.h[0] = f2b(b2f(rv.h[0]) + LRELU(v0) * es);
                o.h[1] = f2b(b2f(rv.h[1]) + LRELU(v1) * es);
                o.h[2] = f2b(b2f(rv.h[2]) + LRELU(v2) * es);
                o.h[3] = f2b(b2f(rv.h[3]) + LRELU(v3) * es);
                *(short4*)((bf16*)dst + di) = o.s;
            }
        }
    }
}

// ---------------------------------------------------------------------------
// Generic (slow) conv path — kept for 16x16 tiles (mux 16x16 convs, S=16 strips).
// ---------------------------------------------------------------------------
template <int PS, int CIC>
__global__ void __launch_bounds__(256)
conv3x3_kernel(const void* __restrict__ src,
               const void* __restrict__ add_src,
               const void* __restrict__ add_scale_ptr,
               const void* __restrict__ wgt, long weoff,
               const void* __restrict__ bias,
               void* __restrict__ dst, int dst_f32,
               const bf16* __restrict__ resid,
               const float* __restrict__ att,
               const void* __restrict__ es_ptr,
               const void* __restrict__ eb_ptr,
               int e_idx,
               const int* __restrict__ dflag, int src_ext, int add_ext,
               int b_off,
               int B, int Cin, int Cout, int H, int W,
               int up, int act, int mode,
               int src_buf_row0, int src_buf_rows,
               int dst_buf_row0, int dst_buf_rows,
               int dst_y0, int dst_rows)
{
    constexpr int TILE = 16 * PS;
    constexpr int TIN  = TILE + 2;
    __shared__ float slds[TIN * TIN * CIC];
    __shared__ float wlds[16 * CIC * 9];

    const int ef = dflag[0];
    const int sf = src_ext ? ef : 0;
    const int af = add_ext ? ef : 0;
    const int sb = src_ext ? b_off : 0;
    const int ab = add_ext ? b_off : 0;

    const int coChunks = (Cout + 15) >> 4;
    const int tilesX   = W / TILE;
    const int tilesY   = dst_rows / TILE;

    int bid = blockIdx.x;
    const int coI = bid % coChunks; bid /= coChunks;
    const int tx  = bid % tilesX;   bid /= tilesX;
    const int ty  = bid % tilesY;
    const int b   = bid / tilesY;

    const int co0 = coI * 16;
    const int coN = min(16, Cout - co0);
    const int tid = threadIdx.x;
    const int py  = tid >> 4;
    const int px  = tid & 15;
    const int inW = up ? (W >> 1) : W;
    const int yb  = dst_y0 + ty * TILE;

    const float a_s = add_src ? eload(add_scale_ptr, 0, ef) : 0.0f;

    float acc[16][PS * PS];
#pragma unroll
    for (int i = 0; i < 16; ++i)
#pragma unroll
        for (int j = 0; j < PS * PS; ++j) acc[i][j] = 0.0f;

    for (int ci0 = 0; ci0 < Cin; ci0 += CIC) {
        const int cic = min(CIC, Cin - ci0);

        const int tot = TIN * TIN * cic;
        for (int i = tid; i < tot; i += 256) {
            const int c = i / (TIN * TIN);
            const int p = i % (TIN * TIN);
            const int iy = yb + p / TIN - 1;
            const int ix = tx * TILE + p % TIN - 1;
            float v = 0.0f;
            if (iy >= 0 && iy < H && ix >= 0 && ix < W) {
                const int sy = up ? (iy >> 1) : iy;
                const int sx = up ? (ix >> 1) : ix;
                const long row = (long)(sy - src_buf_row0);
                const long idxS = (((long)(b + sb) * Cin + ci0 + c) * src_buf_rows
                                   + row) * inW + sx;
                v = eload(src, idxS, sf);
                if (add_src) {
                    const long idxA = (((long)(b + ab) * Cin + ci0 + c) * src_buf_rows
                                       + row) * inW + sx;
                    v += a_s * eload(add_src, idxA, af);
                }
            }
            slds[i] = v;
        }

        const int wtot = 16 * cic * 9;
        for (int i = tid; i < wtot; i += 256) {
            const int co = i / (cic * 9);
            const int r  = i % (cic * 9);
            const int ci = r / 9;
            const int k  = r % 9;
            float v = 0.0f;
            if (co0 + co < Cout)
                v = eload(wgt, weoff + (((long)(co0 + co)) * Cin + ci0 + ci) * 9 + k, ef);
            wlds[(co * CIC + ci) * 9 + k] = v;
        }
        __syncthreads();

        for (int ci = 0; ci < cic; ++ci) {
            float in[(PS + 2) * (PS + 2)];
            const float* sp = &slds[ci * TIN * TIN + (py * PS) * TIN + px * PS];
#pragma unroll
            for (int i = 0; i < PS + 2; ++i)
#pragma unroll
                for (int j = 0; j < PS + 2; ++j)
                    in[i * (PS + 2) + j] = sp[i * TIN + j];

            const float* wbase = &wlds[ci * 9];
#pragma unroll
            for (int co = 0; co < 16; ++co) {
                const float* wp = wbase + co * CIC * 9;
                const float w0 = wp[0], w1 = wp[1], w2 = wp[2];
                const float w3 = wp[3], w4 = wp[4], w5 = wp[5];
                const float w6 = wp[6], w7 = wp[7], w8 = wp[8];
#pragma unroll
                for (int r = 0; r < PS; ++r)
#pragma unroll
                    for (int c = 0; c < PS; ++c) {
                        const float* q = &in[r * (PS + 2) + c];
                        float s = q[0] * w0 + q[1] * w1 + q[2] * w2
                                + q[PS + 2] * w3 + q[PS + 3] * w4 + q[PS + 4] * w5
                                + q[2 * (PS + 2)] * w6 + q[2 * (PS + 2) + 1] * w7
                                + q[2 * (PS + 2) + 2] * w8;
                        acc[co][r * PS + c] += s;
                    }
            }
        }
        __syncthreads();
    }

    const float es = es_ptr ? eload(es_ptr, e_idx, ef) : 1.0f;
    const float eb = eb_ptr ? eload(eb_ptr, e_idx, ef) : 0.0f;
#pragma unroll
    for (int r = 0; r < PS; ++r) {
#pragma unroll
        for (int c = 0; c < PS; ++c) {
            const int y  = yb + py * PS + r;
            const int xx = tx * TILE + px * PS + c;
            const int yr = y - dst_buf_row0;
            float attv = 0.0f;
            if (mode == 1)
                attv = att[(((long)b * 8 + e_idx) * H + y) * W + xx];
#pragma unroll
            for (int co = 0; co < 16; ++co) {
                if (co < coN) {
                    float v = acc[co][r * PS + c];
                    if (bias) v += eload(bias, co0 + co, ef);
                    const long di = (((long)b * Cout + co0 + co) * dst_buf_rows
                                     + yr) * W + xx;
                    if (mode == 0) {
                        if (act) v = LRELU(v);
                        if (dst_f32) ((float*)dst)[di] = v;
                        else         ((bf16*)dst)[di]  = f2b(v);
                    } else if (mode == 1) {
                        ((float*)dst)[di] += (v * es + eb) * attv;
                    } else {
                        const float lr = LRELU(v);
                        ((bf16*)dst)[di] = f2b(b2f(resid[di]) + lr * es);
                    }
                }
            }
        }
    }
}

// ---------------------------------------------------------------------------
__global__ void __launch_bounds__(256)
gn_silu_kernel(bf16* __restrict__ d, const void* __restrict__ g,
               const void* __restrict__ be, const int* __restrict__ dflag,
               int C, int gsize, int HW)
{
    const int ef = dflag[0];
    const int groups = C / gsize;
    const int blk = blockIdx.x;
    const int b  = blk / groups;
    const int gr = blk % groups;
    const long base = ((long)b * C + (long)gr * gsize) * HW;
    const int N = gsize * HW;

    float s = 0.0f, ss = 0.0f;
    for (int i = threadIdx.x; i < N; i += 256) {
        const float v = b2f(d[base + i]);
        s += v;
        ss += v * v;
    }
    __shared__ float rs[256], rss[256];
    rs[threadIdx.x] = s;
    rss[threadIdx.x] = ss;
    __syncthreads();
    for (int o = 128; o > 0; o >>= 1) {
        if (threadIdx.x < o) {
            rs[threadIdx.x]  += rs[threadIdx.x + o];
            rss[threadIdx.x] += rss[threadIdx.x + o];
        }
        __syncthreads();
    }
    __shared__ float mean_s, inv_s;
    if (threadIdx.x == 0) {
        const float mean = rs[0] / (float)N;
        const float var  = rss[0] / (float)N - mean * mean;
        mean_s = mean;
        inv_s  = rsqrtf(var + 1e-5f);
    }
    __syncthreads();
    const float mean = mean_s, inv = inv_s;
    for (int i = threadIdx.x; i < N; i += 256) {
        const int c = gr * gsize + i / HW;
        const float v  = b2f(d[base + i]);
        const float xn = (v - mean) * inv * eload(g, c, ef) + eload(be, c, ef);
        d[base + i] = f2b(xn / (1.0f + expf(-xn)));
    }
}

__global__ void __launch_bounds__(256)
softmax_t_kernel(float* __restrict__ m, int BHW, int HW, float invtemp)
{
    const int i = blockIdx.x * 256 + threadIdx.x;
    if (i >= BHW) return;
    const int b = i / HW;
    const int p = i % HW;
    const long base = (long)b * 8 * HW + p;
    float v[8];
    float mx = -1e30f;
#pragma unroll
    for (int t = 0; t < 8; ++t) {
        v[t] = m[base + (long)t * HW] * invtemp;
        mx = fmaxf(mx, v[t]);
    }
    float s = 0.0f;
#pragma unroll
    for (int t = 0; t < 8; ++t) {
        v[t] = expf(v[t] - mx);
        s += v[t];
    }
    const float r = 1.0f / s;
#pragma unroll
    for (int t = 0; t < 8; ++t)
        m[base + (long)t * HW] = v[t] * r;
}

__global__ void __launch_bounds__(256)
combine_kernel(const bf16* __restrict__ x0, const float* __restrict__ acc,
               const void* __restrict__ ss, const int* __restrict__ dflag,
               bf16* __restrict__ out, long n)
{
    const long i = (long)blockIdx.x * 256 + threadIdx.x;
    if (i < n) out[i] = f2b(b2f(x0[i]) + acc[i] * eload(ss, 0, dflag[0]));
}

__global__ void __launch_bounds__(256)
zero_kernel(float* __restrict__ p, long n)
{
    const long i = (long)blockIdx.x * 256 + threadIdx.x;
    if (i < n) p[i] = 0.0f;
}

// ---------------------------------------------------------------------------
static const int* g_dflag;

static void launch_conv_w(hipStream_t st, const void* src, const void* wgt,
                          const void* bias, void* dst, int dst_f32,
                          int B, int Cin, int Cout, int H, int W,
                          int up, int act,
                          int src_buf_row0, int src_buf_rows,
                          int dst_buf_row0, int dst_buf_rows,
                          int dst_y0, int dst_rows,
                          int src_ext = 0, int b_off = 0,
                          const void* add_src = nullptr,
                          const void* add_scale = nullptr, int add_ext = 0,
                          long weoff = 0,
                          int mode = 0, const bf16* resid = nullptr,
                          const float* att = nullptr,
                          const void* es = nullptr, const void* eb = nullptr,
                          int eidx = 0)
{
    const bool fast = (dst_rows % 32 == 0) && (W % 32 == 0) && (dst_y0 % 32 == 0);
    const int TILE = fast ? 32 : 16;
    const int blocks = B * (dst_rows / TILE) * (W / TILE) * ((Cout + 15) / 16);
    if (fast)
        conv3x3_fast<<<blocks, 256, 0, st>>>(
            src, add_src, add_scale, wgt, weoff, bias, dst, dst_f32, resid, att,
            es, eb, eidx, g_dflag, src_ext, add_ext, b_off,
            B, Cin, Cout, H, W, up, act, mode,
            src_buf_row0, src_buf_rows, dst_buf_row0, dst_buf_rows, dst_y0, dst_rows);
    else
        conv3x3_kernel<1, 16><<<blocks, 256, 0, st>>>(
            src, add_src, add_scale, wgt, weoff, bias, dst, dst_f32, resid, att,
            es, eb, eidx, g_dflag, src_ext, add_ext, b_off,
            B, Cin, Cout, H, W, up, act, mode,
            src_buf_row0, src_buf_rows, dst_buf_row0, dst_buf_rows, dst_y0, dst_rows);
}

static void launch_conv(hipStream_t st, const void* src, const void* wgt,
                        const void* bias, void* dst, int dst_f32,
                        int B, int Cin, int Cout, int H, int W,
                        int up, int act,
                        int src_ext = 0, int b_off = 0,
                        const void* add_src = nullptr,
                        const void* add_scale = nullptr, int add_ext = 0,
                        long weoff = 0,
                        int mode = 0, const bf16* resid = nullptr,
                        const float* att = nullptr,
                        const void* es = nullptr, const void* eb = nullptr,
                        int eidx = 0)
{
    launch_conv_w(st, src, wgt, bias, dst, dst_f32, B, Cin, Cout, H, W, up, act,
                  0, up ? (H >> 1) : H, 0, H, 0, H,
                  src_ext, b_off, add_src, add_scale, add_ext, weoff,
                  mode, resid, att, es, eb, eidx);
}

extern "C" void kernel_launch(void* const* d_in, const int* in_sizes, int n_in,
                              void* d_out, int out_size, void* d_ws, size_t ws_size,
                              hipStream_t stream)
{
    const void* x_all   = d_in[0];
    const void* sp_all  = d_in[1];
    const void* nz_all  = d_in[2];
    const void* init_w  = d_in[3];
    const void* init_b  = d_in[4];
    const void* pre_w   = d_in[5];
    const void* tw0     = d_in[6];
    const void* tw1     = d_in[7];
    const void* tw2     = d_in[8];
    const void* tw3     = d_in[9];
    const void* tscale  = d_in[10];
    const void* tbias   = d_in[11];
    const void* nscale  = d_in[12];
    const void* sscale  = d_in[13];
    const void* pscale  = d_in[14];
    const void* post_w  = d_in[15];
    const void* post_b  = d_in[16];
    const void* m1_w    = d_in[17];
    const void* m1_b    = d_in[18];
    const void* m1_g    = d_in[19];
    const void* m1_be   = d_in[20];
    const void* m2_w    = d_in[21];
    const void* m2_g    = d_in[22];
    const void* m2_be   = d_in[23];
    const void* u1a_w   = d_in[24];
    const void* u1b_w   = d_in[25];
    const void* u1b_g   = d_in[26];
    const void* u1b_be  = d_in[27];
    const void* u2a_w   = d_in[28];
    const void* u2b_w   = d_in[29];
    const void* u2b_g   = d_in[30];
    const void* u2b_be  = d_in[31];
    const void* mf_w    = d_in[32];
    const void* up1_w   = d_in[33];
    const void* up1_b   = d_in[34];
    const void* up2_w   = d_in[35];
    const void* up2_b   = d_in[36];
    const void* hr_w    = d_in[37];
    const void* hr_b    = d_in[38];
    const void* fin_w   = d_in[39];
    const void* fin_b   = d_in[40];
    (void)in_sizes; (void)n_in; (void)out_size;

    // dtype flag in first 256 bytes of ws
    char* wsb = (char*)d_ws;
    int* dflag = (int*)wsb;
    g_dflag = dflag;
    dtype_detect_kernel<<<1, 64, 0, stream>>>(tw1, 128, dflag);

    // schedule: batch chunk bc, tail strip S
    int bc = 1, S = 16, tc = 1;
    for (int c = 16; c >= 1; c >>= 1) {
        const size_t fixed = 256u + (size_t)c * 1703936u;
        if (ws_size < fixed) continue;
        const size_t rem = ws_size - fixed;
        if (rem < (size_t)c * 2621440u) continue;
        if (rem >= 18874368u) {
            bc = c; S = 256;
            tc = (int)(rem / 18874368u); if (tc > c) tc = c;
            break;
        } else if (rem >= 9437184u)  { bc = c; S = 64; tc = 1; break; }
        else if (rem >= 7340032u)    { bc = c; S = 32; tc = 1; break; }
        else if (rem >= 6291456u)    { bc = c; S = 16; tc = 1; break; }
    }

    float* M    = (float*)(wsb + 256);
    float* ACC  = (float*)(wsb + 256 + (size_t)bc * 131072u);
    bf16*  OUT2 = (bf16*)(wsb + 256 + (size_t)bc * 1179648u);
    bf16*  A    = (bf16*)(wsb + 256 + (size_t)bc * 1703936u);

    for (int b0 = 0; b0 < 16; b0 += bc) {
        float* outp = (float*)d_out + (size_t)b0 * 3 * 65536;    // f32 output

        // ---- phase 1: multiplexer ----
        bf16* f1 = A;
        bf16* f2 = A + (size_t)bc * 65536;
        bf16* g1 = A + (size_t)bc * 131072;
        bf16* g2 = A + (size_t)bc * 262144;
        bf16* h1 = A + (size_t)bc * 393216;
        bf16* h2 = A + (size_t)bc * 655360;

        launch_conv(stream, sp_all, m1_w, m1_b, f1, 0, bc, 256, 256, 16, 16, 0, 0,
                    1, b0);
        gn_silu_kernel<<<bc * 8, 256, 0, stream>>>(f1, m1_g, m1_be, dflag, 256, 32, 256);
        launch_conv(stream, f1, m2_w, nullptr, f2, 0, bc, 256, 256, 16, 16, 0, 0);
        gn_silu_kernel<<<bc * 8, 256, 0, stream>>>(f2, m2_g, m2_be, dflag, 256, 32, 256);
        launch_conv(stream, f2, u1a_w, nullptr, g1, 0, bc, 256, 128, 32, 32, 1, 0);
        launch_conv(stream, g1, u1b_w, nullptr, g2, 0, bc, 128, 128, 32, 32, 0, 0);
        gn_silu_kernel<<<bc * 8, 256, 0, stream>>>(g2, u1b_g, u1b_be, dflag, 128, 16, 1024);
        launch_conv(stream, g2, u2a_w, nullptr, h1, 0, bc, 128, 64, 64, 64, 1, 0);
        launch_conv(stream, h1, u2b_w, nullptr, h2, 0, bc, 64, 64, 64, 64, 0, 0);
        gn_silu_kernel<<<bc * 8, 256, 0, stream>>>(h2, u2b_g, u2b_be, dflag, 64, 8, 4096);
        launch_conv(stream, h2, mf_w, nullptr, M, 1, bc, 64, 8, 64, 64, 0, 0);
        softmax_t_kernel<<<(bc * 4096 + 255) / 256, 256, 0, stream>>>(
            M, bc * 4096, 4096, 1.0f / 20.0f);

        // ---- phase 2: stem + branches ----
        bf16* x0   = A;
        bf16* xsp  = A + (size_t)bc * 262144;
        bf16* ping = A + (size_t)bc * 524288;
        bf16* pong = A + (size_t)bc * 917504;

        launch_conv(stream, x_all, init_w, init_b, x0, 0, bc, 3, 64, 64, 64, 0, 0,
                    1, b0);
        launch_conv(stream, x0, pre_w, nullptr, xsp, 0, bc, 64, 64, 64, 64, 0, 0,
                    0, b0, nz_all, nscale, 1);

        const long accn = (long)bc * 262144;
        zero_kernel<<<(int)((accn + 255) / 256), 256, 0, stream>>>(ACC, accn);

        for (int t = 0; t < 8; ++t) {
            launch_conv(stream, xsp,  tw0, nullptr, ping, 0, bc, 64, 96, 64, 64, 0, 1,
                        0, 0, nullptr, nullptr, 0, (long)t * 96 * 64 * 9);
            launch_conv(stream, ping, tw1, nullptr, pong, 0, bc, 96, 96, 64, 64, 0, 1,
                        0, 0, nullptr, nullptr, 0, (long)t * 96 * 96 * 9);
            launch_conv(stream, pong, tw2, nullptr, ping, 0, bc, 96, 96, 64, 64, 0, 1,
                        0, 0, nullptr, nullptr, 0, (long)t * 96 * 96 * 9);
            launch_conv(stream, ping, tw3, nullptr, ACC, 1, bc, 96, 64, 64, 64, 0, 0,
                        0, 0, nullptr, nullptr, 0, (long)t * 64 * 96 * 9,
                        1, nullptr, M, tscale, tbias, t);
        }

        bf16* outc = xsp;
        combine_kernel<<<(int)((accn + 255) / 256), 256, 0, stream>>>(
            x0, ACC, sscale, dflag, outc, accn);

        launch_conv(stream, outc, post_w, post_b, OUT2, 0, bc, 64, 64, 64, 64, 0, 0,
                    0, 0, nullptr, nullptr, 0, 0,
                    2, outc, nullptr, pscale, nullptr, 0);

        // ---- phase 3: tail (direct f32 writes to d_out) ----
        if (S == 256) {
            bf16* a1 = A;
            bf16* a2 = A + (size_t)tc * 1048576;
            bf16* a3 = A + (size_t)tc * 5242880;
            for (int s0 = 0; s0 < bc; s0 += tc) {
                const int cur = (tc < bc - s0) ? tc : (bc - s0);
                const bf16* src_c = OUT2 + (size_t)s0 * 64 * 4096;
                float* out_c = outp + (size_t)s0 * 3 * 65536;
                launch_conv(stream, src_c, up1_w, up1_b, a1, 0, cur, 64, 64, 128, 128, 1, 1);
                launch_conv(stream, a1,   up2_w, up2_b, a2, 0, cur, 64, 64, 256, 256, 1, 1);
                launch_conv(stream, a2,   hr_w,  hr_b,  a3, 0, cur, 64, 64, 256, 256, 0, 1);
                launch_conv(stream, a3,   fin_w, fin_b, out_c, 1, cur, 64, 3, 256, 256, 0, 0);
            }
        } else {
            bf16* a1  = A;
            bf16* a2s = A + 1048576;
            bf16* a3s = a2s + (size_t)(S + 64) * 16384;
            for (int i = 0; i < bc; ++i) {
                const bf16* src_i = OUT2 + (size_t)i * 64 * 4096;
                float* out_i = outp + (size_t)i * 3 * 65536;
                launch_conv(stream, src_i, up1_w, up1_b, a1, 0, 1, 64, 64, 128, 128, 1, 1);
                for (int r0 = 0; r0 < 256; r0 += S) {
                    const int r1 = r0 + S;
                    const int w2a = (r0 - 32 > 0) ? r0 - 32 : 0;
                    const int w2b = (r1 + 32 < 256) ? r1 + 32 : 256;
                    const int w3a = (r0 - 16 > 0) ? r0 - 16 : 0;
                    const int w3b = (r1 + 16 < 256) ? r1 + 16 : 256;
                    launch_conv_w(stream, a1, up2_w, up2_b, a2s, 0,
                                  1, 64, 64, 256, 256, 1, 1,
                                  0, 128, w2a, w2b - w2a, w2a, w2b - w2a);
                    launch_conv_w(stream, a2s, hr_w, hr_b, a3s, 0,
                                  1, 64, 64, 256, 256, 0, 1,
                                  w2a, w2b - w2a, w3a, w3b - w3a, w3a, w3b - w3a);
                    launch_conv_w(stream, a3s, fin_w, fin_b, out_i, 1,
                                  1, 64, 3, 256, 256, 0, 0,
                                  w3a, w3b - w3a, 0, 256, r0, S);
                }
            }
        }
    }
}

// Round 9
// 6356.030 us; speedup vs baseline: 4.5868x; 2.7858x over previous
//
#include <hip/hip_runtime.h>
#include <hip/hip_bf16.h>
#include <math.h>

typedef __hip_bfloat16 bf16;

#define LRELU(v) ((v) >= 0.f ? (v) : 0.2f * (v))

__device__ __forceinline__ float b2f(bf16 v) { return __bfloat162float(v); }
__device__ __forceinline__ bf16 f2b(float v) { return __float2bfloat16(v); }

// load element i of an EXTERNAL tensor whose dtype is f32 (isf32=1) or bf16
__device__ __forceinline__ float eload(const void* p, long i, int isf32)
{
    return isf32 ? ((const float*)p)[i] : b2f(((const bf16*)p)[i]);
}

union BfPack { short4 s; bf16 h[4]; };

typedef __attribute__((ext_vector_type(8))) short bfrag_t;   // 8 bf16
typedef __attribute__((ext_vector_type(4))) float ffrag_t;   // 4 f32 acc
union PackU { bfrag_t v; bf16 b[8]; };

// ---------------------------------------------------------------------------
// Input-dtype detector (inputs observed f32 on this harness; keep for safety).
// ---------------------------------------------------------------------------
__global__ void dtype_detect_kernel(const void* probe, int n, int* flag)
{
    if (threadIdx.x == 0 && blockIdx.x == 0) {
        const bf16* e = (const bf16*)probe;
        int f32 = 0;
        for (int i = 0; i < n; ++i) {
            const float v = b2f(e[i]);
            if (!(v > -1.0f && v < 1.0f)) f32 = 1;   // catches NaN too
        }
        *flag = f32;
    }
}

// ---------------------------------------------------------------------------
// MFMA implicit-GEMM 3x3 conv. Tile: R rows x 16 cols x 16 co, 4 waves.
// Requires Cin%32==0, W%16==0, dst_rows%R==0, dst_y0%16==0.
// wave w owns rows [w*G, (w+1)*G), G=R/4; per (tap,row): one 16x16x32 MFMA
//   A = W[co 16][ci 32] (per tap), B = I[ci 32][col 16] (row r+dy, cols +dx).
// LDS: sI[row][col][ci32] bf16, K-block swizzled by (col>>1)&3;
//      sW[tap][co][ci32] bf16, swizzled by (co>>1)&3. 16B reads, <=2-way bank.
// Fragment layouts (HW-verified, guide §3): A[m=lane&15][k=q*8+j],
//   B[k=q*8+j][n=lane&15], C/D: col=lane&15, row=q*4+reg.
// Modes identical to the generic kernel.
// ---------------------------------------------------------------------------
template <int R>
__global__ void __launch_bounds__(256)
conv3x3_mfma(const void* __restrict__ src,
             const void* __restrict__ add_src,
             const void* __restrict__ add_scale_ptr,
             const void* __restrict__ wgt, long weoff,
             const void* __restrict__ bias,
             void* __restrict__ dst, int dst_f32,
             const bf16* __restrict__ resid,
             const float* __restrict__ att,
             const void* __restrict__ es_ptr,
             const void* __restrict__ eb_ptr,
             int e_idx,
             const int* __restrict__ dflag, int src_ext, int add_ext,
             int b_off,
             int B, int Cin, int Cout, int H, int W,
             int up, int act, int mode,
             int src_buf_row0, int src_buf_rows,
             int dst_buf_row0, int dst_buf_rows,
             int dst_y0, int dst_rows)
{
    constexpr int TR = R + 2;
    constexpr int G  = R / 4;
    __shared__ __align__(16) bf16 sI[TR * 18 * 32];
    __shared__ __align__(16) bf16 sW[9 * 16 * 32];

    const int ef = dflag[0];
    const int sf = src_ext ? ef : 0;
    const int af = add_ext ? ef : 0;
    const int sb = src_ext ? b_off : 0;
    const int ab = add_ext ? b_off : 0;

    const int coChunks = (Cout + 15) >> 4;
    const int tilesX   = W >> 4;
    const int tilesY   = dst_rows / R;

    int bid = blockIdx.x;
    const int coI = bid % coChunks; bid /= coChunks;
    const int tx  = bid % tilesX;   bid /= tilesX;
    const int ty  = bid % tilesY;
    const int b   = bid / tilesY;

    const int co0 = coI * 16;
    const int coN = min(16, Cout - co0);
    const int tid  = threadIdx.x;
    const int wave = tid >> 6;
    const int lane = tid & 63;
    const int n = lane & 15;
    const int q = lane >> 4;
    const int inW = up ? (W >> 1) : W;
    const int yb  = dst_y0 + ty * R;
    const int xb  = tx * 16;
    const int r0w = wave * G;

    const float a_s = add_src ? eload(add_scale_ptr, 0, ef) : 0.0f;

    // per-lane LDS element offsets (swizzled)
    int cb[3];
#pragma unroll
    for (int d = 0; d < 3; ++d) {
        const int tc = n + d;
        cb[d] = tc * 32 + ((q ^ ((tc >> 1) & 3)) << 3);
    }
    const int aoff = n * 32 + ((q ^ ((n >> 1) & 3)) << 3);

    ffrag_t acc[G];
#pragma unroll
    for (int g = 0; g < G; ++g) acc[g] = (ffrag_t){0.f, 0.f, 0.f, 0.f};

    for (int ci0 = 0; ci0 < Cin; ci0 += 32) {
        // ---- stage input (TR x 18 x 32 ci, bf16, swizzled 16B packs) ----
        for (int i = tid; i < TR * 18 * 4; i += 256) {
            const int cig  = i & 3;
            const int pc   = i >> 2;
            const int tcol = pc % 18;
            const int trow = pc / 18;
            const int iy = yb + trow - 1;
            const int ix = xb + tcol - 1;
            PackU p;
            if (iy >= 0 && iy < H && ix >= 0 && ix < W) {
                const int sy = up ? (iy >> 1) : iy;
                const int sx = up ? (ix >> 1) : ix;
                const long rr = (long)(sy - src_buf_row0);
                const long cstr = (long)src_buf_rows * inW;
                long idx  = (((long)(b + sb) * Cin + ci0 + cig * 8) * src_buf_rows + rr) * inW + sx;
                long idxA = (((long)(b + ab) * Cin + ci0 + cig * 8) * src_buf_rows + rr) * inW + sx;
#pragma unroll
                for (int j = 0; j < 8; ++j) {
                    float v = eload(src, idx, sf);
                    if (add_src) v += a_s * eload(add_src, idxA, af);
                    p.b[j] = f2b(v);
                    idx += cstr; idxA += cstr;
                }
            } else {
#pragma unroll
                for (int j = 0; j < 8; ++j) p.b[j] = f2b(0.0f);
            }
            *(bfrag_t*)&sI[(trow * 18 + tcol) * 32 + ((cig ^ ((tcol >> 1) & 3)) << 3)] = p.v;
        }
        // ---- stage weights (9 taps x 16 co x 32 ci, swizzled) ----
        for (int i = tid; i < 4608; i += 256) {
            const int ci  = i & 31;
            const int rem = i >> 5;
            const int co  = rem & 15;
            const int tap = rem >> 4;
            float v = 0.0f;
            if (co0 + co < Cout)
                v = eload(wgt, weoff + ((long)(co0 + co) * Cin + ci0 + ci) * 9 + tap, ef);
            const int slot = (ci >> 3) ^ ((co >> 1) & 3);
            sW[(tap * 16 + co) * 32 + slot * 8 + (ci & 7)] = f2b(v);
        }
        __syncthreads();

        // ---- MFMA main loop ----
#pragma unroll
        for (int tap = 0; tap < 9; ++tap) {
            const int dy  = tap / 3;
            const int dxi = tap % 3;
            const bfrag_t a = *(const bfrag_t*)&sW[tap * 512 + aoff];
            const int cbase = cb[dxi];
#pragma unroll
            for (int g = 0; g < G; ++g) {
                const int trow = r0w + g + dy;
                const bfrag_t bb = *(const bfrag_t*)&sI[trow * 576 + cbase];
                acc[g] = __builtin_amdgcn_mfma_f32_16x16x32_bf16(a, bb, acc[g], 0, 0, 0);
            }
        }
        __syncthreads();
    }

    // ---- epilogue: lane holds D[co=q*4+reg][px=n] for each row-group ----
    const float es = es_ptr ? eload(es_ptr, e_idx, ef) : 1.0f;
    const float eb = eb_ptr ? eload(eb_ptr, e_idx, ef) : 0.0f;
    const int x = xb + n;
#pragma unroll
    for (int g = 0; g < G; ++g) {
        const int y  = yb + r0w + g;
        const int yr = y - dst_buf_row0;
        float attv = 0.0f;
        if (mode == 1)
            attv = att[(((long)b * 8 + e_idx) * H + y) * W + x];
#pragma unroll
        for (int reg = 0; reg < 4; ++reg) {
            const int cr = q * 4 + reg;
            if (cr < coN) {
                const int co = co0 + cr;
                float v = acc[g][reg];
                if (bias) v += eload(bias, co, ef);
                const long di = (((long)b * Cout + co) * dst_buf_rows + yr) * W + x;
                if (mode == 0) {
                    if (act) v = LRELU(v);
                    if (dst_f32) ((float*)dst)[di] = v;
                    else         ((bf16*)dst)[di]  = f2b(v);
                } else if (mode == 1) {
                    ((float*)dst)[di] += (v * es + eb) * attv;
                } else {
                    ((bf16*)dst)[di] = f2b(b2f(resid[di]) + LRELU(v) * es);
                }
            }
        }
    }
}

// ---------------------------------------------------------------------------
// FAST VALU conv (32x32 tile) — fallback for Cin%32!=0 (init conv).
// ---------------------------------------------------------------------------
__global__ void __launch_bounds__(256)
conv3x3_fast(const void* __restrict__ src,
             const void* __restrict__ add_src,
             const void* __restrict__ add_scale_ptr,
             const void* __restrict__ wgt, long weoff,
             const void* __restrict__ bias,
             void* __restrict__ dst, int dst_f32,
             const bf16* __restrict__ resid,
             const float* __restrict__ att,
             const void* __restrict__ es_ptr,
             const void* __restrict__ eb_ptr,
             int e_idx,
             const int* __restrict__ dflag, int src_ext, int add_ext,
             int b_off,
             int B, int Cin, int Cout, int H, int W,
             int up, int act, int mode,
             int src_buf_row0, int src_buf_rows,
             int dst_buf_row0, int dst_buf_rows,
             int dst_y0, int dst_rows)
{
    constexpr int CIC = 8;
    __shared__ float slds[CIC * 34 * 36];
    __shared__ float wlds[CIC * 16 * 12];

    const int ef = dflag[0];
    const int sf = src_ext ? ef : 0;
    const int af = add_ext ? ef : 0;
    const int sb = src_ext ? b_off : 0;
    const int ab = add_ext ? b_off : 0;

    const int coChunks = (Cout + 15) >> 4;
    const int tilesX   = W >> 5;
    const int tilesY   = dst_rows >> 5;

    int bid = blockIdx.x;
    const int coI = bid % coChunks; bid /= coChunks;
    const int tx  = bid % tilesX;   bid /= tilesX;
    const int ty  = bid % tilesY;
    const int b   = bid / tilesY;

    const int co0 = coI * 16;
    const int coN = min(16, Cout - co0);
    const int tid = threadIdx.x;
    const int wave = tid >> 6;
    const int lane = tid & 63;
    const int ty4 = lane >> 3;
    const int tx4 = lane & 7;
    const int inW = up ? (W >> 1) : W;
    const int yb  = dst_y0 + ty * 32;
    const int xb  = tx * 32;

    const float a_s = add_src ? eload(add_scale_ptr, 0, ef) : 0.0f;

    float acc[4][16];
#pragma unroll
    for (int i = 0; i < 4; ++i)
#pragma unroll
        for (int j = 0; j < 16; ++j) acc[i][j] = 0.0f;

    for (int ci0 = 0; ci0 < Cin; ci0 += CIC) {
        const int cic = min(CIC, Cin - ci0);

        const int tot = 34 * 34 * cic;
        for (int i = tid; i < tot; i += 256) {
            const int c = i / 1156;
            const int p = i % 1156;
            const int row = p / 34;
            const int col = p % 34;
            const int iy = yb + row - 1;
            const int ix = xb + col - 1;
            float v = 0.0f;
            if (iy >= 0 && iy < H && ix >= 0 && ix < W) {
                const int sy = up ? (iy >> 1) : iy;
                const int sx = up ? (ix >> 1) : ix;
                const long rrow = (long)(sy - src_buf_row0);
                const long idxS = (((long)(b + sb) * Cin + ci0 + c) * src_buf_rows
                                   + rrow) * inW + sx;
                v = eload(src, idxS, sf);
                if (add_src) {
                    const long idxA = (((long)(b + ab) * Cin + ci0 + c) * src_buf_rows
                                       + rrow) * inW + sx;
                    v += a_s * eload(add_src, idxA, af);
                }
            }
            slds[(c * 34 + row) * 36 + col] = v;
        }

        const int wtot = cic * 144;
        for (int i = tid; i < wtot; i += 256) {
            const int ci = i / 144;
            const int r  = i % 144;
            const int co = r / 9;
            const int k  = r % 9;
            float v = 0.0f;
            if (co0 + co < Cout)
                v = eload(wgt, weoff + (((long)(co0 + co)) * Cin + ci0 + ci) * 9 + k, ef);
            wlds[(ci * 16 + co) * 12 + k] = v;
        }
        __syncthreads();

        for (int ci = 0; ci < cic; ++ci) {
            float in[6][6];
            const float* sp = &slds[(ci * 34 + ty4 * 4) * 36 + tx4 * 4];
#pragma unroll
            for (int r = 0; r < 6; ++r) {
                const float4 v4 = *(const float4*)(sp + r * 36);
                const float2 v2 = *(const float2*)(sp + r * 36 + 4);
                in[r][0] = v4.x; in[r][1] = v4.y; in[r][2] = v4.z; in[r][3] = v4.w;
                in[r][4] = v2.x; in[r][5] = v2.y;
            }
#pragma unroll
            for (int cc = 0; cc < 4; ++cc) {
                const float* wp = &wlds[(ci * 16 + wave * 4 + cc) * 12];
                const float4 wa = *(const float4*)wp;
                const float4 wb = *(const float4*)(wp + 4);
                const float w8 = wp[8];
#pragma unroll
                for (int r = 0; r < 4; ++r)
#pragma unroll
                    for (int c = 0; c < 4; ++c) {
                        float s = in[r][c]     * wa.x + in[r][c+1]     * wa.y + in[r][c+2]     * wa.z
                                + in[r+1][c]   * wa.w + in[r+1][c+1]   * wb.x + in[r+1][c+2]   * wb.y
                                + in[r+2][c]   * wb.z + in[r+2][c+1]   * wb.w + in[r+2][c+2]   * w8;
                        acc[cc][r * 4 + c] += s;
                    }
            }
        }
        __syncthreads();
    }

    const float es = es_ptr ? eload(es_ptr, e_idx, ef) : 1.0f;
    const float eb = eb_ptr ? eload(eb_ptr, e_idx, ef) : 0.0f;
    const int xx0 = xb + tx4 * 4;

#pragma unroll
    for (int cc = 0; cc < 4; ++cc) {
        const int cr = wave * 4 + cc;
        if (cr >= coN) continue;
        const int co = co0 + cr;
        const float bv = bias ? eload(bias, co, ef) : 0.0f;
#pragma unroll
        for (int r = 0; r < 4; ++r) {
            const int y  = yb + ty4 * 4 + r;
            const int yr = y - dst_buf_row0;
            const long di = (((long)b * Cout + co) * dst_buf_rows + yr) * W + xx0;
            float v0 = acc[cc][r * 4 + 0] + bv;
            float v1 = acc[cc][r * 4 + 1] + bv;
            float v2 = acc[cc][r * 4 + 2] + bv;
            float v3 = acc[cc][r * 4 + 3] + bv;
            if (mode == 0) {
                if (act) { v0 = LRELU(v0); v1 = LRELU(v1); v2 = LRELU(v2); v3 = LRELU(v3); }
                if (dst_f32) {
                    float4 o; o.x = v0; o.y = v1; o.z = v2; o.w = v3;
                    *(float4*)((float*)dst + di) = o;
                } else {
                    BfPack o;
                    o.h[0] = f2b(v0); o.h[1] = f2b(v1); o.h[2] = f2b(v2); o.h[3] = f2b(v3);
                    *(short4*)((bf16*)dst + di) = o.s;
                }
            } else if (mode == 1) {
                const float4 at = *(const float4*)&att[(((long)b * 8 + e_idx) * H + y) * W + xx0];
                float* dp = (float*)dst + di;
                float4 dv = *(float4*)dp;
                dv.x += (v0 * es + eb) * at.x;
                dv.y += (v1 * es + eb) * at.y;
                dv.z += (v2 * es + eb) * at.z;
                dv.w += (v3 * es + eb) * at.w;
                *(float4*)dp = dv;
            } else {
                BfPack rv; rv.s = *(const short4*)(resid + di);
                BfPack o;
                o.h[0] = f2b(b2f(rv.h[0]) + LRELU(v0) * es);
                o.h[1] = f2b(b2f(rv.h[1]) + LRELU(v1) * es);
                o.h[2] = f2b(b2f(rv.h[2]) + LRELU(v2) * es);
                o.h[3] = f2b(b2f(rv.h[3]) + LRELU(v3) * es);
                *(short4*)((bf16*)dst + di) = o.s;
            }
        }
    }
}

// ---------------------------------------------------------------------------
// Generic (slow) conv path — last-resort fallback (16x16 tiles).
// ---------------------------------------------------------------------------
template <int PS, int CIC>
__global__ void __launch_bounds__(256)
conv3x3_kernel(const void* __restrict__ src,
               const void* __restrict__ add_src,
               const void* __restrict__ add_scale_ptr,
               const void* __restrict__ wgt, long weoff,
               const void* __restrict__ bias,
               void* __restrict__ dst, int dst_f32,
               const bf16* __restrict__ resid,
               const float* __restrict__ att,
               const void* __restrict__ es_ptr,
               const void* __restrict__ eb_ptr,
               int e_idx,
               const int* __restrict__ dflag, int src_ext, int add_ext,
               int b_off,
               int B, int Cin, int Cout, int H, int W,
               int up, int act, int mode,
               int src_buf_row0, int src_buf_rows,
               int dst_buf_row0, int dst_buf_rows,
               int dst_y0, int dst_rows)
{
    constexpr int TILE = 16 * PS;
    constexpr int TIN  = TILE + 2;
    __shared__ float slds[TIN * TIN * CIC];
    __shared__ float wlds[16 * CIC * 9];

    const int ef = dflag[0];
    const int sf = src_ext ? ef : 0;
    const int af = add_ext ? ef : 0;
    const int sb = src_ext ? b_off : 0;
    const int ab = add_ext ? b_off : 0;

    const int coChunks = (Cout + 15) >> 4;
    const int tilesX   = W / TILE;
    const int tilesY   = dst_rows / TILE;

    int bid = blockIdx.x;
    const int coI = bid % coChunks; bid /= coChunks;
    const int tx  = bid % tilesX;   bid /= tilesX;
    const int ty  = bid % tilesY;
    const int b   = bid / tilesY;

    const int co0 = coI * 16;
    const int coN = min(16, Cout - co0);
    const int tid = threadIdx.x;
    const int py  = tid >> 4;
    const int px  = tid & 15;
    const int inW = up ? (W >> 1) : W;
    const int yb  = dst_y0 + ty * TILE;

    const float a_s = add_src ? eload(add_scale_ptr, 0, ef) : 0.0f;

    float acc[16][PS * PS];
#pragma unroll
    for (int i = 0; i < 16; ++i)
#pragma unroll
        for (int j = 0; j < PS * PS; ++j) acc[i][j] = 0.0f;

    for (int ci0 = 0; ci0 < Cin; ci0 += CIC) {
        const int cic = min(CIC, Cin - ci0);

        const int tot = TIN * TIN * cic;
        for (int i = tid; i < tot; i += 256) {
            const int c = i / (TIN * TIN);
            const int p = i % (TIN * TIN);
            const int iy = yb + p / TIN - 1;
            const int ix = tx * TILE + p % TIN - 1;
            float v = 0.0f;
            if (iy >= 0 && iy < H && ix >= 0 && ix < W) {
                const int sy = up ? (iy >> 1) : iy;
                const int sx = up ? (ix >> 1) : ix;
                const long row = (long)(sy - src_buf_row0);
                const long idxS = (((long)(b + sb) * Cin + ci0 + c) * src_buf_rows
                                   + row) * inW + sx;
                v = eload(src, idxS, sf);
                if (add_src) {
                    const long idxA = (((long)(b + ab) * Cin + ci0 + c) * src_buf_rows
                                       + row) * inW + sx;
                    v += a_s * eload(add_src, idxA, af);
                }
            }
            slds[i] = v;
        }

        const int wtot = 16 * cic * 9;
        for (int i = tid; i < wtot; i += 256) {
            const int co = i / (cic * 9);
            const int r  = i % (cic * 9);
            const int ci = r / 9;
            const int k  = r % 9;
            float v = 0.0f;
            if (co0 + co < Cout)
                v = eload(wgt, weoff + (((long)(co0 + co)) * Cin + ci0 + ci) * 9 + k, ef);
            wlds[(co * CIC + ci) * 9 + k] = v;
        }
        __syncthreads();

        for (int ci = 0; ci < cic; ++ci) {
            float in[(PS + 2) * (PS + 2)];
            const float* sp = &slds[ci * TIN * TIN + (py * PS) * TIN + px * PS];
#pragma unroll
            for (int i = 0; i < PS + 2; ++i)
#pragma unroll
                for (int j = 0; j < PS + 2; ++j)
                    in[i * (PS + 2) + j] = sp[i * TIN + j];

            const float* wbase = &wlds[ci * 9];
#pragma unroll
            for (int co = 0; co < 16; ++co) {
                const float* wp = wbase + co * CIC * 9;
                const float w0 = wp[0], w1 = wp[1], w2 = wp[2];
                const float w3 = wp[3], w4 = wp[4], w5 = wp[5];
                const float w6 = wp[6], w7 = wp[7], w8 = wp[8];
#pragma unroll
                for (int r = 0; r < PS; ++r)
#pragma unroll
                    for (int c = 0; c < PS; ++c) {
                        const float* qq = &in[r * (PS + 2) + c];
                        float s = qq[0] * w0 + qq[1] * w1 + qq[2] * w2
                                + qq[PS + 2] * w3 + qq[PS + 3] * w4 + qq[PS + 4] * w5
                                + qq[2 * (PS + 2)] * w6 + qq[2 * (PS + 2) + 1] * w7
                                + qq[2 * (PS + 2) + 2] * w8;
                        acc[co][r * PS + c] += s;
                    }
            }
        }
        __syncthreads();
    }

    const float es = es_ptr ? eload(es_ptr, e_idx, ef) : 1.0f;
    const float eb = eb_ptr ? eload(eb_ptr, e_idx, ef) : 0.0f;
#pragma unroll
    for (int r = 0; r < PS; ++r) {
#pragma unroll
        for (int c = 0; c < PS; ++c) {
            const int y  = yb + py * PS + r;
            const int xx = tx * TILE + px * PS + c;
            const int yr = y - dst_buf_row0;
            float attv = 0.0f;
            if (mode == 1)
                attv = att[(((long)b * 8 + e_idx) * H + y) * W + xx];
#pragma unroll
            for (int co = 0; co < 16; ++co) {
                if (co < coN) {
                    float v = acc[co][r * PS + c];
                    if (bias) v += eload(bias, co0 + co, ef);
                    const long di = (((long)b * Cout + co0 + co) * dst_buf_rows
                                     + yr) * W + xx;
                    if (mode == 0) {
                        if (act) v = LRELU(v);
                        if (dst_f32) ((float*)dst)[di] = v;
                        else         ((bf16*)dst)[di]  = f2b(v);
                    } else if (mode == 1) {
                        ((float*)dst)[di] += (v * es + eb) * attv;
                    } else {
                        const float lr = LRELU(v);
                        ((bf16*)dst)[di] = f2b(b2f(resid[di]) + lr * es);
                    }
                }
            }
        }
    }
}

// ---------------------------------------------------------------------------
__global__ void __launch_bounds__(256)
gn_silu_kernel(bf16* __restrict__ d, const void* __restrict__ g,
               const void* __restrict__ be, const int* __restrict__ dflag,
               int C, int gsize, int HW)
{
    const int ef = dflag[0];
    const int groups = C / gsize;
    const int blk = blockIdx.x;
    const int b  = blk / groups;
    const int gr = blk % groups;
    const long base = ((long)b * C + (long)gr * gsize) * HW;
    const int N = gsize * HW;

    float s = 0.0f, ss = 0.0f;
    for (int i = threadIdx.x; i < N; i += 256) {
        const float v = b2f(d[base + i]);
        s += v;
        ss += v * v;
    }
    __shared__ float rs[256], rss[256];
    rs[threadIdx.x] = s;
    rss[threadIdx.x] = ss;
    __syncthreads();
    for (int o = 128; o > 0; o >>= 1) {
        if (threadIdx.x < o) {
            rs[threadIdx.x]  += rs[threadIdx.x + o];
            rss[threadIdx.x] += rss[threadIdx.x + o];
        }
        __syncthreads();
    }
    __shared__ float mean_s, inv_s;
    if (threadIdx.x == 0) {
        const float mean = rs[0] / (float)N;
        const float var  = rss[0] / (float)N - mean * mean;
        mean_s = mean;
        inv_s  = rsqrtf(var + 1e-5f);
    }
    __syncthreads();
    const float mean = mean_s, inv = inv_s;
    for (int i = threadIdx.x; i < N; i += 256) {
        const int c = gr * gsize + i / HW;
        const float v  = b2f(d[base + i]);
        const float xn = (v - mean) * inv * eload(g, c, ef) + eload(be, c, ef);
        d[base + i] = f2b(xn / (1.0f + expf(-xn)));
    }
}

__global__ void __launch_bounds__(256)
softmax_t_kernel(float* __restrict__ m, int BHW, int HW, float invtemp)
{
    const int i = blockIdx.x * 256 + threadIdx.x;
    if (i >= BHW) return;
    const int b = i / HW;
    const int p = i % HW;
    const long base = (long)b * 8 * HW + p;
    float v[8];
    float mx = -1e30f;
#pragma unroll
    for (int t = 0; t < 8; ++t) {
        v[t] = m[base + (long)t * HW] * invtemp;
        mx = fmaxf(mx, v[t]);
    }
    float s = 0.0f;
#pragma unroll
    for (int t = 0; t < 8; ++t) {
        v[t] = expf(v[t] - mx);
        s += v[t];
    }
    const float r = 1.0f / s;
#pragma unroll
    for (int t = 0; t < 8; ++t)
        m[base + (long)t * HW] = v[t] * r;
}

__global__ void __launch_bounds__(256)
combine_kernel(const bf16* __restrict__ x0, const float* __restrict__ acc,
               const void* __restrict__ ss, const int* __restrict__ dflag,
               bf16* __restrict__ out, long n)
{
    const long i = (long)blockIdx.x * 256 + threadIdx.x;
    if (i < n) out[i] = f2b(b2f(x0[i]) + acc[i] * eload(ss, 0, dflag[0]));
}

__global__ void __launch_bounds__(256)
zero_kernel(float* __restrict__ p, long n)
{
    const long i = (long)blockIdx.x * 256 + threadIdx.x;
    if (i < n) p[i] = 0.0f;
}

// ---------------------------------------------------------------------------
static const int* g_dflag;

static void launch_conv_w(hipStream_t st, const void* src, const void* wgt,
                          const void* bias, void* dst, int dst_f32,
                          int B, int Cin, int Cout, int H, int W,
                          int up, int act,
                          int src_buf_row0, int src_buf_rows,
                          int dst_buf_row0, int dst_buf_rows,
                          int dst_y0, int dst_rows,
                          int src_ext = 0, int b_off = 0,
                          const void* add_src = nullptr,
                          const void* add_scale = nullptr, int add_ext = 0,
                          long weoff = 0,
                          int mode = 0, const bf16* resid = nullptr,
                          const float* att = nullptr,
                          const void* es = nullptr, const void* eb = nullptr,
                          int eidx = 0)
{
    const bool mfma_ok = (Cin % 32 == 0) && (W % 16 == 0) &&
                         (dst_rows % 16 == 0) && (dst_y0 % 16 == 0);
    if (mfma_ok) {
        const int R = (dst_rows % 32 == 0) ? 32 : 16;
        const int blocks = B * (dst_rows / R) * (W / 16) * ((Cout + 15) / 16);
        if (R == 32)
            conv3x3_mfma<32><<<blocks, 256, 0, st>>>(
                src, add_src, add_scale, wgt, weoff, bias, dst, dst_f32, resid,
                att, es, eb, eidx, g_dflag, src_ext, add_ext, b_off,
                B, Cin, Cout, H, W, up, act, mode,
                src_buf_row0, src_buf_rows, dst_buf_row0, dst_buf_rows,
                dst_y0, dst_rows);
        else
            conv3x3_mfma<16><<<blocks, 256, 0, st>>>(
                src, add_src, add_scale, wgt, weoff, bias, dst, dst_f32, resid,
                att, es, eb, eidx, g_dflag, src_ext, add_ext, b_off,
                B, Cin, Cout, H, W, up, act, mode,
                src_buf_row0, src_buf_rows, dst_buf_row0, dst_buf_rows,
                dst_y0, dst_rows);
        return;
    }
    const bool fast = (dst_rows % 32 == 0) && (W % 32 == 0) && (dst_y0 % 32 == 0);
    const int TILE = fast ? 32 : 16;
    const int blocks = B * (dst_rows / TILE) * (W / TILE) * ((Cout + 15) / 16);
    if (fast)
        conv3x3_fast<<<blocks, 256, 0, st>>>(
            src, add_src, add_scale, wgt, weoff, bias, dst, dst_f32, resid, att,
            es, eb, eidx, g_dflag, src_ext, add_ext, b_off,
            B, Cin, Cout, H, W, up, act, mode,
            src_buf_row0, src_buf_rows, dst_buf_row0, dst_buf_rows, dst_y0, dst_rows);
    else
        conv3x3_kernel<1, 16><<<blocks, 256, 0, st>>>(
            src, add_src, add_scale, wgt, weoff, bias, dst, dst_f32, resid, att,
            es, eb, eidx, g_dflag, src_ext, add_ext, b_off,
            B, Cin, Cout, H, W, up, act, mode,
            src_buf_row0, src_buf_rows, dst_buf_row0, dst_buf_rows, dst_y0, dst_rows);
}

static void launch_conv(hipStream_t st, const void* src, const void* wgt,
                        const void* bias, void* dst, int dst_f32,
                        int B, int Cin, int Cout, int H, int W,
                        int up, int act,
                        int src_ext = 0, int b_off = 0,
                        const void* add_src = nullptr,
                        const void* add_scale = nullptr, int add_ext = 0,
                        long weoff = 0,
                        int mode = 0, const bf16* resid = nullptr,
                        const float* att = nullptr,
                        const void* es = nullptr, const void* eb = nullptr,
                        int eidx = 0)
{
    launch_conv_w(st, src, wgt, bias, dst, dst_f32, B, Cin, Cout, H, W, up, act,
                  0, up ? (H >> 1) : H, 0, H, 0, H,
                  src_ext, b_off, add_src, add_scale, add_ext, weoff,
                  mode, resid, att, es, eb, eidx);
}

extern "C" void kernel_launch(void* const* d_in, const int* in_sizes, int n_in,
                              void* d_out, int out_size, void* d_ws, size_t ws_size,
                              hipStream_t stream)
{
    const void* x_all   = d_in[0];
    const void* sp_all  = d_in[1];
    const void* nz_all  = d_in[2];
    const void* init_w  = d_in[3];
    const void* init_b  = d_in[4];
    const void* pre_w   = d_in[5];
    const void* tw0     = d_in[6];
    const void* tw1     = d_in[7];
    const void* tw2     = d_in[8];
    const void* tw3     = d_in[9];
    const void* tscale  = d_in[10];
    const void* tbias   = d_in[11];
    const void* nscale  = d_in[12];
    const void* sscale  = d_in[13];
    const void* pscale  = d_in[14];
    const void* post_w  = d_in[15];
    const void* post_b  = d_in[16];
    const void* m1_w    = d_in[17];
    const void* m1_b    = d_in[18];
    const void* m1_g    = d_in[19];
    const void* m1_be   = d_in[20];
    const void* m2_w    = d_in[21];
    const void* m2_g    = d_in[22];
    const void* m2_be   = d_in[23];
    const void* u1a_w   = d_in[24];
    const void* u1b_w   = d_in[25];
    const void* u1b_g   = d_in[26];
    const void* u1b_be  = d_in[27];
    const void* u2a_w   = d_in[28];
    const void* u2b_w   = d_in[29];
    const void* u2b_g   = d_in[30];
    const void* u2b_be  = d_in[31];
    const void* mf_w    = d_in[32];
    const void* up1_w   = d_in[33];
    const void* up1_b   = d_in[34];
    const void* up2_w   = d_in[35];
    const void* up2_b   = d_in[36];
    const void* hr_w    = d_in[37];
    const void* hr_b    = d_in[38];
    const void* fin_w   = d_in[39];
    const void* fin_b   = d_in[40];
    (void)in_sizes; (void)n_in; (void)out_size;

    // dtype flag in first 256 bytes of ws
    char* wsb = (char*)d_ws;
    int* dflag = (int*)wsb;
    g_dflag = dflag;
    dtype_detect_kernel<<<1, 64, 0, stream>>>(tw1, 128, dflag);

    // schedule: batch chunk bc, tail strip S
    int bc = 1, S = 16, tc = 1;
    for (int c = 16; c >= 1; c >>= 1) {
        const size_t fixed = 256u + (size_t)c * 1703936u;
        if (ws_size < fixed) continue;
        const size_t rem = ws_size - fixed;
        if (rem < (size_t)c * 2621440u) continue;
        if (rem >= 18874368u) {
            bc = c; S = 256;
            tc = (int)(rem / 18874368u); if (tc > c) tc = c;
            break;
        } else if (rem >= 9437184u)  { bc = c; S = 64; tc = 1; break; }
        else if (rem >= 7340032u)    { bc = c; S = 32; tc = 1; break; }
        else if (rem >= 6291456u)    { bc = c; S = 16; tc = 1; break; }
    }

    float* M    = (float*)(wsb + 256);
    float* ACC  = (float*)(wsb + 256 + (size_t)bc * 131072u);
    bf16*  OUT2 = (bf16*)(wsb + 256 + (size_t)bc * 1179648u);
    bf16*  A    = (bf16*)(wsb + 256 + (size_t)bc * 1703936u);

    for (int b0 = 0; b0 < 16; b0 += bc) {
        float* outp = (float*)d_out + (size_t)b0 * 3 * 65536;    // f32 output

        // ---- phase 1: multiplexer ----
        bf16* f1 = A;
        bf16* f2 = A + (size_t)bc * 65536;
        bf16* g1 = A + (size_t)bc * 131072;
        bf16* g2 = A + (size_t)bc * 262144;
        bf16* h1 = A + (size_t)bc * 393216;
        bf16* h2 = A + (size_t)bc * 655360;

        launch_conv(stream, sp_all, m1_w, m1_b, f1, 0, bc, 256, 256, 16, 16, 0, 0,
                    1, b0);
        gn_silu_kernel<<<bc * 8, 256, 0, stream>>>(f1, m1_g, m1_be, dflag, 256, 32, 256);
        launch_conv(stream, f1, m2_w, nullptr, f2, 0, bc, 256, 256, 16, 16, 0, 0);
        gn_silu_kernel<<<bc * 8, 256, 0, stream>>>(f2, m2_g, m2_be, dflag, 256, 32, 256);
        launch_conv(stream, f2, u1a_w, nullptr, g1, 0, bc, 256, 128, 32, 32, 1, 0);
        launch_conv(stream, g1, u1b_w, nullptr, g2, 0, bc, 128, 128, 32, 32, 0, 0);
        gn_silu_kernel<<<bc * 8, 256, 0, stream>>>(g2, u1b_g, u1b_be, dflag, 128, 16, 1024);
        launch_conv(stream, g2, u2a_w, nullptr, h1, 0, bc, 128, 64, 64, 64, 1, 0);
        launch_conv(stream, h1, u2b_w, nullptr, h2, 0, bc, 64, 64, 64, 64, 0, 0);
        gn_silu_kernel<<<bc * 8, 256, 0, stream>>>(h2, u2b_g, u2b_be, dflag, 64, 8, 4096);
        launch_conv(stream, h2, mf_w, nullptr, M, 1, bc, 64, 8, 64, 64, 0, 0);
        softmax_t_kernel<<<(bc * 4096 + 255) / 256, 256, 0, stream>>>(
            M, bc * 4096, 4096, 1.0f / 20.0f);

        // ---- phase 2: stem + branches ----
        bf16* x0   = A;
        bf16* xsp  = A + (size_t)bc * 262144;
        bf16* ping = A + (size_t)bc * 524288;
        bf16* pong = A + (size_t)bc * 917504;

        launch_conv(stream, x_all, init_w, init_b, x0, 0, bc, 3, 64, 64, 64, 0, 0,
                    1, b0);
        launch_conv(stream, x0, pre_w, nullptr, xsp, 0, bc, 64, 64, 64, 64, 0, 0,
                    0, b0, nz_all, nscale, 1);

        const long accn = (long)bc * 262144;
        zero_kernel<<<(int)((accn + 255) / 256), 256, 0, stream>>>(ACC, accn);

        for (int t = 0; t < 8; ++t) {
            launch_conv(stream, xsp,  tw0, nullptr, ping, 0, bc, 64, 96, 64, 64, 0, 1,
                        0, 0, nullptr, nullptr, 0, (long)t * 96 * 64 * 9);
            launch_conv(stream, ping, tw1, nullptr, pong, 0, bc, 96, 96, 64, 64, 0, 1,
                        0, 0, nullptr, nullptr, 0, (long)t * 96 * 96 * 9);
            launch_conv(stream, pong, tw2, nullptr, ping, 0, bc, 96, 96, 64, 64, 0, 1,
                        0, 0, nullptr, nullptr, 0, (long)t * 96 * 96 * 9);
            launch_conv(stream, ping, tw3, nullptr, ACC, 1, bc, 96, 64, 64, 64, 0, 0,
                        0, 0, nullptr, nullptr, 0, (long)t * 64 * 96 * 9,
                        1, nullptr, M, tscale, tbias, t);
        }

        bf16* outc = xsp;
        combine_kernel<<<(int)((accn + 255) / 256), 256, 0, stream>>>(
            x0, ACC, sscale, dflag, outc, accn);

        launch_conv(stream, outc, post_w, post_b, OUT2, 0, bc, 64, 64, 64, 64, 0, 0,
                    0, 0, nullptr, nullptr, 0, 0,
                    2, outc, nullptr, pscale, nullptr, 0);

        // ---- phase 3: tail (direct f32 writes to d_out) ----
        if (S == 256) {
            bf16* a1 = A;
            bf16* a2 = A + (size_t)tc * 1048576;
            bf16* a3 = A + (size_t)tc * 5242880;
            for (int s0 = 0; s0 < bc; s0 += tc) {
                const int cur = (tc < bc - s0) ? tc : (bc - s0);
                const bf16* src_c = OUT2 + (size_t)s0 * 64 * 4096;
                float* out_c = outp + (size_t)s0 * 3 * 65536;
                launch_conv(stream, src_c, up1_w, up1_b, a1, 0, cur, 64, 64, 128, 128, 1, 1);
                launch_conv(stream, a1,   up2_w, up2_b, a2, 0, cur, 64, 64, 256, 256, 1, 1);
                launch_conv(stream, a2,   hr_w,  hr_b,  a3, 0, cur, 64, 64, 256, 256, 0, 1);
                launch_conv(stream, a3,   fin_w, fin_b, out_c, 1, cur, 64, 3, 256, 256, 0, 0);
            }
        } else {
            bf16* a1  = A;
            bf16* a2s = A + 1048576;
            bf16* a3s = a2s + (size_t)(S + 64) * 16384;
            for (int i = 0; i < bc; ++i) {
                const bf16* src_i = OUT2 + (size_t)i * 64 * 4096;
                float* out_i = outp + (size_t)i * 3 * 65536;
                launch_conv(stream, src_i, up1_w, up1_b, a1, 0, 1, 64, 64, 128, 128, 1, 1);
                for (int r0 = 0; r0 < 256; r0 += S) {
                    const int r1 = r0 + S;
                    const int w2a = (r0 - 32 > 0) ? r0 - 32 : 0;
                    const int w2b = (r1 + 32 < 256) ? r1 + 32 : 256;
                    const int w3a = (r0 - 16 > 0) ? r0 - 16 : 0;
                    const int w3b = (r1 + 16 < 256) ? r1 + 16 : 256;
                    launch_conv_w(stream, a1, up2_w, up2_b, a2s, 0,
                                  1, 64, 64, 256, 256, 1, 1,
                                  0, 128, w2a, w2b - w2a, w2a, w2b - w2a);
                    launch_conv_w(stream, a2s, hr_w, hr_b, a3s, 0,
                                  1, 64, 64, 256, 256, 0, 1,
                                  w2a, w2b - w2a, w3a, w3b - w3a, w3a, w3b - w3a);
                    launch_conv_w(stream, a3s, fin_w, fin_b, out_i, 1,
                                  1, 64, 3, 256, 256, 0, 0,
                                  w3a, w3b - w3a, 0, 256, r0, S);
                }
            }
        }
    }
}

// Round 10
// 1978.708 us; speedup vs baseline: 14.7338x; 3.2122x over previous
//
#include <hip/hip_runtime.h>
#include <hip/hip_bf16.h>
#include <math.h>

typedef __hip_bfloat16 bf16;

#define LRELU(v) ((v) >= 0.f ? (v) : 0.2f * (v))

__device__ __forceinline__ float b2f(bf16 v) { return __bfloat162float(v); }
__device__ __forceinline__ bf16 f2b(float v) { return __float2bfloat16(v); }

// load element i of an EXTERNAL tensor whose dtype is f32 (isf32=1) or bf16
__device__ __forceinline__ float eload(const void* p, long i, int isf32)
{
    return isf32 ? ((const float*)p)[i] : b2f(((const bf16*)p)[i]);
}

union BfPack { short4 s; bf16 h[4]; };
typedef __attribute__((ext_vector_type(8))) short bfrag_t;   // 8 bf16
typedef __attribute__((ext_vector_type(4))) float ffrag_t;   // 4 f32 acc
union PackU { bfrag_t v; bf16 b[8]; };

// ---------------------------------------------------------------------------
// dtype detector (inputs observed f32; keep for robustness)
// ---------------------------------------------------------------------------
__global__ void dtype_detect_kernel(const void* probe, int n, int* flag)
{
    if (threadIdx.x == 0 && blockIdx.x == 0) {
        const bf16* e = (const bf16*)probe;
        int f32 = 0;
        for (int i = 0; i < n; ++i) {
            const float v = b2f(e[i]);
            if (!(v > -1.0f && v < 1.0f)) f32 = 1;
        }
        *flag = f32;
    }
}

// ---------------------------------------------------------------------------
// planar external [b0+b][C][HW] (dtype ef) -> NHWC8 bf16 [b][C/8][HW][8]
// ---------------------------------------------------------------------------
__global__ void __launch_bounds__(256)
to_nhwc8_kernel(const void* __restrict__ src, const int* __restrict__ dflag,
                bf16* __restrict__ out, int b_off, int C, int HW, long n)
{
    const int ef = dflag[0];
    const int CG = C >> 3;
    for (long i = (long)blockIdx.x * 256 + threadIdx.x; i < n;
         i += (long)gridDim.x * 256) {
        const int c8 = (int)(i & 7);
        long r = i >> 3;
        const int p = (int)(r % HW); r /= HW;
        const int cg = (int)(r % CG);
        const int b = (int)(r / CG);
        out[i] = f2b(eload(src, ((long)(b_off + b) * C + cg * 8 + c8) * HW + p, ef));
    }
}

// xs(NHWC8) = x0(NHWC8) + ns * noise(planar ext), C=64, HW=4096
__global__ void __launch_bounds__(256)
addnoise_kernel(const bf16* __restrict__ x0, const void* __restrict__ noise,
                const void* __restrict__ ns_ptr, const int* __restrict__ dflag,
                bf16* __restrict__ out, int b_off, long n)
{
    const int ef = dflag[0];
    const float ns = eload(ns_ptr, 0, ef);
    for (long i = (long)blockIdx.x * 256 + threadIdx.x; i < n;
         i += (long)gridDim.x * 256) {
        const int c8 = (int)(i & 7);
        long r = i >> 3;
        const int p = (int)(r % 4096); r /= 4096;
        const int cg = (int)(r % 8);
        const int b = (int)(r / 8);
        out[i] = f2b(b2f(x0[i]) +
                     ns * eload(noise, ((long)(b_off + b) * 64 + cg * 8 + c8) * 4096 + p, ef));
    }
}

// ---------------------------------------------------------------------------
// Weight prep: external [t][co][ci][3][3] (dtype ef) ->
//   wp[t][cog][cc][tap][co16][ci32] bf16 (A-fragment-ready, zero-pad co)
// ---------------------------------------------------------------------------
__global__ void __launch_bounds__(256)
wprep_kernel(const void* __restrict__ w, const int* __restrict__ dflag,
             bf16* __restrict__ out, int Cout, int Cin, long src_t, long total)
{
    const int ef = dflag[0];
    const int cogs = (Cout + 15) >> 4, ccs = Cin >> 5;
    for (long i = (long)blockIdx.x * 256 + threadIdx.x; i < total;
         i += (long)gridDim.x * 256) {
        const int e = (int)(i & 511);
        long r = i >> 9;
        const int tap = (int)(r % 9); r /= 9;
        const int cc = (int)(r % ccs); r /= ccs;
        const int cog = (int)(r % cogs);
        const int t = (int)(r / cogs);
        const int nn = e >> 5, k = e & 31;
        const int co = cog * 16 + nn, ci = cc * 32 + k;
        float v = 0.f;
        if (co < Cout)
            v = eload(w, (long)t * src_t + ((long)co * Cin + ci) * 9 + tap, ef);
        out[i] = f2b(v);
    }
}

// ---------------------------------------------------------------------------
// MFMA implicit-GEMM 3x3 conv, NHWC8 src, prepped weights.
// Tile 16x16 px x 16 co; 4 waves, wave owns 4 rows; 16x16x32 bf16 MFMA.
// cog_blocks>1: one cog per block (persistent acc, ci-chunk groups of 2).
// cog_blocks==1: requires ccs<=2; stage once, loop cogs inside.
// dst_kind: 0=NHWC8 bf16 (+act), 1=NHWC8 f32 += (v*es+eb)*att,
//           2=NHWC8 bf16 resid + lrelu(v)*es, 3=planar f32 (+act).
// ---------------------------------------------------------------------------
__global__ void __launch_bounds__(256)
conv_mfma(const bf16* __restrict__ src,
          const bf16* __restrict__ wp,
          const void* __restrict__ bias,
          void* __restrict__ dst, int dst_kind, int act,
          const bf16* __restrict__ resid,
          const float* __restrict__ att,
          const void* __restrict__ es_ptr, const void* __restrict__ eb_ptr,
          int e_idx,
          const int* __restrict__ dflag,
          int B, int Cin, int Cout, int H, int W, int up,
          int cog_blocks,
          int src_row0, int src_rows, int dst_row0, int dst_rows_buf,
          int dst_y0, int dst_rows)
{
    __shared__ __align__(16) bf16 sI[2 * 324 * 32];   // 41,472 B

    const int ef = dflag[0];
    const int ccs  = Cin >> 5;
    const int cogs = (Cout + 15) >> 4;
    const int CGi = Cin >> 3;
    const int CGo = Cout >> 3;          // valid for dst_kind 0/1/2
    const int tilesX = W >> 4;
    const int tilesY = dst_rows >> 4;
    const int inW = up ? (W >> 1) : W;

    int bid = blockIdx.x;
    const int cogb = bid % cog_blocks; bid /= cog_blocks;
    const int tx = bid % tilesX; bid /= tilesX;
    const int ty = bid % tilesY;
    const int b  = bid / tilesY;

    const int tid = threadIdx.x;
    const int wave = tid >> 6, lane = tid & 63;
    const int n = lane & 15, q = lane >> 4;
    const int yb = dst_y0 + ty * 16, xb = tx * 16;
    const int r0w = wave * 4;

    int cb[3];
#pragma unroll
    for (int d = 0; d < 3; ++d) {
        const int tc = n + d;
        cb[d] = tc * 32 + ((q ^ ((tc >> 1) & 3)) << 3);
    }

    // ---- staging: chunk group [cc0, cc0+ncc), coalesced 16B loads ----
    auto stage = [&](int cc0, int ncc) {
        const int items = ncc * 4 * 324;
        for (int i = tid; i < items; i += 256) {
            const int pc = i % 324;
            const int gi = i / 324;
            const int lc = gi >> 2, cig = gi & 3;
            const int trow = pc / 18, tcol = pc % 18;
            const int iy = yb + trow - 1, ix = xb + tcol - 1;
            PackU p;
            if (iy >= 0 && iy < H && ix >= 0 && ix < W) {
                const int sy = up ? (iy >> 1) : iy;
                const int sx = up ? (ix >> 1) : ix;
                const long gidx = ((((long)b * CGi + (long)(cc0 + lc) * 4 + cig) * src_rows
                                   + (sy - src_row0)) * inW + sx) << 3;
                p.v = *(const bfrag_t*)&src[gidx];
            } else {
#pragma unroll
                for (int j = 0; j < 8; ++j) p.b[j] = f2b(0.0f);
            }
            *(bfrag_t*)&sI[(lc * 324 + pc) * 32 + ((cig ^ ((tcol >> 1) & 3)) << 3)] = p.v;
        }
    };

    auto compute = [&](int cog, int cc_abs, int lc, ffrag_t* acc) {
        bfrag_t bfr[6][3];
#pragma unroll
        for (int rr = 0; rr < 6; ++rr) {
            const int base = (lc * 324 + (r0w + rr) * 18) * 32;
#pragma unroll
            for (int d = 0; d < 3; ++d)
                bfr[rr][d] = *(const bfrag_t*)&sI[base + cb[d]];
        }
        const bf16* wbase = wp + ((long)cog * ccs + cc_abs) * 9 * 512 + n * 32 + q * 8;
#pragma unroll
        for (int tap = 0; tap < 9; ++tap) {
            const bfrag_t a = *(const bfrag_t*)&wbase[(long)tap * 512];
            const int dy = tap / 3, dxi = tap % 3;
#pragma unroll
            for (int g = 0; g < 4; ++g)
                acc[g] = __builtin_amdgcn_mfma_f32_16x16x32_bf16(a, bfr[g + dy][dxi],
                                                                 acc[g], 0, 0, 0);
        }
    };

    auto epilogue = [&](int cog, ffrag_t* acc) {
        const float es  = es_ptr ? eload(es_ptr, e_idx, ef) : 1.0f;
        const float ebv = eb_ptr ? eload(eb_ptr, e_idx, ef) : 0.0f;
        const int x = xb + n;
        if (dst_kind == 3) {
#pragma unroll
            for (int g = 0; g < 4; ++g) {
                const int y = yb + r0w + g, yr = y - dst_row0;
#pragma unroll
                for (int reg = 0; reg < 4; ++reg) {
                    const int co = cog * 16 + q * 4 + reg;
                    if (co < Cout) {
                        float v = acc[g][reg];
                        if (bias) v += eload(bias, co, ef);
                        if (act) v = LRELU(v);
                        ((float*)dst)[(((long)b * Cout + co) * dst_rows_buf + yr) * W + x] = v;
                    }
                }
            }
            return;
        }
        const int cg = cog * 2 + (q >> 1);
        const int c8 = (q & 1) * 4;
        float bv[4];
#pragma unroll
        for (int reg = 0; reg < 4; ++reg)
            bv[reg] = bias ? eload(bias, cog * 16 + q * 4 + reg, ef) : 0.0f;
#pragma unroll
        for (int g = 0; g < 4; ++g) {
            const int y = yb + r0w + g, yr = y - dst_row0;
            const long base = ((((long)b * CGo + cg) * dst_rows_buf + yr) * W + x) * 8 + c8;
            if (dst_kind == 0) {
                BfPack o;
#pragma unroll
                for (int reg = 0; reg < 4; ++reg) {
                    float v = acc[g][reg] + bv[reg];
                    if (act) v = LRELU(v);
                    o.h[reg] = f2b(v);
                }
                *(short4*)&((bf16*)dst)[base] = o.s;
            } else if (dst_kind == 1) {
                const float attv = att[(((long)b * 8 + e_idx) * H + y) * W + x];
                float* dp = (float*)dst + base;
                float4 dv = *(float4*)dp;
                dv.x += ((acc[g][0] + bv[0]) * es + ebv) * attv;
                dv.y += ((acc[g][1] + bv[1]) * es + ebv) * attv;
                dv.z += ((acc[g][2] + bv[2]) * es + ebv) * attv;
                dv.w += ((acc[g][3] + bv[3]) * es + ebv) * attv;
                *(float4*)dp = dv;
            } else {
                BfPack rv; rv.s = *(const short4*)&resid[base];
                BfPack o;
#pragma unroll
                for (int reg = 0; reg < 4; ++reg) {
                    const float v = acc[g][reg] + bv[reg];
                    o.h[reg] = f2b(b2f(rv.h[reg]) + LRELU(v) * es);
                }
                *(short4*)&((bf16*)dst)[base] = o.s;
            }
        }
    };

    if (cog_blocks > 1) {
        ffrag_t acc[4];
#pragma unroll
        for (int g = 0; g < 4; ++g) acc[g] = (ffrag_t){0.f, 0.f, 0.f, 0.f};
        for (int cc0 = 0; cc0 < ccs; cc0 += 2) {
            const int ncc = (ccs - cc0 < 2) ? (ccs - cc0) : 2;
            stage(cc0, ncc);
            __syncthreads();
            for (int lc = 0; lc < ncc; ++lc) compute(cogb, cc0 + lc, lc, acc);
            __syncthreads();
        }
        epilogue(cogb, acc);
    } else {
        stage(0, ccs);          // ccs <= 2 guaranteed by host
        __syncthreads();
        for (int cog = 0; cog < cogs; ++cog) {
            ffrag_t acc[4];
#pragma unroll
            for (int g = 0; g < 4; ++g) acc[g] = (ffrag_t){0.f, 0.f, 0.f, 0.f};
            for (int lc = 0; lc < ccs; ++lc) compute(cog, lc, lc, acc);
            epilogue(cog, acc);
        }
    }
}

// ---------------------------------------------------------------------------
// init conv: planar ext x [b0+b][3][64][64] -> NHWC8 x0, Cout=64, 32x32 tiles
// ---------------------------------------------------------------------------
__global__ void __launch_bounds__(256)
conv_init_kernel(const void* __restrict__ src, const void* __restrict__ wgt,
                 const void* __restrict__ bias, bf16* __restrict__ dst,
                 const int* __restrict__ dflag, int b_off, int B)
{
    __shared__ float slds[3 * 34 * 36];
    __shared__ float wlds[3 * 16 * 12];
    const int ef = dflag[0];

    int bid = blockIdx.x;
    const int coI = bid & 3; bid >>= 2;
    const int tx = bid & 1; bid >>= 1;
    const int ty = bid & 1; bid >>= 1;
    const int b = bid;
    const int co0 = coI * 16;
    const int tid = threadIdx.x;
    const int wave = tid >> 6, lane = tid & 63;
    const int ty4 = lane >> 3, tx4 = lane & 7;
    const int yb = ty * 32, xb = tx * 32;

    for (int i = tid; i < 34 * 34 * 3; i += 256) {
        const int c = i / 1156, p = i % 1156;
        const int row = p / 34, col = p % 34;
        const int iy = yb + row - 1, ix = xb + col - 1;
        float v = 0.f;
        if (iy >= 0 && iy < 64 && ix >= 0 && ix < 64)
            v = eload(src, ((long)(b_off + b) * 3 + c) * 4096 + iy * 64 + ix, ef);
        slds[(c * 34 + row) * 36 + col] = v;
    }
    for (int i = tid; i < 3 * 144; i += 256) {
        const int ci = i / 144, r = i % 144;
        const int co = r / 9, k = r % 9;
        wlds[(ci * 16 + co) * 12 + k] = eload(wgt, ((long)(co0 + co) * 3 + ci) * 9 + k, ef);
    }
    __syncthreads();

    float acc[4][16];
#pragma unroll
    for (int i = 0; i < 4; ++i)
#pragma unroll
        for (int j = 0; j < 16; ++j) acc[i][j] = 0.f;

    for (int ci = 0; ci < 3; ++ci) {
        float in[6][6];
        const float* sp = &slds[(ci * 34 + ty4 * 4) * 36 + tx4 * 4];
#pragma unroll
        for (int r = 0; r < 6; ++r) {
            const float4 v4 = *(const float4*)(sp + r * 36);
            const float2 v2 = *(const float2*)(sp + r * 36 + 4);
            in[r][0] = v4.x; in[r][1] = v4.y; in[r][2] = v4.z; in[r][3] = v4.w;
            in[r][4] = v2.x; in[r][5] = v2.y;
        }
#pragma unroll
        for (int cc = 0; cc < 4; ++cc) {
            const float* wp = &wlds[(ci * 16 + wave * 4 + cc) * 12];
            const float4 wa = *(const float4*)wp;
            const float4 wb = *(const float4*)(wp + 4);
            const float w8 = wp[8];
#pragma unroll
            for (int r = 0; r < 4; ++r)
#pragma unroll
                for (int c = 0; c < 4; ++c)
                    acc[cc][r * 4 + c] += in[r][c] * wa.x + in[r][c+1] * wa.y + in[r][c+2] * wa.z
                        + in[r+1][c] * wa.w + in[r+1][c+1] * wb.x + in[r+1][c+2] * wb.y
                        + in[r+2][c] * wb.z + in[r+2][c+1] * wb.w + in[r+2][c+2] * w8;
        }
    }

    // NHWC8 epilogue: co = co0 + wave*4 + cc
    const int cg = coI * 2 + (wave >> 1);
    const int c8 = (wave & 1) * 4;
    float bv[4];
#pragma unroll
    for (int cc = 0; cc < 4; ++cc)
        bv[cc] = bias ? eload(bias, co0 + wave * 4 + cc, ef) : 0.0f;
#pragma unroll
    for (int r = 0; r < 4; ++r) {
        const int y = yb + ty4 * 4 + r;
#pragma unroll
        for (int c = 0; c < 4; ++c) {
            const int x = xb + tx4 * 4 + c;
            BfPack o;
#pragma unroll
            for (int cc = 0; cc < 4; ++cc)
                o.h[cc] = f2b(acc[cc][r * 4 + c] + bv[cc]);
            *(short4*)&dst[((((long)b * 8 + cg) * 64 + y) * 64 + x) * 8 + c8] = o.s;
        }
    }
}

// ---------------------------------------------------------------------------
// GroupNorm + SiLU on NHWC8 bf16 (gsize % 8 == 0)
// ---------------------------------------------------------------------------
__global__ void __launch_bounds__(256)
gn_silu_kernel(bf16* __restrict__ d, const void* __restrict__ g,
               const void* __restrict__ be, const int* __restrict__ dflag,
               int C, int gsize, int HW)
{
    const int ef = dflag[0];
    const int groups = C / gsize;
    const int blk = blockIdx.x;
    const int b  = blk / groups;
    const int gr = blk % groups;
    const long base = ((long)b * (C >> 3) + (long)gr * (gsize >> 3)) * HW * 8;
    const int N = gsize * HW;

    float s = 0.0f, ss = 0.0f;
    for (int i = threadIdx.x; i < N; i += 256) {
        const float v = b2f(d[base + i]);
        s += v; ss += v * v;
    }
    __shared__ float rs[256], rss[256];
    rs[threadIdx.x] = s; rss[threadIdx.x] = ss;
    __syncthreads();
    for (int o = 128; o > 0; o >>= 1) {
        if (threadIdx.x < o) {
            rs[threadIdx.x]  += rs[threadIdx.x + o];
            rss[threadIdx.x] += rss[threadIdx.x + o];
        }
        __syncthreads();
    }
    __shared__ float mean_s, inv_s;
    if (threadIdx.x == 0) {
        const float mean = rs[0] / (float)N;
        const float var  = rss[0] / (float)N - mean * mean;
        mean_s = mean; inv_s = rsqrtf(var + 1e-5f);
    }
    __syncthreads();
    const float mean = mean_s, inv = inv_s;
    for (int i = threadIdx.x; i < N; i += 256) {
        const int c = gr * gsize + (i / (HW * 8)) * 8 + (i & 7);
        const float v  = b2f(d[base + i]);
        const float xn = (v - mean) * inv * eload(g, c, ef) + eload(be, c, ef);
        d[base + i] = f2b(xn / (1.0f + expf(-xn)));
    }
}

__global__ void __launch_bounds__(256)
softmax_t_kernel(float* __restrict__ m, int BHW, int HW, float invtemp)
{
    const int i = blockIdx.x * 256 + threadIdx.x;
    if (i >= BHW) return;
    const int b = i / HW;
    const int p = i % HW;
    const long base = (long)b * 8 * HW + p;
    float v[8];
    float mx = -1e30f;
#pragma unroll
    for (int t = 0; t < 8; ++t) {
        v[t] = m[base + (long)t * HW] * invtemp;
        mx = fmaxf(mx, v[t]);
    }
    float s = 0.0f;
#pragma unroll
    for (int t = 0; t < 8; ++t) { v[t] = expf(v[t] - mx); s += v[t]; }
    const float r = 1.0f / s;
#pragma unroll
    for (int t = 0; t < 8; ++t) m[base + (long)t * HW] = v[t] * r;
}

// out(NHWC8 bf16) = x0 + acc(NHWC8 f32) * ss   (identical element ordering)
__global__ void __launch_bounds__(256)
combine_kernel(const bf16* __restrict__ x0, const float* __restrict__ acc,
               const void* __restrict__ ss, const int* __restrict__ dflag,
               bf16* __restrict__ out, long n)
{
    const long i = (long)blockIdx.x * 256 + threadIdx.x;
    if (i < n) out[i] = f2b(b2f(x0[i]) + acc[i] * eload(ss, 0, dflag[0]));
}

__global__ void __launch_bounds__(256)
zero_kernel(float* __restrict__ p, long n)
{
    const long i = (long)blockIdx.x * 256 + threadIdx.x;
    if (i < n) p[i] = 0.0f;
}

// ---------------------------------------------------------------------------
static const int* g_dflag;

static void conv2w(hipStream_t st, const bf16* src, const bf16* wp,
                   const void* bias, void* dst, int dst_kind, int act,
                   int B, int Cin, int Cout, int H, int W, int up,
                   int src_row0, int src_rows, int dst_row0, int dst_rows_buf,
                   int dst_y0, int dst_rows,
                   const bf16* resid = nullptr, const float* att = nullptr,
                   const void* es = nullptr, const void* eb = nullptr, int eidx = 0)
{
    const int ccs = Cin >> 5, cogs = (Cout + 15) >> 4;
    const int spatial = B * (dst_rows >> 4) * (W >> 4);
    const int cogb = (ccs > 2 || spatial < 1024) ? cogs : 1;
    conv_mfma<<<spatial * cogb, 256, 0, st>>>(
        src, wp, bias, dst, dst_kind, act, resid, att, es, eb, eidx, g_dflag,
        B, Cin, Cout, H, W, up, cogb,
        src_row0, src_rows, dst_row0, dst_rows_buf, dst_y0, dst_rows);
}

static void conv2(hipStream_t st, const bf16* src, const bf16* wp,
                  const void* bias, void* dst, int dst_kind, int act,
                  int B, int Cin, int Cout, int H, int W, int up,
                  const bf16* resid = nullptr, const float* att = nullptr,
                  const void* es = nullptr, const void* eb = nullptr, int eidx = 0)
{
    conv2w(st, src, wp, bias, dst, dst_kind, act, B, Cin, Cout, H, W, up,
           0, up ? (H >> 1) : H, 0, H, 0, H, resid, att, es, eb, eidx);
}

static long wp_elems(int T, int Cout, int Cin)
{
    return (long)T * ((Cout + 15) / 16) * (Cin / 32) * 9 * 512;
}

extern "C" void kernel_launch(void* const* d_in, const int* in_sizes, int n_in,
                              void* d_out, int out_size, void* d_ws, size_t ws_size,
                              hipStream_t stream)
{
    const void* x_all   = d_in[0];
    const void* sp_all  = d_in[1];
    const void* nz_all  = d_in[2];
    const void* init_w  = d_in[3];
    const void* init_b  = d_in[4];
    const void* pre_w   = d_in[5];
    const void* tw0     = d_in[6];
    const void* tw1     = d_in[7];
    const void* tw2     = d_in[8];
    const void* tw3     = d_in[9];
    const void* tscale  = d_in[10];
    const void* tbias   = d_in[11];
    const void* nscale  = d_in[12];
    const void* sscale  = d_in[13];
    const void* pscale  = d_in[14];
    const void* post_w  = d_in[15];
    const void* post_b  = d_in[16];
    const void* m1_w    = d_in[17];
    const void* m1_b    = d_in[18];
    const void* m1_g    = d_in[19];
    const void* m1_be   = d_in[20];
    const void* m2_w    = d_in[21];
    const void* m2_g    = d_in[22];
    const void* m2_be   = d_in[23];
    const void* u1a_w   = d_in[24];
    const void* u1b_w   = d_in[25];
    const void* u1b_g   = d_in[26];
    const void* u1b_be  = d_in[27];
    const void* u2a_w   = d_in[28];
    const void* u2b_w   = d_in[29];
    const void* u2b_g   = d_in[30];
    const void* u2b_be  = d_in[31];
    const void* mf_w    = d_in[32];
    const void* up1_w   = d_in[33];
    const void* up1_b   = d_in[34];
    const void* up2_w   = d_in[35];
    const void* up2_b   = d_in[36];
    const void* hr_w    = d_in[37];
    const void* hr_b    = d_in[38];
    const void* fin_w   = d_in[39];
    const void* fin_b   = d_in[40];
    (void)in_sizes; (void)n_in; (void)out_size;

    char* wsb = (char*)d_ws;
    int* dflag = (int*)wsb;
    g_dflag = dflag;
    dtype_detect_kernel<<<1, 64, 0, stream>>>(tw1, 128, dflag);

    // ---- prepped-weight region ----
    bf16* WP = (bf16*)(wsb + 256);
    long off = 0;
    auto alloc = [&](int T, int Cout, int Cin) { long o = off; off += wp_elems(T, Cout, Cin); return o; };
    const long o_m1  = alloc(1, 256, 256);
    const long o_m2  = alloc(1, 256, 256);
    const long o_u1a = alloc(1, 128, 256);
    const long o_u1b = alloc(1, 128, 128);
    const long o_u2a = alloc(1, 64, 128);
    const long o_u2b = alloc(1, 64, 64);
    const long o_mf  = alloc(1, 8, 64);
    const long o_pre = alloc(1, 64, 64);
    const long o_tw0 = alloc(8, 96, 64);
    const long o_tw1 = alloc(8, 96, 96);
    const long o_tw2 = alloc(8, 96, 96);
    const long o_tw3 = alloc(8, 64, 96);
    const long o_post = alloc(1, 64, 64);
    const long o_up1 = alloc(1, 64, 64);
    const long o_up2 = alloc(1, 64, 64);
    const long o_hr  = alloc(1, 64, 64);
    const long o_fin = alloc(1, 3, 64);
    const long wp_total = off;
    const size_t wp_bytes = (size_t)((wp_total * 2 + 255) & ~255L);

    auto prep = [&](const void* w, long o, int T, int Cout, int Cin) {
        const long tot = wp_elems(T, Cout, Cin);
        int gb = (int)((tot + 255) / 256); if (gb > 2048) gb = 2048;
        wprep_kernel<<<gb, 256, 0, stream>>>(w, dflag, WP + o, Cout, Cin,
                                             (long)Cout * Cin * 9, tot);
    };
    prep(m1_w, o_m1, 1, 256, 256);   prep(m2_w, o_m2, 1, 256, 256);
    prep(u1a_w, o_u1a, 1, 128, 256); prep(u1b_w, o_u1b, 1, 128, 128);
    prep(u2a_w, o_u2a, 1, 64, 128);  prep(u2b_w, o_u2b, 1, 64, 64);
    prep(mf_w, o_mf, 1, 8, 64);      prep(pre_w, o_pre, 1, 64, 64);
    prep(tw0, o_tw0, 8, 96, 64);     prep(tw1, o_tw1, 8, 96, 96);
    prep(tw2, o_tw2, 8, 96, 96);     prep(tw3, o_tw3, 8, 64, 96);
    prep(post_w, o_post, 1, 64, 64); prep(up1_w, o_up1, 1, 64, 64);
    prep(up2_w, o_up2, 1, 64, 64);   prep(hr_w, o_hr, 1, 64, 64);
    prep(fin_w, o_fin, 1, 3, 64);
    const long pt_tw0 = wp_elems(1, 96, 64), pt_tw1 = wp_elems(1, 96, 96);
    const long pt_tw3 = wp_elems(1, 64, 96);

    // ---- schedule: batch chunk bc, tail strip S ----
    int bc = 1, S = 16, tc = 1;
    for (int c = 16; c >= 1; c >>= 1) {
        const size_t fixed = 256u + wp_bytes + (size_t)c * 1703936u;
        if (ws_size < fixed) continue;
        const size_t rem = ws_size - fixed;
        if (rem < (size_t)c * 2621440u) continue;
        if (rem >= 18874368u) {
            bc = c; S = 256;
            tc = (int)(rem / 18874368u); if (tc > c) tc = c;
            break;
        } else if (rem >= 9437184u)  { bc = c; S = 64; tc = 1; break; }
        else if (rem >= 7340032u)    { bc = c; S = 32; tc = 1; break; }
        else if (rem >= 6291456u)    { bc = c; S = 16; tc = 1; break; }
    }

    char* dyn = wsb + 256 + wp_bytes;
    float* M    = (float*)dyn;                                   // bc*32768 f32
    float* ACC  = (float*)(dyn + (size_t)bc * 131072u);          // bc*262144 f32 (NHWC8)
    bf16*  OUT2 = (bf16*)(dyn + (size_t)bc * 1179648u);          // bc*262144 bf16
    bf16*  A    = (bf16*)(dyn + (size_t)bc * 1703936u);          // arena

    for (int b0 = 0; b0 < 16; b0 += bc) {
        float* outp = (float*)d_out + (size_t)b0 * 3 * 65536;

        // ---- phase 1: multiplexer ----
        bf16* SP8 = A;                            // bc*65536
        bf16* f1 = A + (size_t)bc * 65536;        // bc*65536
        bf16* f2 = A + (size_t)bc * 131072;       // bc*65536
        bf16* g1 = A + (size_t)bc * 196608;       // bc*131072
        bf16* g2 = A + (size_t)bc * 327680;       // bc*131072
        bf16* h1 = A + (size_t)bc * 458752;       // bc*262144
        bf16* h2 = A + (size_t)bc * 720896;       // bc*262144

        {
            const long n = (long)bc * 65536;
            to_nhwc8_kernel<<<2048, 256, 0, stream>>>(sp_all, dflag, SP8, b0, 256, 256, n);
        }
        conv2(stream, SP8, WP + o_m1, m1_b, f1, 0, 0, bc, 256, 256, 16, 16, 0);
        gn_silu_kernel<<<bc * 8, 256, 0, stream>>>(f1, m1_g, m1_be, dflag, 256, 32, 256);
        conv2(stream, f1, WP + o_m2, nullptr, f2, 0, 0, bc, 256, 256, 16, 16, 0);
        gn_silu_kernel<<<bc * 8, 256, 0, stream>>>(f2, m2_g, m2_be, dflag, 256, 32, 256);
        conv2(stream, f2, WP + o_u1a, nullptr, g1, 0, 0, bc, 256, 128, 32, 32, 1);
        conv2(stream, g1, WP + o_u1b, nullptr, g2, 0, 0, bc, 128, 128, 32, 32, 0);
        gn_silu_kernel<<<bc * 8, 256, 0, stream>>>(g2, u1b_g, u1b_be, dflag, 128, 16, 1024);
        conv2(stream, g2, WP + o_u2a, nullptr, h1, 0, 0, bc, 128, 64, 64, 64, 1);
        conv2(stream, h1, WP + o_u2b, nullptr, h2, 0, 0, bc, 64, 64, 64, 64, 0);
        gn_silu_kernel<<<bc * 8, 256, 0, stream>>>(h2, u2b_g, u2b_be, dflag, 64, 8, 4096);
        conv2(stream, h2, WP + o_mf, nullptr, M, 3, 0, bc, 64, 8, 64, 64, 0);
        softmax_t_kernel<<<(bc * 4096 + 255) / 256, 256, 0, stream>>>(
            M, bc * 4096, 4096, 1.0f / 20.0f);

        // ---- phase 2: stem + branches ----
        bf16* x0   = A;                            // bc*262144
        bf16* xsp  = A + (size_t)bc * 262144;      // bc*262144
        bf16* ping = A + (size_t)bc * 524288;      // bc*393216
        bf16* pong = A + (size_t)bc * 917504;      // bc*393216

        conv_init_kernel<<<bc * 16, 256, 0, stream>>>(x_all, init_w, init_b, x0,
                                                      dflag, b0, bc);
        {
            const long n = (long)bc * 262144;
            addnoise_kernel<<<2048, 256, 0, stream>>>(x0, nz_all, nscale, dflag,
                                                      ping, b0, n);   // xs -> ping
        }
        conv2(stream, ping, WP + o_pre, nullptr, xsp, 0, 0, bc, 64, 64, 64, 64, 0);

        const long accn = (long)bc * 262144;
        zero_kernel<<<(int)((accn + 255) / 256), 256, 0, stream>>>(ACC, accn);

        for (int t = 0; t < 8; ++t) {
            conv2(stream, xsp,  WP + o_tw0 + t * pt_tw0, nullptr, ping, 0, 1,
                  bc, 64, 96, 64, 64, 0);
            conv2(stream, ping, WP + o_tw1 + t * pt_tw1, nullptr, pong, 0, 1,
                  bc, 96, 96, 64, 64, 0);
            conv2(stream, pong, WP + o_tw2 + t * pt_tw1, nullptr, ping, 0, 1,
                  bc, 96, 96, 64, 64, 0);
            conv2(stream, ping, WP + o_tw3 + t * pt_tw3, nullptr, ACC, 1, 0,
                  bc, 96, 64, 64, 64, 0, nullptr, M, tscale, tbias, t);
        }

        bf16* outc = xsp;   // xsp dead after branch loop
        combine_kernel<<<(int)((accn + 255) / 256), 256, 0, stream>>>(
            x0, ACC, sscale, dflag, outc, accn);

        conv2(stream, outc, WP + o_post, post_b, OUT2, 2, 0, bc, 64, 64, 64, 64, 0,
              outc, nullptr, pscale, nullptr, 0);

        // ---- phase 3: tail ----
        if (S == 256) {
            bf16* a1 = A;                               // tc*1048576
            bf16* a2 = A + (size_t)tc * 1048576;        // tc*4194304
            bf16* a3 = A + (size_t)tc * 5242880;        // tc*4194304
            for (int s0 = 0; s0 < bc; s0 += tc) {
                const int cur = (tc < bc - s0) ? tc : (bc - s0);
                const bf16* src_c = OUT2 + (size_t)s0 * 262144;
                float* out_c = outp + (size_t)s0 * 3 * 65536;
                conv2(stream, src_c, WP + o_up1, up1_b, a1, 0, 1, cur, 64, 64, 128, 128, 1);
                conv2(stream, a1,   WP + o_up2, up2_b, a2, 0, 1, cur, 64, 64, 256, 256, 1);
                conv2(stream, a2,   WP + o_hr,  hr_b,  a3, 0, 1, cur, 64, 64, 256, 256, 0);
                conv2(stream, a3,   WP + o_fin, fin_b, out_c, 3, 0, cur, 64, 3, 256, 256, 0);
            }
        } else {
            bf16* a1  = A;                              // 1,048,576 elems
            bf16* a2s = A + 1048576;                    // (S+64)*16384
            bf16* a3s = a2s + (size_t)(S + 64) * 16384; // (S+32)*16384
            for (int i = 0; i < bc; ++i) {
                const bf16* src_i = OUT2 + (size_t)i * 262144;
                float* out_i = outp + (size_t)i * 3 * 65536;
                conv2(stream, src_i, WP + o_up1, up1_b, a1, 0, 1, 1, 64, 64, 128, 128, 1);
                for (int r0 = 0; r0 < 256; r0 += S) {
                    const int r1 = r0 + S;
                    const int w2a = (r0 - 32 > 0) ? r0 - 32 : 0;
                    const int w2b = (r1 + 32 < 256) ? r1 + 32 : 256;
                    const int w3a = (r0 - 16 > 0) ? r0 - 16 : 0;
                    const int w3b = (r1 + 16 < 256) ? r1 + 16 : 256;
                    conv2w(stream, a1, WP + o_up2, up2_b, a2s, 0, 1,
                           1, 64, 64, 256, 256, 1,
                           0, 128, w2a, w2b - w2a, w2a, w2b - w2a);
                    conv2w(stream, a2s, WP + o_hr, hr_b, a3s, 0, 1,
                           1, 64, 64, 256, 256, 0,
                           w2a, w2b - w2a, w3a, w3b - w3a, w3a, w3b - w3a);
                    conv2w(stream, a3s, WP + o_fin, fin_b, out_i, 3, 0,
                           1, 64, 3, 256, 256, 0,
                           w3a, w3b - w3a, 0, 256, r0, S);
                }
            }
        }
    }
}

// Round 11
// 1762.602 us; speedup vs baseline: 16.5402x; 1.1226x over previous
//
#include <hip/hip_runtime.h>
#include <hip/hip_bf16.h>
#include <math.h>

typedef __hip_bfloat16 bf16;

#define LRELU(v) ((v) >= 0.f ? (v) : 0.2f * (v))

__device__ __forceinline__ float b2f(bf16 v) { return __bfloat162float(v); }
__device__ __forceinline__ bf16 f2b(float v) { return __float2bfloat16(v); }

__device__ __forceinline__ float eload(const void* p, long i, int isf32)
{
    return isf32 ? ((const float*)p)[i] : b2f(((const bf16*)p)[i]);
}

union BfPack { short4 s; bf16 h[4]; };
typedef __attribute__((ext_vector_type(8))) short bfrag_t;   // 8 bf16
typedef __attribute__((ext_vector_type(4))) float ffrag_t;   // 4 f32 acc
union PackU { bfrag_t v; bf16 b[8]; };

// ---------------------------------------------------------------------------
__global__ void dtype_detect_kernel(const void* probe, int n, int* flag)
{
    if (threadIdx.x == 0 && blockIdx.x == 0) {
        const bf16* e = (const bf16*)probe;
        int f32 = 0;
        for (int i = 0; i < n; ++i) {
            const float v = b2f(e[i]);
            if (!(v > -1.0f && v < 1.0f)) f32 = 1;
        }
        *flag = f32;
    }
}

// planar external [b0+b][C][HW] -> NHWC8 bf16 [b][C/8][HW][8]
__global__ void __launch_bounds__(256)
to_nhwc8_kernel(const void* __restrict__ src, const int* __restrict__ dflag,
                bf16* __restrict__ out, int b_off, int C, int HW, long n)
{
    const int ef = dflag[0];
    const int CG = C >> 3;
    for (long i = (long)blockIdx.x * 256 + threadIdx.x; i < n;
         i += (long)gridDim.x * 256) {
        const int c8 = (int)(i & 7);
        long r = i >> 3;
        const int p = (int)(r % HW); r /= HW;
        const int cg = (int)(r % CG);
        const int b = (int)(r / CG);
        out[i] = f2b(eload(src, ((long)(b_off + b) * C + cg * 8 + c8) * HW + p, ef));
    }
}

// xs(NHWC8) = x0(NHWC8) + ns * noise(planar ext), C=64, HW=4096
__global__ void __launch_bounds__(256)
addnoise_kernel(const bf16* __restrict__ x0, const void* __restrict__ noise,
                const void* __restrict__ ns_ptr, const int* __restrict__ dflag,
                bf16* __restrict__ out, int b_off, long n)
{
    const int ef = dflag[0];
    const float ns = eload(ns_ptr, 0, ef);
    for (long i = (long)blockIdx.x * 256 + threadIdx.x; i < n;
         i += (long)gridDim.x * 256) {
        const int c8 = (int)(i & 7);
        long r = i >> 3;
        const int p = (int)(r % 4096); r /= 4096;
        const int cg = (int)(r % 8);
        const int b = (int)(r / 8);
        out[i] = f2b(b2f(x0[i]) +
                     ns * eload(noise, ((long)(b_off + b) * 64 + cg * 8 + c8) * 4096 + p, ef));
    }
}

// ---------------------------------------------------------------------------
// single-launch weight prep: external [t][co][ci][3][3] ->
//   wp[t][cog][cc][tap][co16][ci32] bf16 (A-fragment-ready, zero-pad co)
// ---------------------------------------------------------------------------
struct WEnt { const void* src; long dst_off; long total; int Cout; int Cin; };
struct WTab { WEnt e[17]; int n; };

__global__ void __launch_bounds__(256)
wprep_all_kernel(WTab tab, const int* __restrict__ dflag, bf16* __restrict__ out)
{
    const int ef = dflag[0];
    for (int k = 0; k < tab.n; ++k) {
        const WEnt E = tab.e[k];
        const int cogs = (E.Cout + 15) >> 4, ccs = E.Cin >> 5;
        const long src_t = (long)E.Cout * E.Cin * 9;
        for (long i = (long)blockIdx.x * 256 + threadIdx.x; i < E.total;
             i += (long)gridDim.x * 256) {
            const int e = (int)(i & 511);
            long r = i >> 9;
            const int tap = (int)(r % 9); r /= 9;
            const int cc = (int)(r % ccs); r /= ccs;
            const int cog = (int)(r % cogs);
            const int t = (int)(r / cogs);
            const int nn = e >> 5, kk = e & 31;
            const int co = cog * 16 + nn, ci = cc * 32 + kk;
            float v = 0.f;
            if (co < E.Cout)
                v = eload(E.src, (long)t * src_t + ((long)co * E.Cin + ci) * 9 + tap, ef);
            out[E.dst_off + i] = f2b(v);
        }
    }
}

// ---------------------------------------------------------------------------
// MFMA implicit-GEMM 3x3 conv, NHWC8 src, prepped weights.
// Tile 16x16 px; block handles CPB consecutive cogs (persistent acc,
// B-fragments hoisted out of the cog loop). 4 waves; wave owns 4 rows.
// dst_kind: 0=NHWC8 bf16 (+act), 1=NHWC8 f32 += (v*es+eb)*att,
//           2=NHWC8 bf16 resid + lrelu(v)*es, 3=planar f32 (+act).
// ---------------------------------------------------------------------------
template <int CPB>
__global__ void __launch_bounds__(256, 2)
conv_mfma(const bf16* __restrict__ src,
          const bf16* __restrict__ wp,
          const void* __restrict__ bias,
          void* __restrict__ dst, int dst_kind, int act,
          const bf16* __restrict__ resid,
          const float* __restrict__ att,
          const void* __restrict__ es_ptr, const void* __restrict__ eb_ptr,
          int e_idx,
          const int* __restrict__ dflag,
          int B, int Cin, int Cout, int H, int W, int up,
          int cog_blocks,
          int src_row0, int src_rows, int dst_row0, int dst_rows_buf,
          int dst_y0, int dst_rows)
{
    __shared__ __align__(16) bf16 sI[2 * 324 * 32];   // 41,472 B

    const int ef = dflag[0];
    const int ccs  = Cin >> 5;
    const int cogs = (Cout + 15) >> 4;
    const int CGi = Cin >> 3;
    const int CGo = Cout >> 3;
    const int tilesX = W >> 4;
    const int tilesY = dst_rows >> 4;
    const int inW = up ? (W >> 1) : W;

    int bid = blockIdx.x;
    const int cogb = bid % cog_blocks; bid /= cog_blocks;
    const int tx = bid % tilesX; bid /= tilesX;
    const int ty = bid % tilesY;
    const int b  = bid / tilesY;
    const int cog0 = cogb * CPB;

    const int tid = threadIdx.x;
    const int wave = tid >> 6, lane = tid & 63;
    const int n = lane & 15, q = lane >> 4;
    const int yb = dst_y0 + ty * 16, xb = tx * 16;
    const int r0w = wave * 4;

    int cb[3];
#pragma unroll
    for (int d = 0; d < 3; ++d) {
        const int tc = n + d;
        cb[d] = tc * 32 + ((q ^ ((tc >> 1) & 3)) << 3);
    }

    ffrag_t acc[CPB][4];
#pragma unroll
    for (int c = 0; c < CPB; ++c)
#pragma unroll
        for (int g = 0; g < 4; ++g) acc[c][g] = (ffrag_t){0.f, 0.f, 0.f, 0.f};

    for (int cc0 = 0; cc0 < ccs; cc0 += 2) {
        const int ncc = (ccs - cc0 < 2) ? (ccs - cc0) : 2;

        // ---- stage [cc0, cc0+ncc) : coalesced 16B granule loads ----
        {
            const int items = ncc * 4 * 324;
            for (int i = tid; i < items; i += 256) {
                const int pc = i % 324;
                const int gi = i / 324;
                const int lc = gi >> 2, cig = gi & 3;
                const int trow = pc / 18, tcol = pc % 18;
                const int iy = yb + trow - 1, ix = xb + tcol - 1;
                PackU p;
                if (iy >= 0 && iy < H && ix >= 0 && ix < W) {
                    const int sy = up ? (iy >> 1) : iy;
                    const int sx = up ? (ix >> 1) : ix;
                    const long gidx = ((((long)b * CGi + (long)(cc0 + lc) * 4 + cig) * src_rows
                                       + (sy - src_row0)) * inW + sx) << 3;
                    p.v = *(const bfrag_t*)&src[gidx];
                } else {
#pragma unroll
                    for (int j = 0; j < 8; ++j) p.b[j] = f2b(0.0f);
                }
                *(bfrag_t*)&sI[(lc * 324 + pc) * 32 + ((cig ^ ((tcol >> 1) & 3)) << 3)] = p.v;
            }
        }
        __syncthreads();

        for (int lc = 0; lc < ncc; ++lc) {
            // hoisted B-fragments (shared across all CPB cogs)
            bfrag_t bfr[6][3];
#pragma unroll
            for (int rr = 0; rr < 6; ++rr) {
                const int base = (lc * 324 + (r0w + rr) * 18) * 32;
#pragma unroll
                for (int d = 0; d < 3; ++d)
                    bfr[rr][d] = *(const bfrag_t*)&sI[base + cb[d]];
            }
            const int cc = cc0 + lc;
#pragma unroll
            for (int c = 0; c < CPB; ++c) {
                const int cog = cog0 + c;
                if (cog >= cogs) break;
                const bf16* wbase = wp + ((long)cog * ccs + cc) * 9 * 512 + n * 32 + q * 8;
#pragma unroll
                for (int tap = 0; tap < 9; ++tap) {
                    const bfrag_t a = *(const bfrag_t*)&wbase[(long)tap * 512];
                    const int dy = tap / 3, dxi = tap % 3;
#pragma unroll
                    for (int g = 0; g < 4; ++g)
                        acc[c][g] = __builtin_amdgcn_mfma_f32_16x16x32_bf16(
                            a, bfr[g + dy][dxi], acc[c][g], 0, 0, 0);
                }
            }
        }
        __syncthreads();
    }

    // ---- epilogue ----
    const float es  = es_ptr ? eload(es_ptr, e_idx, ef) : 1.0f;
    const float ebv = eb_ptr ? eload(eb_ptr, e_idx, ef) : 0.0f;
    const int x = xb + n;
#pragma unroll
    for (int c = 0; c < CPB; ++c) {
        const int cog = cog0 + c;
        if (cog >= cogs) break;
        if (dst_kind == 3) {
#pragma unroll
            for (int g = 0; g < 4; ++g) {
                const int y = yb + r0w + g, yr = y - dst_row0;
#pragma unroll
                for (int reg = 0; reg < 4; ++reg) {
                    const int co = cog * 16 + q * 4 + reg;
                    if (co < Cout) {
                        float v = acc[c][g][reg];
                        if (bias) v += eload(bias, co, ef);
                        if (act) v = LRELU(v);
                        ((float*)dst)[(((long)b * Cout + co) * dst_rows_buf + yr) * W + x] = v;
                    }
                }
            }
            continue;
        }
        const int cg = cog * 2 + (q >> 1);
        const int c8 = (q & 1) * 4;
        float bv[4];
#pragma unroll
        for (int reg = 0; reg < 4; ++reg)
            bv[reg] = bias ? eload(bias, cog * 16 + q * 4 + reg, ef) : 0.0f;
#pragma unroll
        for (int g = 0; g < 4; ++g) {
            const int y = yb + r0w + g, yr = y - dst_row0;
            const long base = ((((long)b * CGo + cg) * dst_rows_buf + yr) * W + x) * 8 + c8;
            if (dst_kind == 0) {
                BfPack o;
#pragma unroll
                for (int reg = 0; reg < 4; ++reg) {
                    float v = acc[c][g][reg] + bv[reg];
                    if (act) v = LRELU(v);
                    o.h[reg] = f2b(v);
                }
                *(short4*)&((bf16*)dst)[base] = o.s;
            } else if (dst_kind == 1) {
                const float attv = att[(((long)b * 8 + e_idx) * H + y) * W + x];
                float* dp = (float*)dst + base;
                float4 dv = *(float4*)dp;
                dv.x += ((acc[c][g][0] + bv[0]) * es + ebv) * attv;
                dv.y += ((acc[c][g][1] + bv[1]) * es + ebv) * attv;
                dv.z += ((acc[c][g][2] + bv[2]) * es + ebv) * attv;
                dv.w += ((acc[c][g][3] + bv[3]) * es + ebv) * attv;
                *(float4*)dp = dv;
            } else {
                BfPack rv; rv.s = *(const short4*)&resid[base];
                BfPack o;
#pragma unroll
                for (int reg = 0; reg < 4; ++reg) {
                    const float v = acc[c][g][reg] + bv[reg];
                    o.h[reg] = f2b(b2f(rv.h[reg]) + LRELU(v) * es);
                }
                *(short4*)&((bf16*)dst)[base] = o.s;
            }
        }
    }
}

// ---------------------------------------------------------------------------
// init conv: planar ext x [b0+b][3][64][64] -> NHWC8 x0, Cout=64
// ---------------------------------------------------------------------------
__global__ void __launch_bounds__(256)
conv_init_kernel(const void* __restrict__ src, const void* __restrict__ wgt,
                 const void* __restrict__ bias, bf16* __restrict__ dst,
                 const int* __restrict__ dflag, int b_off, int B)
{
    __shared__ float slds[3 * 34 * 36];
    __shared__ float wlds[3 * 16 * 12];
    const int ef = dflag[0];

    int bid = blockIdx.x;
    const int coI = bid & 3; bid >>= 2;
    const int tx = bid & 1; bid >>= 1;
    const int ty = bid & 1; bid >>= 1;
    const int b = bid;
    const int co0 = coI * 16;
    const int tid = threadIdx.x;
    const int wave = tid >> 6, lane = tid & 63;
    const int ty4 = lane >> 3, tx4 = lane & 7;
    const int yb = ty * 32, xb = tx * 32;

    for (int i = tid; i < 34 * 34 * 3; i += 256) {
        const int c = i / 1156, p = i % 1156;
        const int row = p / 34, col = p % 34;
        const int iy = yb + row - 1, ix = xb + col - 1;
        float v = 0.f;
        if (iy >= 0 && iy < 64 && ix >= 0 && ix < 64)
            v = eload(src, ((long)(b_off + b) * 3 + c) * 4096 + iy * 64 + ix, ef);
        slds[(c * 34 + row) * 36 + col] = v;
    }
    for (int i = tid; i < 3 * 144; i += 256) {
        const int ci = i / 144, r = i % 144;
        const int co = r / 9, k = r % 9;
        wlds[(ci * 16 + co) * 12 + k] = eload(wgt, ((long)(co0 + co) * 3 + ci) * 9 + k, ef);
    }
    __syncthreads();

    float acc[4][16];
#pragma unroll
    for (int i = 0; i < 4; ++i)
#pragma unroll
        for (int j = 0; j < 16; ++j) acc[i][j] = 0.f;

    for (int ci = 0; ci < 3; ++ci) {
        float in[6][6];
        const float* sp = &slds[(ci * 34 + ty4 * 4) * 36 + tx4 * 4];
#pragma unroll
        for (int r = 0; r < 6; ++r) {
            const float4 v4 = *(const float4*)(sp + r * 36);
            const float2 v2 = *(const float2*)(sp + r * 36 + 4);
            in[r][0] = v4.x; in[r][1] = v4.y; in[r][2] = v4.z; in[r][3] = v4.w;
            in[r][4] = v2.x; in[r][5] = v2.y;
        }
#pragma unroll
        for (int cc = 0; cc < 4; ++cc) {
            const float* wp = &wlds[(ci * 16 + wave * 4 + cc) * 12];
            const float4 wa = *(const float4*)wp;
            const float4 wb = *(const float4*)(wp + 4);
            const float w8 = wp[8];
#pragma unroll
            for (int r = 0; r < 4; ++r)
#pragma unroll
                for (int c = 0; c < 4; ++c)
                    acc[cc][r * 4 + c] += in[r][c] * wa.x + in[r][c+1] * wa.y + in[r][c+2] * wa.z
                        + in[r+1][c] * wa.w + in[r+1][c+1] * wb.x + in[r+1][c+2] * wb.y
                        + in[r+2][c] * wb.z + in[r+2][c+1] * wb.w + in[r+2][c+2] * w8;
        }
    }

    const int cg = coI * 2 + (wave >> 1);
    const int c8 = (wave & 1) * 4;
    float bv[4];
#pragma unroll
    for (int cc = 0; cc < 4; ++cc)
        bv[cc] = bias ? eload(bias, co0 + wave * 4 + cc, ef) : 0.0f;
#pragma unroll
    for (int r = 0; r < 4; ++r) {
        const int y = yb + ty4 * 4 + r;
#pragma unroll
        for (int c = 0; c < 4; ++c) {
            const int x = xb + tx4 * 4 + c;
            BfPack o;
#pragma unroll
            for (int cc = 0; cc < 4; ++cc)
                o.h[cc] = f2b(acc[cc][r * 4 + c] + bv[cc]);
            *(short4*)&dst[((((long)b * 8 + cg) * 64 + y) * 64 + x) * 8 + c8] = o.s;
        }
    }
}

// ---------------------------------------------------------------------------
__global__ void __launch_bounds__(256)
gn_silu_kernel(bf16* __restrict__ d, const void* __restrict__ g,
               const void* __restrict__ be, const int* __restrict__ dflag,
               int C, int gsize, int HW)
{
    const int ef = dflag[0];
    const int groups = C / gsize;
    const int blk = blockIdx.x;
    const int b  = blk / groups;
    const int gr = blk % groups;
    const long base = ((long)b * (C >> 3) + (long)gr * (gsize >> 3)) * HW * 8;
    const int N = gsize * HW;

    float s = 0.0f, ss = 0.0f;
    for (int i = threadIdx.x; i < N; i += 256) {
        const float v = b2f(d[base + i]);
        s += v; ss += v * v;
    }
    __shared__ float rs[256], rss[256];
    rs[threadIdx.x] = s; rss[threadIdx.x] = ss;
    __syncthreads();
    for (int o = 128; o > 0; o >>= 1) {
        if (threadIdx.x < o) {
            rs[threadIdx.x]  += rs[threadIdx.x + o];
            rss[threadIdx.x] += rss[threadIdx.x + o];
        }
        __syncthreads();
    }
    __shared__ float mean_s, inv_s;
    if (threadIdx.x == 0) {
        const float mean = rs[0] / (float)N;
        const float var  = rss[0] / (float)N - mean * mean;
        mean_s = mean; inv_s = rsqrtf(var + 1e-5f);
    }
    __syncthreads();
    const float mean = mean_s, inv = inv_s;
    for (int i = threadIdx.x; i < N; i += 256) {
        const int c = gr * gsize + (i / (HW * 8)) * 8 + (i & 7);
        const float v  = b2f(d[base + i]);
        const float xn = (v - mean) * inv * eload(g, c, ef) + eload(be, c, ef);
        d[base + i] = f2b(xn / (1.0f + expf(-xn)));
    }
}

__global__ void __launch_bounds__(256)
softmax_t_kernel(float* __restrict__ m, int BHW, int HW, float invtemp)
{
    const int i = blockIdx.x * 256 + threadIdx.x;
    if (i >= BHW) return;
    const int b = i / HW;
    const int p = i % HW;
    const long base = (long)b * 8 * HW + p;
    float v[8];
    float mx = -1e30f;
#pragma unroll
    for (int t = 0; t < 8; ++t) {
        v[t] = m[base + (long)t * HW] * invtemp;
        mx = fmaxf(mx, v[t]);
    }
    float s = 0.0f;
#pragma unroll
    for (int t = 0; t < 8; ++t) { v[t] = expf(v[t] - mx); s += v[t]; }
    const float r = 1.0f / s;
#pragma unroll
    for (int t = 0; t < 8; ++t) m[base + (long)t * HW] = v[t] * r;
}

__global__ void __launch_bounds__(256)
combine_kernel(const bf16* __restrict__ x0, const float* __restrict__ acc,
               const void* __restrict__ ss, const int* __restrict__ dflag,
               bf16* __restrict__ out, long n)
{
    const long i = (long)blockIdx.x * 256 + threadIdx.x;
    if (i < n) out[i] = f2b(b2f(x0[i]) + acc[i] * eload(ss, 0, dflag[0]));
}

__global__ void __launch_bounds__(256)
zero_kernel(float* __restrict__ p, long n)
{
    const long i = (long)blockIdx.x * 256 + threadIdx.x;
    if (i < n) p[i] = 0.0f;
}

// ---------------------------------------------------------------------------
static const int* g_dflag;

static void conv2w(hipStream_t st, const bf16* src, const bf16* wp,
                   const void* bias, void* dst, int dst_kind, int act,
                   int B, int Cin, int Cout, int H, int W, int up,
                   int src_row0, int src_rows, int dst_row0, int dst_rows_buf,
                   int dst_y0, int dst_rows,
                   const bf16* resid = nullptr, const float* att = nullptr,
                   const void* es = nullptr, const void* eb = nullptr, int eidx = 0)
{
    const int cogs = (Cout + 15) >> 4;
    const int spatial = B * (dst_rows >> 4) * (W >> 4);
    // pick CPB: among {6,4,3,2,1} (<=cogs) meeting spatial*cogb>=512, take the
    // one with fewest cog blocks (least staging); tie-break balanced/larger CPB.
    static const int cands[5] = {6, 4, 3, 2, 1};
    int cpb = 1, cogb = cogs, best_gb = 1 << 30, have = 0;
    for (int k = 0; k < 5; ++k) {
        const int c = cands[k];
        if (c > cogs) continue;
        const int gb = (cogs + c - 1) / c;
        const bool ok = (long)spatial * gb >= 512;
        if (ok) {
            const bool bal = (cogs % c) == 0;
            if (gb < best_gb || (gb == best_gb && bal && have == 0)) {
                cpb = c; cogb = gb; best_gb = gb; have = bal ? 1 : have;
            }
        }
    }
    if (best_gb == (1 << 30)) { cpb = 1; cogb = cogs; }   // tiny spatial: max blocks
    const int blocks = spatial * cogb;
#define LAUNCH(CP) conv_mfma<CP><<<blocks, 256, 0, st>>>( \
        src, wp, bias, dst, dst_kind, act, resid, att, es, eb, eidx, g_dflag, \
        B, Cin, Cout, H, W, up, cogb, \
        src_row0, src_rows, dst_row0, dst_rows_buf, dst_y0, dst_rows)
    switch (cpb) {
        case 6: LAUNCH(6); break;
        case 4: LAUNCH(4); break;
        case 3: LAUNCH(3); break;
        case 2: LAUNCH(2); break;
        default: LAUNCH(1); break;
    }
#undef LAUNCH
}

static void conv2(hipStream_t st, const bf16* src, const bf16* wp,
                  const void* bias, void* dst, int dst_kind, int act,
                  int B, int Cin, int Cout, int H, int W, int up,
                  const bf16* resid = nullptr, const float* att = nullptr,
                  const void* es = nullptr, const void* eb = nullptr, int eidx = 0)
{
    conv2w(st, src, wp, bias, dst, dst_kind, act, B, Cin, Cout, H, W, up,
           0, up ? (H >> 1) : H, 0, H, 0, H, resid, att, es, eb, eidx);
}

static long wp_elems(int T, int Cout, int Cin)
{
    return (long)T * ((Cout + 15) / 16) * (Cin / 32) * 9 * 512;
}

extern "C" void kernel_launch(void* const* d_in, const int* in_sizes, int n_in,
                              void* d_out, int out_size, void* d_ws, size_t ws_size,
                              hipStream_t stream)
{
    const void* x_all   = d_in[0];
    const void* sp_all  = d_in[1];
    const void* nz_all  = d_in[2];
    const void* init_w  = d_in[3];
    const void* init_b  = d_in[4];
    const void* pre_w   = d_in[5];
    const void* tw0     = d_in[6];
    const void* tw1     = d_in[7];
    const void* tw2     = d_in[8];
    const void* tw3     = d_in[9];
    const void* tscale  = d_in[10];
    const void* tbias   = d_in[11];
    const void* nscale  = d_in[12];
    const void* sscale  = d_in[13];
    const void* pscale  = d_in[14];
    const void* post_w  = d_in[15];
    const void* post_b  = d_in[16];
    const void* m1_w    = d_in[17];
    const void* m1_b    = d_in[18];
    const void* m1_g    = d_in[19];
    const void* m1_be   = d_in[20];
    const void* m2_w    = d_in[21];
    const void* m2_g    = d_in[22];
    const void* m2_be   = d_in[23];
    const void* u1a_w   = d_in[24];
    const void* u1b_w   = d_in[25];
    const void* u1b_g   = d_in[26];
    const void* u1b_be  = d_in[27];
    const void* u2a_w   = d_in[28];
    const void* u2b_w   = d_in[29];
    const void* u2b_g   = d_in[30];
    const void* u2b_be  = d_in[31];
    const void* mf_w    = d_in[32];
    const void* up1_w   = d_in[33];
    const void* up1_b   = d_in[34];
    const void* up2_w   = d_in[35];
    const void* up2_b   = d_in[36];
    const void* hr_w    = d_in[37];
    const void* hr_b    = d_in[38];
    const void* fin_w   = d_in[39];
    const void* fin_b   = d_in[40];
    (void)in_sizes; (void)n_in; (void)out_size;

    char* wsb = (char*)d_ws;
    int* dflag = (int*)wsb;
    g_dflag = dflag;
    dtype_detect_kernel<<<1, 64, 0, stream>>>(tw1, 128, dflag);

    // ---- prepped-weight region ----
    bf16* WP = (bf16*)(wsb + 256);
    long off = 0;
    WTab tab; tab.n = 0;
    auto alloc = [&](const void* w, int T, int Cout, int Cin) {
        long o = off;
        long tot = wp_elems(T, Cout, Cin);
        tab.e[tab.n++] = WEnt{w, o, tot, Cout, Cin};
        off += tot;
        return o;
    };
    const long o_m1  = alloc(m1_w, 1, 256, 256);
    const long o_m2  = alloc(m2_w, 1, 256, 256);
    const long o_u1a = alloc(u1a_w, 1, 128, 256);
    const long o_u1b = alloc(u1b_w, 1, 128, 128);
    const long o_u2a = alloc(u2a_w, 1, 64, 128);
    const long o_u2b = alloc(u2b_w, 1, 64, 64);
    const long o_mf  = alloc(mf_w, 1, 8, 64);
    const long o_pre = alloc(pre_w, 1, 64, 64);
    const long o_tw0 = alloc(tw0, 8, 96, 64);
    const long o_tw1 = alloc(tw1, 8, 96, 96);
    const long o_tw2 = alloc(tw2, 8, 96, 96);
    const long o_tw3 = alloc(tw3, 8, 64, 96);
    const long o_post = alloc(post_w, 1, 64, 64);
    const long o_up1 = alloc(up1_w, 1, 64, 64);
    const long o_up2 = alloc(up2_w, 1, 64, 64);
    const long o_hr  = alloc(hr_w, 1, 64, 64);
    const long o_fin = alloc(fin_w, 1, 3, 64);
    const long wp_total = off;
    const size_t wp_bytes = (size_t)((wp_total * 2 + 255) & ~255L);

    wprep_all_kernel<<<1024, 256, 0, stream>>>(tab, dflag, WP);

    const long pt_tw0 = wp_elems(1, 96, 64), pt_tw1 = wp_elems(1, 96, 96);
    const long pt_tw3 = wp_elems(1, 64, 96);

    // ---- schedule: batch chunk bc, tail strip S ----
    int bc = 1, S = 16, tc = 1;
    for (int c = 16; c >= 1; c >>= 1) {
        const size_t fixed = 256u + wp_bytes + (size_t)c * 1703936u;
        if (ws_size < fixed) continue;
        const size_t rem = ws_size - fixed;
        if (rem < (size_t)c * 2621440u) continue;
        if (rem >= 18874368u) {
            bc = c; S = 256;
            tc = (int)(rem / 18874368u); if (tc > c) tc = c;
            break;
        } else if (rem >= 9437184u)  { bc = c; S = 64; tc = 1; break; }
        else if (rem >= 7340032u)    { bc = c; S = 32; tc = 1; break; }
        else if (rem >= 6291456u)    { bc = c; S = 16; tc = 1; break; }
    }

    char* dyn = wsb + 256 + wp_bytes;
    float* M    = (float*)dyn;                                   // bc*32768 f32
    float* ACC  = (float*)(dyn + (size_t)bc * 131072u);          // bc*262144 f32
    bf16*  OUT2 = (bf16*)(dyn + (size_t)bc * 1179648u);          // bc*262144 bf16
    bf16*  A    = (bf16*)(dyn + (size_t)bc * 1703936u);          // arena

    for (int b0 = 0; b0 < 16; b0 += bc) {
        float* outp = (float*)d_out + (size_t)b0 * 3 * 65536;

        // ---- phase 1: multiplexer ----
        bf16* SP8 = A;
        bf16* f1 = A + (size_t)bc * 65536;
        bf16* f2 = A + (size_t)bc * 131072;
        bf16* g1 = A + (size_t)bc * 196608;
        bf16* g2 = A + (size_t)bc * 327680;
        bf16* h1 = A + (size_t)bc * 458752;
        bf16* h2 = A + (size_t)bc * 720896;

        {
            const long n = (long)bc * 65536;
            to_nhwc8_kernel<<<1024, 256, 0, stream>>>(sp_all, dflag, SP8, b0, 256, 256, n);
        }
        conv2(stream, SP8, WP + o_m1, m1_b, f1, 0, 0, bc, 256, 256, 16, 16, 0);
        gn_silu_kernel<<<bc * 8, 256, 0, stream>>>(f1, m1_g, m1_be, dflag, 256, 32, 256);
        conv2(stream, f1, WP + o_m2, nullptr, f2, 0, 0, bc, 256, 256, 16, 16, 0);
        gn_silu_kernel<<<bc * 8, 256, 0, stream>>>(f2, m2_g, m2_be, dflag, 256, 32, 256);
        conv2(stream, f2, WP + o_u1a, nullptr, g1, 0, 0, bc, 256, 128, 32, 32, 1);
        conv2(stream, g1, WP + o_u1b, nullptr, g2, 0, 0, bc, 128, 128, 32, 32, 0);
        gn_silu_kernel<<<bc * 8, 256, 0, stream>>>(g2, u1b_g, u1b_be, dflag, 128, 16, 1024);
        conv2(stream, g2, WP + o_u2a, nullptr, h1, 0, 0, bc, 128, 64, 64, 64, 1);
        conv2(stream, h1, WP + o_u2b, nullptr, h2, 0, 0, bc, 64, 64, 64, 64, 0);
        gn_silu_kernel<<<bc * 8, 256, 0, stream>>>(h2, u2b_g, u2b_be, dflag, 64, 8, 4096);
        conv2(stream, h2, WP + o_mf, nullptr, M, 3, 0, bc, 64, 8, 64, 64, 0);
        softmax_t_kernel<<<(bc * 4096 + 255) / 256, 256, 0, stream>>>(
            M, bc * 4096, 4096, 1.0f / 20.0f);

        // ---- phase 2: stem + branches ----
        bf16* x0   = A;
        bf16* xsp  = A + (size_t)bc * 262144;
        bf16* ping = A + (size_t)bc * 524288;
        bf16* pong = A + (size_t)bc * 917504;

        conv_init_kernel<<<bc * 16, 256, 0, stream>>>(x_all, init_w, init_b, x0,
                                                      dflag, b0, bc);
        {
            const long n = (long)bc * 262144;
            addnoise_kernel<<<1024, 256, 0, stream>>>(x0, nz_all, nscale, dflag,
                                                      ping, b0, n);
        }
        conv2(stream, ping, WP + o_pre, nullptr, xsp, 0, 0, bc, 64, 64, 64, 64, 0);

        const long accn = (long)bc * 262144;
        zero_kernel<<<(int)((accn + 255) / 256), 256, 0, stream>>>(ACC, accn);

        for (int t = 0; t < 8; ++t) {
            conv2(stream, xsp,  WP + o_tw0 + t * pt_tw0, nullptr, ping, 0, 1,
                  bc, 64, 96, 64, 64, 0);
            conv2(stream, ping, WP + o_tw1 + t * pt_tw1, nullptr, pong, 0, 1,
                  bc, 96, 96, 64, 64, 0);
            conv2(stream, pong, WP + o_tw2 + t * pt_tw1, nullptr, ping, 0, 1,
                  bc, 96, 96, 64, 64, 0);
            conv2(stream, ping, WP + o_tw3 + t * pt_tw3, nullptr, ACC, 1, 0,
                  bc, 96, 64, 64, 64, 0, nullptr, M, tscale, tbias, t);
        }

        bf16* outc = xsp;
        combine_kernel<<<(int)((accn + 255) / 256), 256, 0, stream>>>(
            x0, ACC, sscale, dflag, outc, accn);

        conv2(stream, outc, WP + o_post, post_b, OUT2, 2, 0, bc, 64, 64, 64, 64, 0,
              outc, nullptr, pscale, nullptr, 0);

        // ---- phase 3: tail ----
        if (S == 256) {
            bf16* a1 = A;
            bf16* a2 = A + (size_t)tc * 1048576;
            bf16* a3 = A + (size_t)tc * 5242880;
            for (int s0 = 0; s0 < bc; s0 += tc) {
                const int cur = (tc < bc - s0) ? tc : (bc - s0);
                const bf16* src_c = OUT2 + (size_t)s0 * 262144;
                float* out_c = outp + (size_t)s0 * 3 * 65536;
                conv2(stream, src_c, WP + o_up1, up1_b, a1, 0, 1, cur, 64, 64, 128, 128, 1);
                conv2(stream, a1,   WP + o_up2, up2_b, a2, 0, 1, cur, 64, 64, 256, 256, 1);
                conv2(stream, a2,   WP + o_hr,  hr_b,  a3, 0, 1, cur, 64, 64, 256, 256, 0);
                conv2(stream, a3,   WP + o_fin, fin_b, out_c, 3, 0, cur, 64, 3, 256, 256, 0);
            }
        } else {
            bf16* a1  = A;
            bf16* a2s = A + 1048576;
            bf16* a3s = a2s + (size_t)(S + 64) * 16384;
            for (int i = 0; i < bc; ++i) {
                const bf16* src_i = OUT2 + (size_t)i * 262144;
                float* out_i = outp + (size_t)i * 3 * 65536;
                conv2(stream, src_i, WP + o_up1, up1_b, a1, 0, 1, 1, 64, 64, 128, 128, 1);
                for (int r0 = 0; r0 < 256; r0 += S) {
                    const int r1 = r0 + S;
                    const int w2a = (r0 - 32 > 0) ? r0 - 32 : 0;
                    const int w2b = (r1 + 32 < 256) ? r1 + 32 : 256;
                    const int w3a = (r0 - 16 > 0) ? r0 - 16 : 0;
                    const int w3b = (r1 + 16 < 256) ? r1 + 16 : 256;
                    conv2w(stream, a1, WP + o_up2, up2_b, a2s, 0, 1,
                           1, 64, 64, 256, 256, 1,
                           0, 128, w2a, w2b - w2a, w2a, w2b - w2a);
                    conv2w(stream, a2s, WP + o_hr, hr_b, a3s, 0, 1,
                           1, 64, 64, 256, 256, 0,
                           w2a, w2b - w2a, w3a, w3b - w3a, w3a, w3b - w3a);
                    conv2w(stream, a3s, WP + o_fin, fin_b, out_i, 3, 0,
                           1, 64, 3, 256, 256, 0,
                           w3a, w3b - w3a, 0, 256, r0, S);
                }
            }
        }
    }
}

// Round 12
// 1697.800 us; speedup vs baseline: 17.1716x; 1.0382x over previous
//
#include <hip/hip_runtime.h>
#include <hip/hip_bf16.h>
#include <math.h>

typedef __hip_bfloat16 bf16;

#define LRELU(v) ((v) >= 0.f ? (v) : 0.2f * (v))

__device__ __forceinline__ float b2f(bf16 v) { return __bfloat162float(v); }
__device__ __forceinline__ bf16 f2b(float v) { return __float2bfloat16(v); }

__device__ __forceinline__ float eload(const void* p, long i, int isf32)
{
    return isf32 ? ((const float*)p)[i] : b2f(((const bf16*)p)[i]);
}

union BfPack { short4 s; bf16 h[4]; };
typedef __attribute__((ext_vector_type(8))) short bfrag_t;   // 8 bf16
typedef __attribute__((ext_vector_type(4))) float ffrag_t;   // 4 f32 acc
union PackU { bfrag_t v; bf16 b[8]; };

// ---------------------------------------------------------------------------
__global__ void dtype_detect_kernel(const void* probe, int n, int* flag)
{
    if (threadIdx.x == 0 && blockIdx.x == 0) {
        const bf16* e = (const bf16*)probe;
        int f32 = 0;
        for (int i = 0; i < n; ++i) {
            const float v = b2f(e[i]);
            if (!(v > -1.0f && v < 1.0f)) f32 = 1;
        }
        *flag = f32;
    }
}

// planar external [b0+b][C][HW] -> NHWC8 bf16 [b][C/8][HW][8]
__global__ void __launch_bounds__(256)
to_nhwc8_kernel(const void* __restrict__ src, const int* __restrict__ dflag,
                bf16* __restrict__ out, int b_off, int C, int HW, long n)
{
    const int ef = dflag[0];
    const int CG = C >> 3;
    for (long i = (long)blockIdx.x * 256 + threadIdx.x; i < n;
         i += (long)gridDim.x * 256) {
        const int c8 = (int)(i & 7);
        long r = i >> 3;
        const int p = (int)(r % HW); r /= HW;
        const int cg = (int)(r % CG);
        const int b = (int)(r / CG);
        out[i] = f2b(eload(src, ((long)(b_off + b) * C + cg * 8 + c8) * HW + p, ef));
    }
}

// xs(NHWC8) = x0(NHWC8) + ns * noise(planar ext), C=64, HW=4096
__global__ void __launch_bounds__(256)
addnoise_kernel(const bf16* __restrict__ x0, const void* __restrict__ noise,
                const void* __restrict__ ns_ptr, const int* __restrict__ dflag,
                bf16* __restrict__ out, int b_off, long n)
{
    const int ef = dflag[0];
    const float ns = eload(ns_ptr, 0, ef);
    for (long i = (long)blockIdx.x * 256 + threadIdx.x; i < n;
         i += (long)gridDim.x * 256) {
        const int c8 = (int)(i & 7);
        long r = i >> 3;
        const int p = (int)(r % 4096); r /= 4096;
        const int cg = (int)(r % 8);
        const int b = (int)(r / 8);
        out[i] = f2b(b2f(x0[i]) +
                     ns * eload(noise, ((long)(b_off + b) * 64 + cg * 8 + c8) * 4096 + p, ef));
    }
}

// ---------------------------------------------------------------------------
// single-launch weight prep: external [t][co][ci][3][3] ->
//   wp[t][cog][cc][tap][co16][ci32] bf16 (A-fragment-ready, zero-pad co)
// ---------------------------------------------------------------------------
struct WEnt { const void* src; long dst_off; long total; int Cout; int Cin; };
struct WTab { WEnt e[17]; int n; };

__global__ void __launch_bounds__(256)
wprep_all_kernel(WTab tab, const int* __restrict__ dflag, bf16* __restrict__ out)
{
    const int ef = dflag[0];
    for (int k = 0; k < tab.n; ++k) {
        const WEnt E = tab.e[k];
        const int cogs = (E.Cout + 15) >> 4, ccs = E.Cin >> 5;
        const long src_t = (long)E.Cout * E.Cin * 9;
        for (long i = (long)blockIdx.x * 256 + threadIdx.x; i < E.total;
             i += (long)gridDim.x * 256) {
            const int e = (int)(i & 511);
            long r = i >> 9;
            const int tap = (int)(r % 9); r /= 9;
            const int cc = (int)(r % ccs); r /= ccs;
            const int cog = (int)(r % cogs);
            const int t = (int)(r / cogs);
            const int nn = e >> 5, kk = e & 31;
            const int co = cog * 16 + nn, ci = cc * 32 + kk;
            float v = 0.f;
            if (co < E.Cout)
                v = eload(E.src, (long)t * src_t + ((long)co * E.Cin + ci) * 9 + tap, ef);
            out[E.dst_off + i] = f2b(v);
        }
    }
}

// ---------------------------------------------------------------------------
// MFMA implicit-GEMM 3x3 conv, NHWC8 src, prepped weights.
// Tile 16x16 px; block handles CPB consecutive cogs (CPB | cogs guaranteed).
// Single-cc-chunk LDS (20.7 KB -> high blocks/CU); dx-outer compute keeps only
// 6 B-fragments live (low VGPR) while sharing them across all CPB cogs.
// img_per_t>0: per-image-group weights (merged branches), weight idx = b/img_per_t.
// src_bmod>0: src image index = b % src_bmod (shared-input merged conv).
// dst_kind: 0=NHWC8 bf16 (+act), 1=NHWC8 f32 += (v*es[e]+eb[e])*att,
//           2=NHWC8 bf16 resid + lrelu(v)*es[0], 3=planar f32 (+act).
// ---------------------------------------------------------------------------
template <int CPB>
__global__ void __launch_bounds__(256)
conv_mfma(const bf16* __restrict__ src,
          const bf16* __restrict__ wp,
          const void* __restrict__ bias,
          void* __restrict__ dst, int dst_kind, int act,
          const bf16* __restrict__ resid,
          const float* __restrict__ att,
          const void* __restrict__ es_ptr, const void* __restrict__ eb_ptr,
          int e_idx,
          const int* __restrict__ dflag,
          int B, int Cin, int Cout, int H, int W, int up,
          int cog_blocks,
          int src_row0, int src_rows, int dst_row0, int dst_rows_buf,
          int dst_y0, int dst_rows,
          int img_per_t, long wstride, int src_bmod)
{
    __shared__ __align__(16) bf16 sI[324 * 32];   // 20,736 B

    const int ef = dflag[0];
    const int ccs  = Cin >> 5;
    const int cogs = (Cout + 15) >> 4;
    const int CGi = Cin >> 3;
    const int CGo = Cout >> 3;
    const int tilesX = W >> 4;
    const int tilesY = dst_rows >> 4;
    const int inW = up ? (W >> 1) : W;

    int bid = blockIdx.x;
    const int cogb = bid % cog_blocks; bid /= cog_blocks;
    const int tx = bid % tilesX; bid /= tilesX;
    const int ty = bid % tilesY;
    const int b  = bid / tilesY;
    const int cog0 = cogb * CPB;
    const int sbi = src_bmod ? (b % src_bmod) : b;
    const bf16* wpb = wp + (img_per_t ? (long)(b / img_per_t) * wstride : 0);

    const int tid = threadIdx.x;
    const int wave = tid >> 6, lane = tid & 63;
    const int n = lane & 15, q = lane >> 4;
    const int yb = dst_y0 + ty * 16, xb = tx * 16;
    const int r0w = wave * 4;

    int cb[3];
#pragma unroll
    for (int d = 0; d < 3; ++d) {
        const int tc = n + d;
        cb[d] = tc * 32 + ((q ^ ((tc >> 1) & 3)) << 3);
    }

    ffrag_t acc[CPB][4];
#pragma unroll
    for (int c = 0; c < CPB; ++c)
#pragma unroll
        for (int g = 0; g < 4; ++g) acc[c][g] = (ffrag_t){0.f, 0.f, 0.f, 0.f};

    for (int cc = 0; cc < ccs; ++cc) {
        // ---- stage one 32-ci chunk: 1296 coalesced 16B granule loads ----
        for (int i = tid; i < 1296; i += 256) {
            const int pc = i % 324;
            const int cig = i / 324;
            const int trow = pc / 18, tcol = pc % 18;
            const int iy = yb + trow - 1, ix = xb + tcol - 1;
            PackU p;
            if (iy >= 0 && iy < H && ix >= 0 && ix < W) {
                const int sy = up ? (iy >> 1) : iy;
                const int sx = up ? (ix >> 1) : ix;
                const long gidx = ((((long)sbi * CGi + (long)cc * 4 + cig) * src_rows
                                   + (sy - src_row0)) * inW + sx) << 3;
                p.v = *(const bfrag_t*)&src[gidx];
            } else {
#pragma unroll
                for (int j = 0; j < 8; ++j) p.b[j] = f2b(0.0f);
            }
            *(bfrag_t*)&sI[pc * 32 + ((cig ^ ((tcol >> 1) & 3)) << 3)] = p.v;
        }
        __syncthreads();

        // ---- compute: dx outer, 6 B-frags live, shared across CPB cogs ----
#pragma unroll
        for (int dx = 0; dx < 3; ++dx) {
            bfrag_t bcol[6];
#pragma unroll
            for (int rr = 0; rr < 6; ++rr)
                bcol[rr] = *(const bfrag_t*)&sI[(r0w + rr) * 18 * 32 + cb[dx]];
#pragma unroll
            for (int c = 0; c < CPB; ++c) {
                const bf16* wbase = wpb + ((long)(cog0 + c) * ccs + cc) * 9 * 512
                                  + n * 32 + q * 8;
#pragma unroll
                for (int dy = 0; dy < 3; ++dy) {
                    const bfrag_t a = *(const bfrag_t*)&wbase[(long)(dy * 3 + dx) * 512];
#pragma unroll
                    for (int g = 0; g < 4; ++g)
                        acc[c][g] = __builtin_amdgcn_mfma_f32_16x16x32_bf16(
                            a, bcol[g + dy], acc[c][g], 0, 0, 0);
                }
            }
        }
        __syncthreads();
    }

    // ---- epilogue ----
    const float es  = es_ptr ? eload(es_ptr, e_idx, ef) : 1.0f;
    const float ebv = eb_ptr ? eload(eb_ptr, e_idx, ef) : 0.0f;
    const int x = xb + n;
#pragma unroll
    for (int c = 0; c < CPB; ++c) {
        const int cog = cog0 + c;
        if (dst_kind == 3) {
#pragma unroll
            for (int g = 0; g < 4; ++g) {
                const int y = yb + r0w + g, yr = y - dst_row0;
#pragma unroll
                for (int reg = 0; reg < 4; ++reg) {
                    const int co = cog * 16 + q * 4 + reg;
                    if (co < Cout) {
                        float v = acc[c][g][reg];
                        if (bias) v += eload(bias, co, ef);
                        if (act) v = LRELU(v);
                        ((float*)dst)[(((long)b * Cout + co) * dst_rows_buf + yr) * W + x] = v;
                    }
                }
            }
            continue;
        }
        const int cg = cog * 2 + (q >> 1);
        const int c8 = (q & 1) * 4;
        float bv[4];
#pragma unroll
        for (int reg = 0; reg < 4; ++reg)
            bv[reg] = bias ? eload(bias, cog * 16 + q * 4 + reg, ef) : 0.0f;
#pragma unroll
        for (int g = 0; g < 4; ++g) {
            const int y = yb + r0w + g, yr = y - dst_row0;
            const long base = ((((long)b * CGo + cg) * dst_rows_buf + yr) * W + x) * 8 + c8;
            if (dst_kind == 0) {
                BfPack o;
#pragma unroll
                for (int reg = 0; reg < 4; ++reg) {
                    float v = acc[c][g][reg] + bv[reg];
                    if (act) v = LRELU(v);
                    o.h[reg] = f2b(v);
                }
                *(short4*)&((bf16*)dst)[base] = o.s;
            } else if (dst_kind == 1) {
                const float attv = att[(((long)b * 8 + e_idx) * H + y) * W + x];
                float* dp = (float*)dst + base;
                float4 dv = *(float4*)dp;
                dv.x += ((acc[c][g][0] + bv[0]) * es + ebv) * attv;
                dv.y += ((acc[c][g][1] + bv[1]) * es + ebv) * attv;
                dv.z += ((acc[c][g][2] + bv[2]) * es + ebv) * attv;
                dv.w += ((acc[c][g][3] + bv[3]) * es + ebv) * attv;
                *(float4*)dp = dv;
            } else {
                BfPack rv; rv.s = *(const short4*)&resid[base];
                BfPack o;
#pragma unroll
                for (int reg = 0; reg < 4; ++reg) {
                    const float v = acc[c][g][reg] + bv[reg];
                    o.h[reg] = f2b(b2f(rv.h[reg]) + LRELU(v) * es);
                }
                *(short4*)&((bf16*)dst)[base] = o.s;
            }
        }
    }
}

// ---------------------------------------------------------------------------
// ACC (+)= sum_t (xf[t] * tscale[t] + tbias[t]) * att[b,t,:]
// xf: NHWC8 bf16, images [ti*bc + b]; ACC: NHWC8 f32 over bc images.
// ---------------------------------------------------------------------------
__global__ void __launch_bounds__(256)
acc_att_kernel(const bf16* __restrict__ xf, const float* __restrict__ att,
               const void* __restrict__ ts, const void* __restrict__ tb,
               const int* __restrict__ dflag, float* __restrict__ ACC,
               int bc, int tcap, int tgrp, int init, long n)
{
    const int ef = dflag[0];
    for (long i = (long)blockIdx.x * 256 + threadIdx.x; i < n;
         i += (long)gridDim.x * 256) {
        long r = i >> 3;
        const int p = (int)(r % 4096); r /= 4096;
        r /= 8;                         // skip cg
        const int b = (int)r;
        float s = init ? 0.f : ACC[i];
        for (int ti = 0; ti < tcap; ++ti) {
            const int t = tgrp + ti;
            const float a = att[((long)b * 8 + t) * 4096 + p];
            const float v = b2f(xf[(long)ti * bc * 262144 + i]);
            s += (v * eload(ts, t, ef) + eload(tb, t, ef)) * a;
        }
        ACC[i] = s;
    }
}

// ---------------------------------------------------------------------------
// init conv: planar ext x [b0+b][3][64][64] -> NHWC8 x0, Cout=64
// ---------------------------------------------------------------------------
__global__ void __launch_bounds__(256)
conv_init_kernel(const void* __restrict__ src, const void* __restrict__ wgt,
                 const void* __restrict__ bias, bf16* __restrict__ dst,
                 const int* __restrict__ dflag, int b_off, int B)
{
    __shared__ float slds[3 * 34 * 36];
    __shared__ float wlds[3 * 16 * 12];
    const int ef = dflag[0];

    int bid = blockIdx.x;
    const int coI = bid & 3; bid >>= 2;
    const int tx = bid & 1; bid >>= 1;
    const int ty = bid & 1; bid >>= 1;
    const int b = bid;
    const int co0 = coI * 16;
    const int tid = threadIdx.x;
    const int wave = tid >> 6, lane = tid & 63;
    const int ty4 = lane >> 3, tx4 = lane & 7;
    const int yb = ty * 32, xb = tx * 32;

    for (int i = tid; i < 34 * 34 * 3; i += 256) {
        const int c = i / 1156, p = i % 1156;
        const int row = p / 34, col = p % 34;
        const int iy = yb + row - 1, ix = xb + col - 1;
        float v = 0.f;
        if (iy >= 0 && iy < 64 && ix >= 0 && ix < 64)
            v = eload(src, ((long)(b_off + b) * 3 + c) * 4096 + iy * 64 + ix, ef);
        slds[(c * 34 + row) * 36 + col] = v;
    }
    for (int i = tid; i < 3 * 144; i += 256) {
        const int ci = i / 144, r = i % 144;
        const int co = r / 9, k = r % 9;
        wlds[(ci * 16 + co) * 12 + k] = eload(wgt, ((long)(co0 + co) * 3 + ci) * 9 + k, ef);
    }
    __syncthreads();

    float acc[4][16];
#pragma unroll
    for (int i = 0; i < 4; ++i)
#pragma unroll
        for (int j = 0; j < 16; ++j) acc[i][j] = 0.f;

    for (int ci = 0; ci < 3; ++ci) {
        float in[6][6];
        const float* sp = &slds[(ci * 34 + ty4 * 4) * 36 + tx4 * 4];
#pragma unroll
        for (int r = 0; r < 6; ++r) {
            const float4 v4 = *(const float4*)(sp + r * 36);
            const float2 v2 = *(const float2*)(sp + r * 36 + 4);
            in[r][0] = v4.x; in[r][1] = v4.y; in[r][2] = v4.z; in[r][3] = v4.w;
            in[r][4] = v2.x; in[r][5] = v2.y;
        }
#pragma unroll
        for (int cc = 0; cc < 4; ++cc) {
            const float* wp = &wlds[(ci * 16 + wave * 4 + cc) * 12];
            const float4 wa = *(const float4*)wp;
            const float4 wb = *(const float4*)(wp + 4);
            const float w8 = wp[8];
#pragma unroll
            for (int r = 0; r < 4; ++r)
#pragma unroll
                for (int c = 0; c < 4; ++c)
                    acc[cc][r * 4 + c] += in[r][c] * wa.x + in[r][c+1] * wa.y + in[r][c+2] * wa.z
                        + in[r+1][c] * wa.w + in[r+1][c+1] * wb.x + in[r+1][c+2] * wb.y
                        + in[r+2][c] * wb.z + in[r+2][c+1] * wb.w + in[r+2][c+2] * w8;
        }
    }

    const int cg = coI * 2 + (wave >> 1);
    const int c8 = (wave & 1) * 4;
    float bv[4];
#pragma unroll
    for (int cc = 0; cc < 4; ++cc)
        bv[cc] = bias ? eload(bias, co0 + wave * 4 + cc, ef) : 0.0f;
#pragma unroll
    for (int r = 0; r < 4; ++r) {
        const int y = yb + ty4 * 4 + r;
#pragma unroll
        for (int c = 0; c < 4; ++c) {
            const int x = xb + tx4 * 4 + c;
            BfPack o;
#pragma unroll
            for (int cc = 0; cc < 4; ++cc)
                o.h[cc] = f2b(acc[cc][r * 4 + c] + bv[cc]);
            *(short4*)&dst[((((long)b * 8 + cg) * 64 + y) * 64 + x) * 8 + c8] = o.s;
        }
    }
}

// ---------------------------------------------------------------------------
__global__ void __launch_bounds__(256)
gn_silu_kernel(bf16* __restrict__ d, const void* __restrict__ g,
               const void* __restrict__ be, const int* __restrict__ dflag,
               int C, int gsize, int HW)
{
    const int ef = dflag[0];
    const int groups = C / gsize;
    const int blk = blockIdx.x;
    const int b  = blk / groups;
    const int gr = blk % groups;
    const long base = ((long)b * (C >> 3) + (long)gr * (gsize >> 3)) * HW * 8;
    const int N = gsize * HW;

    float s = 0.0f, ss = 0.0f;
    for (int i = threadIdx.x; i < N; i += 256) {
        const float v = b2f(d[base + i]);
        s += v; ss += v * v;
    }
    __shared__ float rs[256], rss[256];
    rs[threadIdx.x] = s; rss[threadIdx.x] = ss;
    __syncthreads();
    for (int o = 128; o > 0; o >>= 1) {
        if (threadIdx.x < o) {
            rs[threadIdx.x]  += rs[threadIdx.x + o];
            rss[threadIdx.x] += rss[threadIdx.x + o];
        }
        __syncthreads();
    }
    __shared__ float mean_s, inv_s;
    if (threadIdx.x == 0) {
        const float mean = rs[0] / (float)N;
        const float var  = rss[0] / (float)N - mean * mean;
        mean_s = mean; inv_s = rsqrtf(var + 1e-5f);
    }
    __syncthreads();
    const float mean = mean_s, inv = inv_s;
    for (int i = threadIdx.x; i < N; i += 256) {
        const int c = gr * gsize + (i / (HW * 8)) * 8 + (i & 7);
        const float v  = b2f(d[base + i]);
        const float xn = (v - mean) * inv * eload(g, c, ef) + eload(be, c, ef);
        d[base + i] = f2b(xn / (1.0f + expf(-xn)));
    }
}

__global__ void __launch_bounds__(256)
softmax_t_kernel(float* __restrict__ m, int BHW, int HW, float invtemp)
{
    const int i = blockIdx.x * 256 + threadIdx.x;
    if (i >= BHW) return;
    const int b = i / HW;
    const int p = i % HW;
    const long base = (long)b * 8 * HW + p;
    float v[8];
    float mx = -1e30f;
#pragma unroll
    for (int t = 0; t < 8; ++t) {
        v[t] = m[base + (long)t * HW] * invtemp;
        mx = fmaxf(mx, v[t]);
    }
    float s = 0.0f;
#pragma unroll
    for (int t = 0; t < 8; ++t) { v[t] = expf(v[t] - mx); s += v[t]; }
    const float r = 1.0f / s;
#pragma unroll
    for (int t = 0; t < 8; ++t) m[base + (long)t * HW] = v[t] * r;
}

__global__ void __launch_bounds__(256)
combine_kernel(const bf16* __restrict__ x0, const float* __restrict__ acc,
               const void* __restrict__ ss, const int* __restrict__ dflag,
               bf16* __restrict__ out, long n)
{
    const long i = (long)blockIdx.x * 256 + threadIdx.x;
    if (i < n) out[i] = f2b(b2f(x0[i]) + acc[i] * eload(ss, 0, dflag[0]));
}

__global__ void __launch_bounds__(256)
zero_kernel(float* __restrict__ p, long n)
{
    const long i = (long)blockIdx.x * 256 + threadIdx.x;
    if (i < n) p[i] = 0.0f;
}

// ---------------------------------------------------------------------------
static const int* g_dflag;

static void conv2w(hipStream_t st, const bf16* src, const bf16* wp,
                   const void* bias, void* dst, int dst_kind, int act,
                   int B, int Cin, int Cout, int H, int W, int up,
                   int src_row0, int src_rows, int dst_row0, int dst_rows_buf,
                   int dst_y0, int dst_rows,
                   const bf16* resid = nullptr, const float* att = nullptr,
                   const void* es = nullptr, const void* eb = nullptr, int eidx = 0,
                   int img_per_t = 0, long wstride = 0, int src_bmod = 0)
{
    const int cogs = (Cout + 15) >> 4;
    const int spatial = B * (dst_rows >> 4) * (W >> 4);
    // CPB: largest divisor of cogs (<=6) whose block count >= 448; else 1.
    static const int cands[5] = {6, 4, 3, 2, 1};
    int cpb = 1;
    for (int k = 0; k < 5; ++k) {
        const int c = cands[k];
        if (cogs % c) continue;
        if ((long)spatial * (cogs / c) >= 448) { cpb = c; break; }
        if (c == 1) cpb = 1;   // tiny spatial: max blocks, L2 eats restaging
    }
    const int cogb = cogs / cpb;
    const int blocks = spatial * cogb;
#define LAUNCH(CP) conv_mfma<CP><<<blocks, 256, 0, st>>>( \
        src, wp, bias, dst, dst_kind, act, resid, att, es, eb, eidx, g_dflag, \
        B, Cin, Cout, H, W, up, cogb, \
        src_row0, src_rows, dst_row0, dst_rows_buf, dst_y0, dst_rows, \
        img_per_t, wstride, src_bmod)
    switch (cpb) {
        case 6: LAUNCH(6); break;
        case 4: LAUNCH(4); break;
        case 3: LAUNCH(3); break;
        case 2: LAUNCH(2); break;
        default: LAUNCH(1); break;
    }
#undef LAUNCH
}

static void conv2(hipStream_t st, const bf16* src, const bf16* wp,
                  const void* bias, void* dst, int dst_kind, int act,
                  int B, int Cin, int Cout, int H, int W, int up,
                  const bf16* resid = nullptr, const float* att = nullptr,
                  const void* es = nullptr, const void* eb = nullptr, int eidx = 0,
                  int img_per_t = 0, long wstride = 0, int src_bmod = 0)
{
    conv2w(st, src, wp, bias, dst, dst_kind, act, B, Cin, Cout, H, W, up,
           0, up ? (H >> 1) : H, 0, H, 0, H, resid, att, es, eb, eidx,
           img_per_t, wstride, src_bmod);
}

static long wp_elems(int T, int Cout, int Cin)
{
    return (long)T * ((Cout + 15) / 16) * (Cin / 32) * 9 * 512;
}

extern "C" void kernel_launch(void* const* d_in, const int* in_sizes, int n_in,
                              void* d_out, int out_size, void* d_ws, size_t ws_size,
                              hipStream_t stream)
{
    const void* x_all   = d_in[0];
    const void* sp_all  = d_in[1];
    const void* nz_all  = d_in[2];
    const void* init_w  = d_in[3];
    const void* init_b  = d_in[4];
    const void* pre_w   = d_in[5];
    const void* tw0     = d_in[6];
    const void* tw1     = d_in[7];
    const void* tw2     = d_in[8];
    const void* tw3     = d_in[9];
    const void* tscale  = d_in[10];
    const void* tbias   = d_in[11];
    const void* nscale  = d_in[12];
    const void* sscale  = d_in[13];
    const void* pscale  = d_in[14];
    const void* post_w  = d_in[15];
    const void* post_b  = d_in[16];
    const void* m1_w    = d_in[17];
    const void* m1_b    = d_in[18];
    const void* m1_g    = d_in[19];
    const void* m1_be   = d_in[20];
    const void* m2_w    = d_in[21];
    const void* m2_g    = d_in[22];
    const void* m2_be   = d_in[23];
    const void* u1a_w   = d_in[24];
    const void* u1b_w   = d_in[25];
    const void* u1b_g   = d_in[26];
    const void* u1b_be  = d_in[27];
    const void* u2a_w   = d_in[28];
    const void* u2b_w   = d_in[29];
    const void* u2b_g   = d_in[30];
    const void* u2b_be  = d_in[31];
    const void* mf_w    = d_in[32];
    const void* up1_w   = d_in[33];
    const void* up1_b   = d_in[34];
    const void* up2_w   = d_in[35];
    const void* up2_b   = d_in[36];
    const void* hr_w    = d_in[37];
    const void* hr_b    = d_in[38];
    const void* fin_w   = d_in[39];
    const void* fin_b   = d_in[40];
    (void)in_sizes; (void)n_in; (void)out_size;

    char* wsb = (char*)d_ws;
    int* dflag = (int*)wsb;
    g_dflag = dflag;
    dtype_detect_kernel<<<1, 64, 0, stream>>>(tw1, 128, dflag);

    // ---- prepped-weight region ----
    bf16* WP = (bf16*)(wsb + 256);
    long off = 0;
    WTab tab; tab.n = 0;
    auto alloc = [&](const void* w, int T, int Cout, int Cin) {
        long o = off;
        long tot = wp_elems(T, Cout, Cin);
        tab.e[tab.n++] = WEnt{w, o, tot, Cout, Cin};
        off += tot;
        return o;
    };
    const long o_m1  = alloc(m1_w, 1, 256, 256);
    const long o_m2  = alloc(m2_w, 1, 256, 256);
    const long o_u1a = alloc(u1a_w, 1, 128, 256);
    const long o_u1b = alloc(u1b_w, 1, 128, 128);
    const long o_u2a = alloc(u2a_w, 1, 64, 128);
    const long o_u2b = alloc(u2b_w, 1, 64, 64);
    const long o_mf  = alloc(mf_w, 1, 8, 64);
    const long o_pre = alloc(pre_w, 1, 64, 64);
    const long o_tw0 = alloc(tw0, 8, 96, 64);
    const long o_tw1 = alloc(tw1, 8, 96, 96);
    const long o_tw2 = alloc(tw2, 8, 96, 96);
    const long o_tw3 = alloc(tw3, 8, 64, 96);
    const long o_post = alloc(post_w, 1, 64, 64);
    const long o_up1 = alloc(up1_w, 1, 64, 64);
    const long o_up2 = alloc(up2_w, 1, 64, 64);
    const long o_hr  = alloc(hr_w, 1, 64, 64);
    const long o_fin = alloc(fin_w, 1, 3, 64);
    const long wp_total = off;
    const size_t wp_bytes = (size_t)((wp_total * 2 + 255) & ~255L);

    wprep_all_kernel<<<1024, 256, 0, stream>>>(tab, dflag, WP);

    const long pt_tw0 = wp_elems(1, 96, 64), pt_tw1 = wp_elems(1, 96, 96);
    const long pt_tw3 = wp_elems(1, 64, 96);

    // ---- schedule: batch chunk bc, branch merge tcap, tail strip S ----
    int bc = 1, tcap = 1, S = 16, tc = 1;
    bool found = false;
    for (int c = 16; c >= 1 && !found; c >>= 1) {
        const size_t fixed = 256u + wp_bytes + (size_t)c * 1703936u;
        if (ws_size < fixed) continue;
        const size_t avail = ws_size - fixed;
        const size_t p1 = (size_t)c * 2228224u;                   // phase1
        auto p2 = [&](int t) -> size_t {
            if (t == 1) return (size_t)c * 2621440u;              // no xf
            return (size_t)c * 2u * (524288u + (size_t)t * 1048576u);
        };
        size_t need = p1;
        if (p2(1) > need) need = p2(1);
        if (need < 6291456u) need = 6291456u;
        if (avail < need) continue;
        bc = c; found = true;
        for (int t = 8; t >= 1; t >>= 1)
            if (p2(t) <= avail && p1 <= avail) { tcap = t; break; }
        if (avail >= 18874368u) {
            S = 256; tc = (int)(avail / 18874368u); if (tc > c) tc = c;
        } else if (avail >= 9437184u) S = 64;
        else if (avail >= 7340032u)  S = 32;
        else S = 16;
    }

    char* dyn = wsb + 256 + wp_bytes;
    float* M    = (float*)dyn;                                   // bc*32768 f32
    float* ACC  = (float*)(dyn + (size_t)bc * 131072u);          // bc*262144 f32
    bf16*  OUT2 = (bf16*)(dyn + (size_t)bc * 1179648u);          // bc*262144 bf16
    bf16*  A    = (bf16*)(dyn + (size_t)bc * 1703936u);          // arena

    for (int b0 = 0; b0 < 16; b0 += bc) {
        float* outp = (float*)d_out + (size_t)b0 * 3 * 65536;

        // ---- phase 1: multiplexer ----
        bf16* SP8 = A;
        bf16* f1 = A + (size_t)bc * 65536;
        bf16* f2 = A + (size_t)bc * 131072;
        bf16* g1 = A + (size_t)bc * 196608;
        bf16* g2 = A + (size_t)bc * 327680;
        bf16* h1 = A + (size_t)bc * 458752;
        bf16* h2 = A + (size_t)bc * 720896;

        {
            const long nn = (long)bc * 65536;
            to_nhwc8_kernel<<<1024, 256, 0, stream>>>(sp_all, dflag, SP8, b0, 256, 256, nn);
        }
        conv2(stream, SP8, WP + o_m1, m1_b, f1, 0, 0, bc, 256, 256, 16, 16, 0);
        gn_silu_kernel<<<bc * 8, 256, 0, stream>>>(f1, m1_g, m1_be, dflag, 256, 32, 256);
        conv2(stream, f1, WP + o_m2, nullptr, f2, 0, 0, bc, 256, 256, 16, 16, 0);
        gn_silu_kernel<<<bc * 8, 256, 0, stream>>>(f2, m2_g, m2_be, dflag, 256, 32, 256);
        conv2(stream, f2, WP + o_u1a, nullptr, g1, 0, 0, bc, 256, 128, 32, 32, 1);
        conv2(stream, g1, WP + o_u1b, nullptr, g2, 0, 0, bc, 128, 128, 32, 32, 0);
        gn_silu_kernel<<<bc * 8, 256, 0, stream>>>(g2, u1b_g, u1b_be, dflag, 128, 16, 1024);
        conv2(stream, g2, WP + o_u2a, nullptr, h1, 0, 0, bc, 128, 64, 64, 64, 1);
        conv2(stream, h1, WP + o_u2b, nullptr, h2, 0, 0, bc, 64, 64, 64, 64, 0);
        gn_silu_kernel<<<bc * 8, 256, 0, stream>>>(h2, u2b_g, u2b_be, dflag, 64, 8, 4096);
        conv2(stream, h2, WP + o_mf, nullptr, M, 3, 0, bc, 64, 8, 64, 64, 0);
        softmax_t_kernel<<<(bc * 4096 + 255) / 256, 256, 0, stream>>>(
            M, bc * 4096, 4096, 1.0f / 20.0f);

        // ---- phase 2: stem + branches ----
        bf16* x0   = A;
        bf16* xsp  = A + (size_t)bc * 262144;
        bf16* ping = A + (size_t)bc * 524288;
        bf16* pong = ping + (size_t)tcap * bc * 393216;
        bf16* xf   = pong + (size_t)tcap * bc * 393216;

        conv_init_kernel<<<bc * 16, 256, 0, stream>>>(x_all, init_w, init_b, x0,
                                                      dflag, b0, bc);
        {
            const long nn = (long)bc * 262144;
            addnoise_kernel<<<1024, 256, 0, stream>>>(x0, nz_all, nscale, dflag,
                                                      ping, b0, nn);
        }
        conv2(stream, ping, WP + o_pre, nullptr, xsp, 0, 0, bc, 64, 64, 64, 64, 0);

        const long accn = (long)bc * 262144;
        if (tcap > 1) {
            const int Beff = tcap * bc;
            for (int tg = 0; tg < 8; tg += tcap) {
                conv2(stream, xsp, WP + o_tw0 + (long)tg * pt_tw0, nullptr, ping, 0, 1,
                      Beff, 64, 96, 64, 64, 0, nullptr, nullptr, nullptr, nullptr, 0,
                      bc, pt_tw0, bc);
                conv2(stream, ping, WP + o_tw1 + (long)tg * pt_tw1, nullptr, pong, 0, 1,
                      Beff, 96, 96, 64, 64, 0, nullptr, nullptr, nullptr, nullptr, 0,
                      bc, pt_tw1, 0);
                conv2(stream, pong, WP + o_tw2 + (long)tg * pt_tw1, nullptr, ping, 0, 1,
                      Beff, 96, 96, 64, 64, 0, nullptr, nullptr, nullptr, nullptr, 0,
                      bc, pt_tw1, 0);
                conv2(stream, ping, WP + o_tw3 + (long)tg * pt_tw3, nullptr, xf, 0, 0,
                      Beff, 96, 64, 64, 64, 0, nullptr, nullptr, nullptr, nullptr, 0,
                      bc, pt_tw3, 0);
                acc_att_kernel<<<2048, 256, 0, stream>>>(xf, M, tscale, tbias, dflag,
                                                         ACC, bc, tcap, tg,
                                                         tg == 0 ? 1 : 0, accn);
            }
        } else {
            zero_kernel<<<(int)((accn + 255) / 256), 256, 0, stream>>>(ACC, accn);
            for (int t = 0; t < 8; ++t) {
                conv2(stream, xsp,  WP + o_tw0 + (long)t * pt_tw0, nullptr, ping, 0, 1,
                      bc, 64, 96, 64, 64, 0);
                conv2(stream, ping, WP + o_tw1 + (long)t * pt_tw1, nullptr, pong, 0, 1,
                      bc, 96, 96, 64, 64, 0);
                conv2(stream, pong, WP + o_tw2 + (long)t * pt_tw1, nullptr, ping, 0, 1,
                      bc, 96, 96, 64, 64, 0);
                conv2(stream, ping, WP + o_tw3 + (long)t * pt_tw3, nullptr, ACC, 1, 0,
                      bc, 96, 64, 64, 64, 0, nullptr, M, tscale, tbias, t);
            }
        }

        bf16* outc = xsp;
        combine_kernel<<<(int)((accn + 255) / 256), 256, 0, stream>>>(
            x0, ACC, sscale, dflag, outc, accn);

        conv2(stream, outc, WP + o_post, post_b, OUT2, 2, 0, bc, 64, 64, 64, 64, 0,
              outc, nullptr, pscale, nullptr, 0);

        // ---- phase 3: tail ----
        if (S == 256) {
            bf16* a1 = A;
            bf16* a2 = A + (size_t)tc * 1048576;
            bf16* a3 = A + (size_t)tc * 5242880;
            for (int s0 = 0; s0 < bc; s0 += tc) {
                const int cur = (tc < bc - s0) ? tc : (bc - s0);
                const bf16* src_c = OUT2 + (size_t)s0 * 262144;
                float* out_c = outp + (size_t)s0 * 3 * 65536;
                conv2(stream, src_c, WP + o_up1, up1_b, a1, 0, 1, cur, 64, 64, 128, 128, 1);
                conv2(stream, a1,   WP + o_up2, up2_b, a2, 0, 1, cur, 64, 64, 256, 256, 1);
                conv2(stream, a2,   WP + o_hr,  hr_b,  a3, 0, 1, cur, 64, 64, 256, 256, 0);
                conv2(stream, a3,   WP + o_fin, fin_b, out_c, 3, 0, cur, 64, 3, 256, 256, 0);
            }
        } else {
            bf16* a1  = A;
            bf16* a2s = A + 1048576;
            bf16* a3s = a2s + (size_t)(S + 64) * 16384;
            for (int i = 0; i < bc; ++i) {
                const bf16* src_i = OUT2 + (size_t)i * 262144;
                float* out_i = outp + (size_t)i * 3 * 65536;
                conv2(stream, src_i, WP + o_up1, up1_b, a1, 0, 1, 1, 64, 64, 128, 128, 1);
                for (int r0 = 0; r0 < 256; r0 += S) {
                    const int r1 = r0 + S;
                    const int w2a = (r0 - 32 > 0) ? r0 - 32 : 0;
                    const int w2b = (r1 + 32 < 256) ? r1 + 32 : 256;
                    const int w3a = (r0 - 16 > 0) ? r0 - 16 : 0;
                    const int w3b = (r1 + 16 < 256) ? r1 + 16 : 256;
                    conv2w(stream, a1, WP + o_up2, up2_b, a2s, 0, 1,
                           1, 64, 64, 256, 256, 1,
                           0, 128, w2a, w2b - w2a, w2a, w2b - w2a);
                    conv2w(stream, a2s, WP + o_hr, hr_b, a3s, 0, 1,
                           1, 64, 64, 256, 256, 0,
                           w2a, w2b - w2a, w3a, w3b - w3a, w3a, w3b - w3a);
                    conv2w(stream, a3s, WP + o_fin, fin_b, out_i, 3, 0,
                           1, 64, 3, 256, 256, 0,
                           w3a, w3b - w3a, 0, 256, r0, S);
                }
            }
        }
    }
}